// Round 5
// baseline (382.398 us; speedup 1.0000x reference)
//
#include <hip/hip_runtime.h>
#include <hip/hip_bf16.h>

#define HID 256
#define H1H 8
#define C1 32
#define C2 16
#define NEG 0.2f

typedef unsigned short ushort_t;
typedef unsigned int uint_t;
typedef __attribute__((ext_vector_type(8))) short short8;
typedef __attribute__((ext_vector_type(4))) float f32x4;

__device__ __forceinline__ float lrelu(float t){ return (t >= 0.f) ? t : NEG * t; }
__device__ __forceinline__ ushort_t f2bf(float f){
    uint_t u = __float_as_uint(f);
    u = (u + 0x7fffu + ((u >> 16) & 1u)) >> 16;   // RNE
    return (ushort_t)u;
}
__device__ __forceinline__ float bf_lo(uint_t p){ return __uint_as_float(p << 16); }
__device__ __forceinline__ float bf_hi(uint_t p){ return __uint_as_float(p & 0xffff0000u); }

// ---------------- prep: W1t[n][k] = bf16(W1[k][n]) ----------------
__global__ __launch_bounds__(256) void w1prep_k(const float* __restrict__ W1,
                                                ushort_t* __restrict__ W1t)
{
    __shared__ ushort_t sh[32][33];
    int bx = blockIdx.x & 7, by = blockIdx.x >> 3;   // k-tile, n-tile
    int tx = threadIdx.x & 31, ty = threadIdx.x >> 5; // 32 x 8
    #pragma unroll
    for (int i = 0; i < 32; i += 8)
        sh[ty + i][tx] = f2bf(W1[(long)(bx * 32 + ty + i) * 256 + by * 32 + tx]);
    __syncthreads();
    #pragma unroll
    for (int i = 0; i < 32; i += 8)
        W1t[(long)(by * 32 + ty + i) * 256 + bx * 32 + tx] = sh[tx][ty + i];
}

// ---------------- GEMM1 (MFMA): h1b = bf16( relu(x) @ W1 ) ----------------
__global__ __launch_bounds__(256) void gemm1_k(const float* __restrict__ X,
                                               const ushort_t* __restrict__ W1t,
                                               ushort_t* __restrict__ H1b, int M)
{
    __shared__ ushort_t A2[4][128][8];   // [kg][row][8k] bf16
    __shared__ ushort_t B2[4][128][8];   // [kg][col][8k] bf16
    int tid = threadIdx.x;
    int bm = blockIdx.y * 128, bn = blockIdx.x * 128;
    int wid = tid >> 6, lane = tid & 63;
    int wr = wid >> 1, wc = wid & 1;
    int lg = lane >> 4, lm = lane & 15;

    f32x4 acc[4][4];
    #pragma unroll
    for (int m = 0; m < 4; m++)
        #pragma unroll
        for (int n = 0; n < 4; n++) acc[m][n] = (f32x4){0.f, 0.f, 0.f, 0.f};

    int tq = tid & 7, trow = tid >> 3;   // A staging: row, 4k-quad
    int bkc = tid & 3, brow = tid >> 2;  // B staging: col-row, 8k-chunk

    for (int k0 = 0; k0 < 256; k0 += 32) {
        __syncthreads();
        // stage A: fp32 -> relu -> bf16
        #pragma unroll
        for (int i = 0; i < 4; i++) {
            int row = trow + (i << 5);
            int gm = bm + row;
            float4 xv = {0.f, 0.f, 0.f, 0.f};
            if (gm < M) xv = *(const float4*)(X + (long)gm * 256 + k0 + (tq << 2));
            uint2 pk;
            pk.x = (uint_t)f2bf(fmaxf(xv.x, 0.f)) | ((uint_t)f2bf(fmaxf(xv.y, 0.f)) << 16);
            pk.y = (uint_t)f2bf(fmaxf(xv.z, 0.f)) | ((uint_t)f2bf(fmaxf(xv.w, 0.f)) << 16);
            *(uint2*)&A2[tq >> 1][row][(tq & 1) << 2] = pk;
        }
        // stage B: already bf16, N-major
        #pragma unroll
        for (int i = 0; i < 2; i++) {
            int row = brow + (i << 6);
            uint4 wv = *(const uint4*)(W1t + (long)(bn + row) * 256 + k0 + (bkc << 3));
            *(uint4*)&B2[bkc][row][0] = wv;
        }
        __syncthreads();
        // fragments + MFMA
        short8 af[4], bf[4];
        #pragma unroll
        for (int m = 0; m < 4; m++)
            af[m] = *(const short8*)&A2[lg][wr * 64 + m * 16 + lm][0];
        #pragma unroll
        for (int n = 0; n < 4; n++)
            bf[n] = *(const short8*)&B2[lg][wc * 64 + n * 16 + lm][0];
        #pragma unroll
        for (int m = 0; m < 4; m++)
            #pragma unroll
            for (int n = 0; n < 4; n++)
                acc[m][n] = __builtin_amdgcn_mfma_f32_16x16x32_bf16(af[m], bf[n], acc[m][n], 0, 0, 0);
    }
    // epilogue: D[row=(lane>>4)*4+r][col=lane&15]
    #pragma unroll
    for (int m = 0; m < 4; m++) {
        #pragma unroll
        for (int r = 0; r < 4; r++) {
            int gm = bm + wr * 64 + m * 16 + lg * 4 + r;
            if (gm < M) {
                long base = (long)gm * 256 + bn + wc * 64 + lm;
                #pragma unroll
                for (int n = 0; n < 4; n++)
                    H1b[base + n * 16] = f2bf(acc[m][n][r]);
            }
        }
    }
}

// ---------------- alpha1: per (n,h) dot of bf16 h1 row with a_src/a_dst ----------------
__global__ __launch_bounds__(256) void alpha1_k(const ushort_t* __restrict__ H1b,
                                                const float* __restrict__ a1s,
                                                const float* __restrict__ a1d,
                                                float* __restrict__ as1,
                                                float* __restrict__ ad1, int Nn)
{
    int i = blockIdx.x * 256 + threadIdx.x;
    if (i >= Nn * H1H) return;
    int h = i & 7;
    const uint4* row = (const uint4*)(H1b + (long)i * C1);
    const float* av = a1s + h * C1;
    const float* dv = a1d + h * C1;
    float ss = 0.f, sd = 0.f;
    #pragma unroll
    for (int q = 0; q < 4; q++) {
        uint4 v = row[q];
        float x0 = bf_lo(v.x), x1 = bf_hi(v.x), x2 = bf_lo(v.y), x3 = bf_hi(v.y);
        float x4 = bf_lo(v.z), x5 = bf_hi(v.z), x6 = bf_lo(v.w), x7 = bf_hi(v.w);
        int k = q << 3;
        ss += x0*av[k] + x1*av[k+1] + x2*av[k+2] + x3*av[k+3]
            + x4*av[k+4] + x5*av[k+5] + x6*av[k+6] + x7*av[k+7];
        sd += x0*dv[k] + x1*dv[k+1] + x2*dv[k+2] + x3*dv[k+3]
            + x4*dv[k+4] + x5*dv[k+5] + x6*dv[k+6] + x7*dv[k+7];
    }
    as1[i] = ss; ad1[i] = sd;
}

// ---------------- CSR build ----------------
__global__ void deg_init_k(int* deg, int Nn)
{
    int i = blockIdx.x * 256 + threadIdx.x;
    if (i < Nn) deg[i] = 1;  // self loop
}
__global__ void deg_count_k(const int* __restrict__ dst, int E, int* deg)
{
    int i = blockIdx.x * 256 + threadIdx.x;
    if (i < E) atomicAdd(&deg[dst[i]], 1);
}
__global__ __launch_bounds__(256) void scan1_k(const int* __restrict__ deg,
                                               int* __restrict__ incl,
                                               int* __restrict__ bsum, int Nn)
{
    __shared__ int sh[256];
    int t = threadIdx.x;
    int base = blockIdx.x * 1024 + t * 4;
    int v0 = (base     < Nn) ? deg[base]     : 0;
    int v1 = (base + 1 < Nn) ? deg[base + 1] : 0;
    int v2 = (base + 2 < Nn) ? deg[base + 2] : 0;
    int v3 = (base + 3 < Nn) ? deg[base + 3] : 0;
    int s0 = v0, s1 = s0 + v1, s2 = s1 + v2, s3 = s2 + v3;
    sh[t] = s3;
    __syncthreads();
    for (int off = 1; off < 256; off <<= 1) {
        int x = (t >= off) ? sh[t - off] : 0;
        __syncthreads();
        sh[t] += x;
        __syncthreads();
    }
    int prev = (t > 0) ? sh[t - 1] : 0;
    if (base     < Nn) incl[base]     = prev + s0;
    if (base + 1 < Nn) incl[base + 1] = prev + s1;
    if (base + 2 < Nn) incl[base + 2] = prev + s2;
    if (base + 3 < Nn) incl[base + 3] = prev + s3;
    if (t == 255) bsum[blockIdx.x] = sh[255];
}
__global__ void scan2_k(const int* __restrict__ bsum, int* __restrict__ bpre, int nb)
{
    int t = threadIdx.x;                // single wave, nb <= 64
    int own = (t < nb) ? bsum[t] : 0;
    int v = own;
    for (int off = 1; off < 64; off <<= 1) {
        int x = __shfl_up(v, off);
        if (t >= off) v += x;
    }
    if (t < nb) bpre[t] = v - own;      // exclusive
}
__global__ void scan3_k(const int* __restrict__ incl, const int* __restrict__ deg,
                        const int* __restrict__ bpre, int* __restrict__ offs,
                        int* __restrict__ cursor, int Nn, int Etot)
{
    int i = blockIdx.x * 256 + threadIdx.x;
    if (i < Nn) {
        int e = bpre[i >> 10] + incl[i] - deg[i];
        offs[i] = e;
        cursor[i] = e;
    }
    if (i == 0) offs[Nn] = Etot;
}
__global__ void scatter_k(const int* __restrict__ src, const int* __restrict__ dst,
                          int E, int Nn, int* cursor, int* __restrict__ srcs)
{
    int i = blockIdx.x * 256 + threadIdx.x;
    if (i < E) {
        int p = atomicAdd(&cursor[dst[i]], 1);
        srcs[p] = src[i];
    } else if (i < E + Nn) {
        int n = i - E;
        int p = atomicAdd(&cursor[n], 1);
        srcs[p] = n;                    // self loop
    }
}

// ---------------- GAT layer 1 aggregate + fused GEMM2/alpha2: wave per dst ----------------
__global__ __launch_bounds__(256) void gat1_fused_k(const ushort_t* __restrict__ H1b,
    const float* __restrict__ as1, const float* __restrict__ ad1,
    const int* __restrict__ offs, const int* __restrict__ srcs,
    const float* __restrict__ b1, const float* __restrict__ W2,
    const float* __restrict__ a2s_w, const float* __restrict__ a2d_w,
    float* __restrict__ H2, float* __restrict__ as2, float* __restrict__ ad2, int Nn)
{
    __shared__ float W2s[16][256];    // transposed: W2s[c][k], 16 KiB
    for (int i = threadIdx.x; i < 16 * 256; i += 256) {
        int k = i >> 4, c = i & 15;
        W2s[c][k] = W2[i];
    }
    __syncthreads();

    int w = (blockIdx.x << 2) + (threadIdx.x >> 6);
    if (w >= Nn) return;
    int lane = threadIdx.x & 63;
    int he = lane & 7, el = lane >> 3;
    int beg = offs[w], end = offs[w + 1];
    float adv = ad1[(w << 3) + he];

    // pass 1: online softmax, 2 independent chains (16 edges/iter)
    float m = -1e30f, d = 0.f, mB = -1e30f, dB = 0.f;
    for (int j0 = beg; j0 < end; j0 += 16) {
        int j = j0 + el, jb = j0 + 8 + el;
        if (j < end) {
            float e = lrelu(as1[(srcs[j] << 3) + he] + adv);
            float nm = fmaxf(m, e);
            d = d * __expf(m - nm) + __expf(e - nm);
            m = nm;
        }
        if (jb < end) {
            float e = lrelu(as1[(srcs[jb] << 3) + he] + adv);
            float nm = fmaxf(mB, e);
            dB = dB * __expf(mB - nm) + __expf(e - nm);
            mB = nm;
        }
    }
    {   // merge chains
        float nm = fmaxf(m, mB);
        d = d * __expf(m - nm) + dB * __expf(mB - nm);
        m = nm;
    }
    #pragma unroll
    for (int off = 8; off < 64; off <<= 1) {
        float mo = __shfl_xor(m, off);
        float dd = __shfl_xor(d, off);
        float nm = fmaxf(m, mo);
        d = d * __expf(m - nm) + dd * __expf(mo - nm);
        m = nm;
    }
    float inv = 1.f / d;

    // pass 2: weighted bf16x4 gather-accumulate, 16 edges in flight
    float4 acc = {0.f, 0.f, 0.f, 0.f};
    int myh = lane >> 3;    // head owning this lane's 4 channels
    for (int j0 = beg; j0 < end; j0 += 16) {
        int j = j0 + el, jb = j0 + 8 + el;
        int s = 0, s2v = 0; float wv = 0.f, wv2 = 0.f;
        if (j < end) {
            s = srcs[j];
            wv = __expf(lrelu(as1[(s << 3) + he] + adv) - m) * inv;
        }
        if (jb < end) {
            s2v = srcs[jb];
            wv2 = __expf(lrelu(as1[(s2v << 3) + he] + adv) - m) * inv;
        }
        int ne = min(end - j0, 16);
        int sb[16]; float wb[16];
        #pragma unroll
        for (int e8 = 0; e8 < 8; e8++) {
            sb[e8] = __shfl(s, e8 << 3);
            wb[e8] = __shfl(wv, (e8 << 3) + myh);
        }
        #pragma unroll
        for (int e8 = 8; e8 < 16; e8++) {
            sb[e8] = __shfl(s2v, (e8 - 8) << 3);
            wb[e8] = __shfl(wv2, ((e8 - 8) << 3) + myh);
        }
        #pragma unroll
        for (int e8 = 0; e8 < 16; e8++) {
            if (e8 < ne) {
                uint2 v = ((const uint2*)(H1b + ((long)sb[e8] << 8)))[lane];
                acc.x += wb[e8] * bf_lo(v.x);
                acc.y += wb[e8] * bf_hi(v.x);
                acc.z += wb[e8] * bf_lo(v.y);
                acc.w += wb[e8] * bf_hi(v.y);
            }
        }
    }
    // x1 row in registers: channels 4*lane .. 4*lane+3 (fp32, no round-trip)
    float4 bb = ((const float4*)b1)[lane];
    float x0 = fmaxf(acc.x + bb.x, 0.f);
    float x1 = fmaxf(acc.y + bb.y, 0.f);
    float x2 = fmaxf(acc.z + bb.z, 0.f);
    float x3 = fmaxf(acc.w + bb.w, 0.f);

    // fused GEMM2: p[c] = sum over this lane's 4 k of x1[k]*W2[k][c]
    float p[16];
    #pragma unroll
    for (int c = 0; c < 16; c++) {
        float4 wc4 = *(const float4*)&W2s[c][lane << 2];
        p[c] = x0 * wc4.x + x1 * wc4.y + x2 * wc4.z + x3 * wc4.w;
    }
    #pragma unroll
    for (int off = 1; off < 64; off <<= 1)
        #pragma unroll
        for (int c = 0; c < 16; c++)
            p[c] += __shfl_xor(p[c], off);
    // all lanes now hold full h2 row; write + alpha2 dots
    float vs = 0.f, vd = 0.f;
    #pragma unroll
    for (int c = 0; c < 16; c++) {
        vs += p[c] * a2s_w[c];
        vd += p[c] * a2d_w[c];
    }
    if (lane < 16) {
        float hv = p[0];
        #pragma unroll
        for (int c = 1; c < 16; c++) if (lane == c) hv = p[c];
        H2[(w << 4) + lane] = hv;
    }
    if (lane == 0) { as2[w] = vs; ad2[w] = vd; }
}

// ---------------- GAT layer 2 aggregate + final softmax ----------------
__global__ __launch_bounds__(256) void gat2_agg_k(const float* __restrict__ H2,
    const float* __restrict__ as2, const float* __restrict__ ad2,
    const int* __restrict__ offs, const int* __restrict__ srcs,
    const float* __restrict__ b2, float* __restrict__ out, int Nn)
{
    int w = (blockIdx.x << 2) + (threadIdx.x >> 6);
    if (w >= Nn) return;
    int lane = threadIdx.x & 63;
    int beg = offs[w], end = offs[w + 1];
    float adv = ad2[w];
    // online max+denom
    float m = -1e30f, d = 0.f;
    for (int j = beg + lane; j < end; j += 64) {
        float e = lrelu(as2[srcs[j]] + adv);
        float nm = fmaxf(m, e);
        d = d * __expf(m - nm) + __expf(e - nm);
        m = nm;
    }
    #pragma unroll
    for (int off = 1; off < 64; off <<= 1) {
        float mo = __shfl_xor(m, off);
        float dd = __shfl_xor(d, off);
        float nm = fmaxf(m, mo);
        d = d * __expf(m - nm) + dd * __expf(mo - nm);
        m = nm;
    }
    float inv = 1.f / d;
    int c = lane & 15, eg = lane >> 4;
    float acc = 0.f;
    for (int j0 = beg; j0 < end; j0 += 4) {
        int j = j0 + eg;
        if (j < end) {
            int s = srcs[j];
            float wv = __expf(lrelu(as2[s] + adv) - m) * inv;
            acc += wv * H2[(s << 4) + c];
        }
    }
    acc += __shfl_xor(acc, 16);
    acc += __shfl_xor(acc, 32);
    float v = acc + b2[c];
    float mx = v;
    #pragma unroll
    for (int off = 1; off < 16; off <<= 1) mx = fmaxf(mx, __shfl_xor(mx, off));
    float ex = __expf(v - mx);
    float se = ex;
    #pragma unroll
    for (int off = 1; off < 16; off <<= 1) se += __shfl_xor(se, off);
    if (eg == 0) out[(w << 4) + c] = ex / se;
}

// ---------------- host launcher ----------------
extern "C" void kernel_launch(void* const* d_in, const int* in_sizes, int n_in,
                              void* d_out, int out_size, void* d_ws, size_t ws_size,
                              hipStream_t stream)
{
    const float* x    = (const float*)d_in[0];
    const int*   ei   = (const int*)d_in[1];
    const float* W1   = (const float*)d_in[2];
    const float* a1s  = (const float*)d_in[3];
    const float* a1d  = (const float*)d_in[4];
    const float* b1   = (const float*)d_in[5];
    const float* W2   = (const float*)d_in[6];
    const float* a2s  = (const float*)d_in[7];
    const float* a2d  = (const float*)d_in[8];
    const float* b2   = (const float*)d_in[9];
    float* out = (float*)d_out;

    int N = in_sizes[0] / HID;
    int E = in_sizes[1] / 2;
    int Etot = E + N;
    const int* src = ei;
    const int* dst = ei + E;

    char* p = (char*)d_ws;
    auto alloc = [&](size_t bytes) {
        void* r = (void*)p;
        p += (bytes + 255) & ~(size_t)255;
        return r;
    };
    ushort_t* h1b  = (ushort_t*)alloc((size_t)N * 256 * 2);
    ushort_t* w1t  = (ushort_t*)alloc((size_t)256 * 256 * 2);
    float* h2      = (float*)alloc((size_t)N * 16 * 4);
    float* as1     = (float*)alloc((size_t)N * 8 * 4);
    float* ad1     = (float*)alloc((size_t)N * 8 * 4);
    float* as2v    = (float*)alloc((size_t)N * 4);
    float* ad2v    = (float*)alloc((size_t)N * 4);
    int*   deg     = (int*)alloc((size_t)N * 4);
    int*   incl    = (int*)alloc((size_t)N * 4);
    int*   offs    = (int*)alloc((size_t)(N + 1) * 4);
    int*   cursor  = (int*)alloc((size_t)N * 4);
    int*   bsum    = (int*)alloc(256 * 4);
    int*   bpre    = (int*)alloc(256 * 4);
    int*   srcs    = (int*)alloc((size_t)Etot * 4);

    int nb = (N + 1023) / 1024;

    // prep + GEMM1 (MFMA) + alpha1
    hipLaunchKernelGGL(w1prep_k, dim3(64), dim3(256), 0, stream, W1, w1t);
    dim3 g1(2, (N + 127) / 128);
    hipLaunchKernelGGL(gemm1_k, g1, dim3(256), 0, stream, x, w1t, h1b, N);
    hipLaunchKernelGGL(alpha1_k, dim3((N * 8 + 255) / 256), dim3(256), 0, stream,
                       h1b, a1s, a1d, as1, ad1, N);
    // CSR build
    hipLaunchKernelGGL(deg_init_k, dim3((N + 255) / 256), dim3(256), 0, stream, deg, N);
    hipLaunchKernelGGL(deg_count_k, dim3((E + 255) / 256), dim3(256), 0, stream, dst, E, deg);
    hipLaunchKernelGGL(scan1_k, dim3(nb), dim3(256), 0, stream, deg, incl, bsum, N);
    hipLaunchKernelGGL(scan2_k, dim3(1), dim3(64), 0, stream, bsum, bpre, nb);
    hipLaunchKernelGGL(scan3_k, dim3((N + 255) / 256), dim3(256), 0, stream,
                       incl, deg, bpre, offs, cursor, N, Etot);
    hipLaunchKernelGGL(scatter_k, dim3((Etot + 255) / 256), dim3(256), 0, stream,
                       src, dst, E, N, cursor, srcs);
    // layer 1 aggregate + fused gemm2/alpha2
    hipLaunchKernelGGL(gat1_fused_k, dim3((N + 3) / 4), dim3(256), 0, stream,
                       h1b, as1, ad1, offs, srcs, b1, W2, a2s, a2d,
                       h2, as2v, ad2v, N);
    // layer 2 aggregate + final softmax
    hipLaunchKernelGGL(gat2_agg_k, dim3((N + 3) / 4), dim3(256), 0, stream,
                       h2, as2v, ad2v, offs, srcs, b2, out, N);
}

// Round 6
// 373.202 us; speedup vs baseline: 1.0246x; 1.0246x over previous
//
#include <hip/hip_runtime.h>
#include <hip/hip_bf16.h>

#define HID 256
#define H1H 8
#define C1 32
#define C2 16
#define NEG 0.2f

typedef unsigned short ushort_t;
typedef unsigned int uint_t;
typedef __attribute__((ext_vector_type(8))) short short8;
typedef __attribute__((ext_vector_type(4))) float f32x4;

__device__ __forceinline__ float lrelu(float t){ return (t >= 0.f) ? t : NEG * t; }
__device__ __forceinline__ ushort_t f2bf(float f){
    uint_t u = __float_as_uint(f);
    u = (u + 0x7fffu + ((u >> 16) & 1u)) >> 16;   // RNE
    return (ushort_t)u;
}
__device__ __forceinline__ float bf_lo(uint_t p){ return __uint_as_float(p << 16); }
__device__ __forceinline__ float bf_hi(uint_t p){ return __uint_as_float(p & 0xffff0000u); }

// ---------------- prep: W1t[n][k] = bf16(W1[k][n]) ----------------
__global__ __launch_bounds__(256) void w1prep_k(const float* __restrict__ W1,
                                                ushort_t* __restrict__ W1t)
{
    __shared__ ushort_t sh[32][33];
    int bx = blockIdx.x & 7, by = blockIdx.x >> 3;   // k-tile, n-tile
    int tx = threadIdx.x & 31, ty = threadIdx.x >> 5; // 32 x 8
    #pragma unroll
    for (int i = 0; i < 32; i += 8)
        sh[ty + i][tx] = f2bf(W1[(long)(bx * 32 + ty + i) * 256 + by * 32 + tx]);
    __syncthreads();
    #pragma unroll
    for (int i = 0; i < 32; i += 8)
        W1t[(long)(by * 32 + ty + i) * 256 + bx * 32 + tx] = sh[tx][ty + i];
}

// ---------------- GEMM1 (MFMA): h1b = bf16( relu(x) @ W1 ) ----------------
__global__ __launch_bounds__(256) void gemm1_k(const float* __restrict__ X,
                                               const ushort_t* __restrict__ W1t,
                                               ushort_t* __restrict__ H1b, int M)
{
    __shared__ ushort_t A2[4][128][8];   // [kg][row][8k] bf16
    __shared__ ushort_t B2[4][128][8];   // [kg][col][8k] bf16
    int tid = threadIdx.x;
    int bm = blockIdx.y * 128, bn = blockIdx.x * 128;
    int wid = tid >> 6, lane = tid & 63;
    int wr = wid >> 1, wc = wid & 1;
    int lg = lane >> 4, lm = lane & 15;

    f32x4 acc[4][4];
    #pragma unroll
    for (int m = 0; m < 4; m++)
        #pragma unroll
        for (int n = 0; n < 4; n++) acc[m][n] = (f32x4){0.f, 0.f, 0.f, 0.f};

    int tq = tid & 7, trow = tid >> 3;   // A staging: row, 4k-quad
    int bkc = tid & 3, brow = tid >> 2;  // B staging: col-row, 8k-chunk

    for (int k0 = 0; k0 < 256; k0 += 32) {
        __syncthreads();
        // stage A: fp32 -> relu -> bf16
        #pragma unroll
        for (int i = 0; i < 4; i++) {
            int row = trow + (i << 5);
            int gm = bm + row;
            float4 xv = {0.f, 0.f, 0.f, 0.f};
            if (gm < M) xv = *(const float4*)(X + (long)gm * 256 + k0 + (tq << 2));
            uint2 pk;
            pk.x = (uint_t)f2bf(fmaxf(xv.x, 0.f)) | ((uint_t)f2bf(fmaxf(xv.y, 0.f)) << 16);
            pk.y = (uint_t)f2bf(fmaxf(xv.z, 0.f)) | ((uint_t)f2bf(fmaxf(xv.w, 0.f)) << 16);
            *(uint2*)&A2[tq >> 1][row][(tq & 1) << 2] = pk;
        }
        // stage B: already bf16, N-major
        #pragma unroll
        for (int i = 0; i < 2; i++) {
            int row = brow + (i << 6);
            uint4 wv = *(const uint4*)(W1t + (long)(bn + row) * 256 + k0 + (bkc << 3));
            *(uint4*)&B2[bkc][row][0] = wv;
        }
        __syncthreads();
        // fragments + MFMA
        short8 af[4], bf[4];
        #pragma unroll
        for (int m = 0; m < 4; m++)
            af[m] = *(const short8*)&A2[lg][wr * 64 + m * 16 + lm][0];
        #pragma unroll
        for (int n = 0; n < 4; n++)
            bf[n] = *(const short8*)&B2[lg][wc * 64 + n * 16 + lm][0];
        #pragma unroll
        for (int m = 0; m < 4; m++)
            #pragma unroll
            for (int n = 0; n < 4; n++)
                acc[m][n] = __builtin_amdgcn_mfma_f32_16x16x32_bf16(af[m], bf[n], acc[m][n], 0, 0, 0);
    }
    // epilogue: D[row=(lane>>4)*4+r][col=lane&15]
    #pragma unroll
    for (int m = 0; m < 4; m++) {
        #pragma unroll
        for (int r = 0; r < 4; r++) {
            int gm = bm + wr * 64 + m * 16 + lg * 4 + r;
            if (gm < M) {
                long base = (long)gm * 256 + bn + wc * 64 + lm;
                #pragma unroll
                for (int n = 0; n < 4; n++)
                    H1b[base + n * 16] = f2bf(acc[m][n][r]);
            }
        }
    }
}

// ---------------- alpha1: per (n,h) dot of bf16 h1 row with a_src/a_dst ----------------
__global__ __launch_bounds__(256) void alpha1_k(const ushort_t* __restrict__ H1b,
                                                const float* __restrict__ a1s,
                                                const float* __restrict__ a1d,
                                                float* __restrict__ as1,
                                                float* __restrict__ ad1, int Nn)
{
    int i = blockIdx.x * 256 + threadIdx.x;
    if (i >= Nn * H1H) return;
    int h = i & 7;
    const uint4* row = (const uint4*)(H1b + (long)i * C1);
    const float* av = a1s + h * C1;
    const float* dv = a1d + h * C1;
    float ss = 0.f, sd = 0.f;
    #pragma unroll
    for (int q = 0; q < 4; q++) {
        uint4 v = row[q];
        float x0 = bf_lo(v.x), x1 = bf_hi(v.x), x2 = bf_lo(v.y), x3 = bf_hi(v.y);
        float x4 = bf_lo(v.z), x5 = bf_hi(v.z), x6 = bf_lo(v.w), x7 = bf_hi(v.w);
        int k = q << 3;
        ss += x0*av[k] + x1*av[k+1] + x2*av[k+2] + x3*av[k+3]
            + x4*av[k+4] + x5*av[k+5] + x6*av[k+6] + x7*av[k+7];
        sd += x0*dv[k] + x1*dv[k+1] + x2*dv[k+2] + x3*dv[k+3]
            + x4*dv[k+4] + x5*dv[k+5] + x6*dv[k+6] + x7*dv[k+7];
    }
    as1[i] = ss; ad1[i] = sd;
}

// ---------------- CSR build ----------------
__global__ void deg_init_k(int* deg, int Nn)
{
    int i = blockIdx.x * 256 + threadIdx.x;
    if (i < Nn) deg[i] = 1;  // self loop
}
__global__ void deg_count_k(const int* __restrict__ dst, int E, int* deg)
{
    int i = blockIdx.x * 256 + threadIdx.x;
    if (i < E) atomicAdd(&deg[dst[i]], 1);
}
__global__ __launch_bounds__(256) void scan1_k(const int* __restrict__ deg,
                                               int* __restrict__ incl,
                                               int* __restrict__ bsum, int Nn)
{
    __shared__ int sh[256];
    int t = threadIdx.x;
    int base = blockIdx.x * 1024 + t * 4;
    int v0 = (base     < Nn) ? deg[base]     : 0;
    int v1 = (base + 1 < Nn) ? deg[base + 1] : 0;
    int v2 = (base + 2 < Nn) ? deg[base + 2] : 0;
    int v3 = (base + 3 < Nn) ? deg[base + 3] : 0;
    int s0 = v0, s1 = s0 + v1, s2 = s1 + v2, s3 = s2 + v3;
    sh[t] = s3;
    __syncthreads();
    for (int off = 1; off < 256; off <<= 1) {
        int x = (t >= off) ? sh[t - off] : 0;
        __syncthreads();
        sh[t] += x;
        __syncthreads();
    }
    int prev = (t > 0) ? sh[t - 1] : 0;
    if (base     < Nn) incl[base]     = prev + s0;
    if (base + 1 < Nn) incl[base + 1] = prev + s1;
    if (base + 2 < Nn) incl[base + 2] = prev + s2;
    if (base + 3 < Nn) incl[base + 3] = prev + s3;
    if (t == 255) bsum[blockIdx.x] = sh[255];
}
__global__ void scan2_k(const int* __restrict__ bsum, int* __restrict__ bpre, int nb)
{
    int t = threadIdx.x;                // single wave, nb <= 64
    int own = (t < nb) ? bsum[t] : 0;
    int v = own;
    for (int off = 1; off < 64; off <<= 1) {
        int x = __shfl_up(v, off);
        if (t >= off) v += x;
    }
    if (t < nb) bpre[t] = v - own;      // exclusive
}
__global__ void scan3_k(const int* __restrict__ incl, const int* __restrict__ deg,
                        const int* __restrict__ bpre, int* __restrict__ offs,
                        int* __restrict__ cursor, int Nn, int Etot)
{
    int i = blockIdx.x * 256 + threadIdx.x;
    if (i < Nn) {
        int e = bpre[i >> 10] + incl[i] - deg[i];
        offs[i] = e;
        cursor[i] = e;
    }
    if (i == 0) offs[Nn] = Etot;
}
__global__ void scatter_k(const int* __restrict__ src, const int* __restrict__ dst,
                          int E, int Nn, int* cursor,
                          int* __restrict__ srcs, int* __restrict__ dsts)
{
    int i = blockIdx.x * 256 + threadIdx.x;
    if (i < E) {
        int d = dst[i];
        int p = atomicAdd(&cursor[d], 1);
        srcs[p] = src[i];
        dsts[p] = d;
    } else if (i < E + Nn) {
        int n = i - E;
        int p = atomicAdd(&cursor[n], 1);
        srcs[p] = n;                    // self loop
        dsts[p] = n;
    }
}

// ---------------- GAT layer 1 aggregate: wave per dst node (no-max softmax) ----------------
__global__ __launch_bounds__(256) void gat1_agg_k(const ushort_t* __restrict__ H1b,
    const float* __restrict__ as1, const float* __restrict__ ad1,
    const int* __restrict__ offs, const int* __restrict__ srcs,
    const float* __restrict__ b1, ushort_t* __restrict__ X1b, int Nn)
{
    int w = (blockIdx.x << 2) + (threadIdx.x >> 6);
    if (w >= Nn) return;
    int lane = threadIdx.x & 63;
    int he = lane & 7, el = lane >> 3;
    int beg = offs[w], end = offs[w + 1];
    float adv = ad1[(w << 3) + he];

    // pass 1: denom = sum exp(e)  (logits bounded ~|e|<4, no max shift needed)
    float dA = 0.f, dB = 0.f;
    for (int j0 = beg; j0 < end; j0 += 16) {
        int j = j0 + el, jb = j0 + 8 + el;
        if (j < end)
            dA += __expf(lrelu(as1[(srcs[j] << 3) + he] + adv));
        if (jb < end)
            dB += __expf(lrelu(as1[(srcs[jb] << 3) + he] + adv));
    }
    float d = dA + dB;
    #pragma unroll
    for (int off = 8; off < 64; off <<= 1) d += __shfl_xor(d, off);
    float inv = 1.f / d;

    // pass 2: weighted bf16x4 gather-accumulate, 16 rows in flight
    float4 acc = {0.f, 0.f, 0.f, 0.f};
    int myh = lane >> 3;    // head owning this lane's 4 channels
    for (int j0 = beg; j0 < end; j0 += 16) {
        int j = j0 + el, jb = j0 + 8 + el;
        int s = 0, s2v = 0; float wv = 0.f, wv2 = 0.f;
        if (j < end) {
            s = srcs[j];
            wv = __expf(lrelu(as1[(s << 3) + he] + adv)) * inv;
        }
        if (jb < end) {
            s2v = srcs[jb];
            wv2 = __expf(lrelu(as1[(s2v << 3) + he] + adv)) * inv;
        }
        int ne = min(end - j0, 16);
        int sb[16]; float wb[16];
        #pragma unroll
        for (int e8 = 0; e8 < 8; e8++) {
            sb[e8] = __shfl(s, e8 << 3);
            wb[e8] = __shfl(wv, (e8 << 3) + myh);
        }
        #pragma unroll
        for (int e8 = 8; e8 < 16; e8++) {
            sb[e8] = __shfl(s2v, (e8 - 8) << 3);
            wb[e8] = __shfl(wv2, ((e8 - 8) << 3) + myh);
        }
        if (ne == 16) {
            #pragma unroll
            for (int e8 = 0; e8 < 16; e8++) {
                uint2 v = ((const uint2*)(H1b + ((long)sb[e8] << 8)))[lane];
                acc.x += wb[e8] * bf_lo(v.x);
                acc.y += wb[e8] * bf_hi(v.x);
                acc.z += wb[e8] * bf_lo(v.y);
                acc.w += wb[e8] * bf_hi(v.y);
            }
        } else {
            #pragma unroll
            for (int e8 = 0; e8 < 16; e8++) {
                if (e8 < ne) {
                    uint2 v = ((const uint2*)(H1b + ((long)sb[e8] << 8)))[lane];
                    acc.x += wb[e8] * bf_lo(v.x);
                    acc.y += wb[e8] * bf_hi(v.x);
                    acc.z += wb[e8] * bf_lo(v.y);
                    acc.w += wb[e8] * bf_hi(v.y);
                }
            }
        }
    }
    float4 bb = ((const float4*)b1)[lane];
    float o0 = fmaxf(acc.x + bb.x, 0.f);
    float o1 = fmaxf(acc.y + bb.y, 0.f);
    float o2 = fmaxf(acc.z + bb.z, 0.f);
    float o3 = fmaxf(acc.w + bb.w, 0.f);
    uint2 ov;
    ov.x = (uint_t)f2bf(o0) | ((uint_t)f2bf(o1) << 16);
    ov.y = (uint_t)f2bf(o2) | ((uint_t)f2bf(o3) << 16);
    ((uint2*)(X1b + ((long)w << 8)))[lane] = ov;
}

// ---------------- GEMM2 + alpha2: h2 = x1 @ W2, wave per node ----------------
// W2 read directly from global: per t-iter the wave reads 256B contiguous (L1-resident 16KB)
__global__ __launch_bounds__(256) void gemm2_k(const ushort_t* __restrict__ X1b,
    const float* __restrict__ W2, const float* __restrict__ a2s_w,
    const float* __restrict__ a2d_w, float* __restrict__ H2,
    float* __restrict__ as2, float* __restrict__ ad2, int Nn)
{
    int w = (blockIdx.x << 2) + (threadIdx.x >> 6);
    if (w >= Nn) return;
    int lane = threadIdx.x & 63;
    int c = lane & 15, kg = lane >> 4;
    const uint2* xr = (const uint2*)(X1b + ((long)w << 8));
    float sum = 0.f;
    #pragma unroll
    for (int t = 0; t < 16; t++) {
        uint2 v = xr[(t << 2) + kg];        // channels k..k+3, k = t*16 + kg*4
        int k = (t << 4) + (kg << 2);
        sum += bf_lo(v.x) * W2[(k << 4) + c]     + bf_hi(v.x) * W2[((k+1) << 4) + c]
             + bf_lo(v.y) * W2[((k+2) << 4) + c] + bf_hi(v.y) * W2[((k+3) << 4) + c];
    }
    sum += __shfl_xor(sum, 16);
    sum += __shfl_xor(sum, 32);
    float vs = sum * a2s_w[c];
    float vd = sum * a2d_w[c];
    #pragma unroll
    for (int off = 1; off < 16; off <<= 1) {
        vs += __shfl_xor(vs, off);
        vd += __shfl_xor(vd, off);
    }
    if (kg == 0) {
        H2[(w << 4) + c] = sum;
        if (c == 0) { as2[w] = vs; ad2[w] = vd; }
    }
}

// ---------------- e2 prep: per-edge exp(lrelu(...)) , edge-parallel ----------------
__global__ __launch_bounds__(256) void e2prep_k(const float* __restrict__ as2,
    const float* __restrict__ ad2, const int* __restrict__ srcs,
    const int* __restrict__ dsts, float* __restrict__ e2x, int Etot)
{
    int i = blockIdx.x * 256 + threadIdx.x;
    if (i < Etot)
        e2x[i] = __expf(lrelu(as2[srcs[i]] + ad2[dsts[i]]));
}

// ---------------- GAT layer 2 aggregate + final softmax (streams e2x) ----------------
__global__ __launch_bounds__(256) void gat2_agg_k(const float* __restrict__ H2,
    const float* __restrict__ e2x,
    const int* __restrict__ offs, const int* __restrict__ srcs,
    const float* __restrict__ b2, float* __restrict__ out, int Nn)
{
    int w = (blockIdx.x << 2) + (threadIdx.x >> 6);
    if (w >= Nn) return;
    int lane = threadIdx.x & 63;
    int beg = offs[w], end = offs[w + 1];
    // denom: coalesced stream of e2x
    float d = 0.f;
    for (int j = beg + lane; j < end; j += 64) d += e2x[j];
    #pragma unroll
    for (int off = 1; off < 64; off <<= 1) d += __shfl_xor(d, off);
    float inv = 1.f / d;
    int c = lane & 15, eg = lane >> 4;
    float acc = 0.f;
    for (int j0 = beg; j0 < end; j0 += 4) {
        int j = j0 + eg;
        if (j < end)
            acc += e2x[j] * inv * H2[(srcs[j] << 4) + c];
    }
    acc += __shfl_xor(acc, 16);
    acc += __shfl_xor(acc, 32);
    float v = acc + b2[c];
    float mx = v;
    #pragma unroll
    for (int off = 1; off < 16; off <<= 1) mx = fmaxf(mx, __shfl_xor(mx, off));
    float ex = __expf(v - mx);
    float se = ex;
    #pragma unroll
    for (int off = 1; off < 16; off <<= 1) se += __shfl_xor(se, off);
    if (eg == 0) out[(w << 4) + c] = ex / se;
}

// ---------------- host launcher ----------------
extern "C" void kernel_launch(void* const* d_in, const int* in_sizes, int n_in,
                              void* d_out, int out_size, void* d_ws, size_t ws_size,
                              hipStream_t stream)
{
    const float* x    = (const float*)d_in[0];
    const int*   ei   = (const int*)d_in[1];
    const float* W1   = (const float*)d_in[2];
    const float* a1s  = (const float*)d_in[3];
    const float* a1d  = (const float*)d_in[4];
    const float* b1   = (const float*)d_in[5];
    const float* W2   = (const float*)d_in[6];
    const float* a2s  = (const float*)d_in[7];
    const float* a2d  = (const float*)d_in[8];
    const float* b2   = (const float*)d_in[9];
    float* out = (float*)d_out;

    int N = in_sizes[0] / HID;
    int E = in_sizes[1] / 2;
    int Etot = E + N;
    const int* src = ei;
    const int* dst = ei + E;

    char* p = (char*)d_ws;
    auto alloc = [&](size_t bytes) {
        void* r = (void*)p;
        p += (bytes + 255) & ~(size_t)255;
        return r;
    };
    ushort_t* h1b  = (ushort_t*)alloc((size_t)N * 256 * 2);
    ushort_t* x1b  = (ushort_t*)alloc((size_t)N * 256 * 2);
    ushort_t* w1t  = (ushort_t*)alloc((size_t)256 * 256 * 2);
    float* h2      = (float*)alloc((size_t)N * 16 * 4);
    float* as1     = (float*)alloc((size_t)N * 8 * 4);
    float* ad1     = (float*)alloc((size_t)N * 8 * 4);
    float* as2v    = (float*)alloc((size_t)N * 4);
    float* ad2v    = (float*)alloc((size_t)N * 4);
    int*   deg     = (int*)alloc((size_t)N * 4);
    int*   incl    = (int*)alloc((size_t)N * 4);
    int*   offs    = (int*)alloc((size_t)(N + 1) * 4);
    int*   cursor  = (int*)alloc((size_t)N * 4);
    int*   bsum    = (int*)alloc(256 * 4);
    int*   bpre    = (int*)alloc(256 * 4);
    int*   srcs    = (int*)alloc((size_t)Etot * 4);
    int*   dsts    = (int*)alloc((size_t)Etot * 4);
    float* e2x     = (float*)alloc((size_t)Etot * 4);

    int nb = (N + 1023) / 1024;

    // prep + GEMM1 (MFMA) + alpha1
    hipLaunchKernelGGL(w1prep_k, dim3(64), dim3(256), 0, stream, W1, w1t);
    dim3 g1(2, (N + 127) / 128);
    hipLaunchKernelGGL(gemm1_k, g1, dim3(256), 0, stream, x, w1t, h1b, N);
    hipLaunchKernelGGL(alpha1_k, dim3((N * 8 + 255) / 256), dim3(256), 0, stream,
                       h1b, a1s, a1d, as1, ad1, N);
    // CSR build
    hipLaunchKernelGGL(deg_init_k, dim3((N + 255) / 256), dim3(256), 0, stream, deg, N);
    hipLaunchKernelGGL(deg_count_k, dim3((E + 255) / 256), dim3(256), 0, stream, dst, E, deg);
    hipLaunchKernelGGL(scan1_k, dim3(nb), dim3(256), 0, stream, deg, incl, bsum, N);
    hipLaunchKernelGGL(scan2_k, dim3(1), dim3(64), 0, stream, bsum, bpre, nb);
    hipLaunchKernelGGL(scan3_k, dim3((N + 255) / 256), dim3(256), 0, stream,
                       incl, deg, bpre, offs, cursor, N, Etot);
    hipLaunchKernelGGL(scatter_k, dim3((Etot + 255) / 256), dim3(256), 0, stream,
                       src, dst, E, N, cursor, srcs, dsts);
    // layer 1 aggregate
    hipLaunchKernelGGL(gat1_agg_k, dim3((N + 3) / 4), dim3(256), 0, stream,
                       h1b, as1, ad1, offs, srcs, b1, x1b, N);
    // layer 2
    hipLaunchKernelGGL(gemm2_k, dim3((N + 3) / 4), dim3(256), 0, stream,
                       x1b, W2, a2s, a2d, h2, as2v, ad2v, N);
    hipLaunchKernelGGL(e2prep_k, dim3((Etot + 255) / 256), dim3(256), 0, stream,
                       as2v, ad2v, srcs, dsts, e2x, Etot);
    hipLaunchKernelGGL(gat2_agg_k, dim3((N + 3) / 4), dim3(256), 0, stream,
                       h2, e2x, offs, srcs, b2, out, N);
}

// Round 8
// 316.104 us; speedup vs baseline: 1.2097x; 1.1806x over previous
//
#include <hip/hip_runtime.h>
#include <hip/hip_bf16.h>

#define HID 256
#define H1H 8
#define C1 32
#define C2 16
#define NEG 0.2f

typedef unsigned short ushort_t;
typedef unsigned int uint_t;
typedef __attribute__((ext_vector_type(8))) short short8;
typedef __attribute__((ext_vector_type(4))) float f32x4;

__device__ __forceinline__ float lrelu(float t){ return (t >= 0.f) ? t : NEG * t; }
__device__ __forceinline__ ushort_t f2bf(float f){
    uint_t u = __float_as_uint(f);
    u = (u + 0x7fffu + ((u >> 16) & 1u)) >> 16;   // RNE
    return (ushort_t)u;
}
__device__ __forceinline__ float bf_lo(uint_t p){ return __uint_as_float(p << 16); }
__device__ __forceinline__ float bf_hi(uint_t p){ return __uint_as_float(p & 0xffff0000u); }

// ---------------- prep: W1t[n][k] = bf16(W1[k][n]) ----------------
__global__ __launch_bounds__(256) void w1prep_k(const float* __restrict__ W1,
                                                ushort_t* __restrict__ W1t)
{
    __shared__ ushort_t sh[32][33];
    int bx = blockIdx.x & 7, by = blockIdx.x >> 3;   // k-tile, n-tile
    int tx = threadIdx.x & 31, ty = threadIdx.x >> 5; // 32 x 8
    #pragma unroll
    for (int i = 0; i < 32; i += 8)
        sh[ty + i][tx] = f2bf(W1[(long)(bx * 32 + ty + i) * 256 + by * 32 + tx]);
    __syncthreads();
    #pragma unroll
    for (int i = 0; i < 32; i += 8)
        W1t[(long)(by * 32 + ty + i) * 256 + bx * 32 + tx] = sh[tx][ty + i];
}

// ---------------- GEMM1 (MFMA): h1b = bf16( relu(x) @ W1 ) + fused alpha1 ----------------
__global__ __launch_bounds__(256) void gemm1_k(const float* __restrict__ X,
                                               const ushort_t* __restrict__ W1t,
                                               const float* __restrict__ a1s_g,
                                               const float* __restrict__ a1d_g,
                                               ushort_t* __restrict__ H1b,
                                               float* __restrict__ as1,
                                               float* __restrict__ ad1, int M)
{
    __shared__ ushort_t A2[4][128][8];   // [kg][row][8k] bf16
    __shared__ ushort_t B2[4][128][8];   // [kg][col][8k] bf16
    int tid = threadIdx.x;
    int bm = blockIdx.y * 128, bn = blockIdx.x * 128;
    int wid = tid >> 6, lane = tid & 63;
    int wr = wid >> 1, wc = wid & 1;
    int lg = lane >> 4, lm = lane & 15;

    f32x4 acc[4][4];
    #pragma unroll
    for (int m = 0; m < 4; m++)
        #pragma unroll
        for (int n = 0; n < 4; n++) acc[m][n] = (f32x4){0.f, 0.f, 0.f, 0.f};

    int tq = tid & 7, trow = tid >> 3;   // A staging: row, 4k-quad
    int bkc = tid & 3, brow = tid >> 2;  // B staging: col-row, 8k-chunk

    for (int k0 = 0; k0 < 256; k0 += 32) {
        __syncthreads();
        // stage A: fp32 -> relu -> bf16
        #pragma unroll
        for (int i = 0; i < 4; i++) {
            int row = trow + (i << 5);
            int gm = bm + row;
            float4 xv = {0.f, 0.f, 0.f, 0.f};
            if (gm < M) xv = *(const float4*)(X + (long)gm * 256 + k0 + (tq << 2));
            uint2 pk;
            pk.x = (uint_t)f2bf(fmaxf(xv.x, 0.f)) | ((uint_t)f2bf(fmaxf(xv.y, 0.f)) << 16);
            pk.y = (uint_t)f2bf(fmaxf(xv.z, 0.f)) | ((uint_t)f2bf(fmaxf(xv.w, 0.f)) << 16);
            *(uint2*)&A2[tq >> 1][row][(tq & 1) << 2] = pk;
        }
        // stage B: already bf16, N-major
        #pragma unroll
        for (int i = 0; i < 2; i++) {
            int row = brow + (i << 6);
            uint4 wv = *(const uint4*)(W1t + (long)(bn + row) * 256 + k0 + (bkc << 3));
            *(uint4*)&B2[bkc][row][0] = wv;
        }
        __syncthreads();
        // fragments + MFMA
        short8 af[4], bf[4];
        #pragma unroll
        for (int m = 0; m < 4; m++)
            af[m] = *(const short8*)&A2[lg][wr * 64 + m * 16 + lm][0];
        #pragma unroll
        for (int n = 0; n < 4; n++)
            bf[n] = *(const short8*)&B2[lg][wc * 64 + n * 16 + lm][0];
        #pragma unroll
        for (int m = 0; m < 4; m++)
            #pragma unroll
            for (int n = 0; n < 4; n++)
                acc[m][n] = __builtin_amdgcn_mfma_f32_16x16x32_bf16(af[m], bf[n], acc[m][n], 0, 0, 0);
    }
    // fused alpha1: this thread's cols for (m,r) live in heads h0 (n=0,1) and h0+1 (n=2,3)
    // head h0 = bn/32 + 2*wc; channel = lm (n even) or lm+16 (n odd)
    int h0 = ((bn >> 5) + (wc << 1));
    float as_l0 = a1s_g[h0 * 32 + lm],       as_h0 = a1s_g[h0 * 32 + 16 + lm];
    float as_l1 = a1s_g[(h0 + 1) * 32 + lm], as_h1 = a1s_g[(h0 + 1) * 32 + 16 + lm];
    float ad_l0 = a1d_g[h0 * 32 + lm],       ad_h0 = a1d_g[h0 * 32 + 16 + lm];
    float ad_l1 = a1d_g[(h0 + 1) * 32 + lm], ad_h1 = a1d_g[(h0 + 1) * 32 + 16 + lm];

    // epilogue: D[row=(lane>>4)*4+r][col=lane&15]
    #pragma unroll
    for (int m = 0; m < 4; m++) {
        #pragma unroll
        for (int r = 0; r < 4; r++) {
            int gm = bm + wr * 64 + m * 16 + lg * 4 + r;
            float s0 = acc[m][0][r] * as_l0 + acc[m][1][r] * as_h0;
            float s1 = acc[m][2][r] * as_l1 + acc[m][3][r] * as_h1;
            float d0 = acc[m][0][r] * ad_l0 + acc[m][1][r] * ad_h0;
            float d1 = acc[m][2][r] * ad_l1 + acc[m][3][r] * ad_h1;
            #pragma unroll
            for (int off = 1; off < 16; off <<= 1) {
                s0 += __shfl_xor(s0, off);
                s1 += __shfl_xor(s1, off);
                d0 += __shfl_xor(d0, off);
                d1 += __shfl_xor(d1, off);
            }
            if (gm < M) {
                long base = (long)gm * 256 + bn + wc * 64 + lm;
                #pragma unroll
                for (int n = 0; n < 4; n++)
                    H1b[base + n * 16] = f2bf(acc[m][n][r]);
                if (lm == 0) {
                    float2 sv = {s0, s1}, dv = {d0, d1};
                    *(float2*)&as1[(gm << 3) + h0] = sv;
                    *(float2*)&ad1[(gm << 3) + h0] = dv;
                }
            }
        }
    }
}

// ---------------- CSR build ----------------
__global__ void deg_init_k(int* deg, int Nn)
{
    int i = blockIdx.x * 256 + threadIdx.x;
    if (i < Nn) deg[i] = 1;  // self loop
}
__global__ void deg_count_k(const int* __restrict__ dst, int E, int* deg)
{
    int i = blockIdx.x * 256 + threadIdx.x;
    if (i < E) atomicAdd(&deg[dst[i]], 1);
}
__global__ __launch_bounds__(256) void scan1_k(const int* __restrict__ deg,
                                               int* __restrict__ incl,
                                               int* __restrict__ bsum, int Nn)
{
    __shared__ int sh[256];
    int t = threadIdx.x;
    int base = blockIdx.x * 1024 + t * 4;
    int v0 = (base     < Nn) ? deg[base]     : 0;
    int v1 = (base + 1 < Nn) ? deg[base + 1] : 0;
    int v2 = (base + 2 < Nn) ? deg[base + 2] : 0;
    int v3 = (base + 3 < Nn) ? deg[base + 3] : 0;
    int s0 = v0, s1 = s0 + v1, s2 = s1 + v2, s3 = s2 + v3;
    sh[t] = s3;
    __syncthreads();
    for (int off = 1; off < 256; off <<= 1) {
        int x = (t >= off) ? sh[t - off] : 0;
        __syncthreads();
        sh[t] += x;
        __syncthreads();
    }
    int prev = (t > 0) ? sh[t - 1] : 0;
    if (base     < Nn) incl[base]     = prev + s0;
    if (base + 1 < Nn) incl[base + 1] = prev + s1;
    if (base + 2 < Nn) incl[base + 2] = prev + s2;
    if (base + 3 < Nn) incl[base + 3] = prev + s3;
    if (t == 255) bsum[blockIdx.x] = sh[255];
}
__global__ void scan2_k(const int* __restrict__ bsum, int* __restrict__ bpre, int nb)
{
    int t = threadIdx.x;                // single wave, nb <= 64
    int own = (t < nb) ? bsum[t] : 0;
    int v = own;
    for (int off = 1; off < 64; off <<= 1) {
        int x = __shfl_up(v, off);
        if (t >= off) v += x;
    }
    if (t < nb) bpre[t] = v - own;      // exclusive
}
__global__ void scan3_k(const int* __restrict__ incl, const int* __restrict__ deg,
                        const int* __restrict__ bpre, int* __restrict__ offs,
                        int* __restrict__ cursor, int Nn, int Etot)
{
    int i = blockIdx.x * 256 + threadIdx.x;
    if (i < Nn) {
        int e = bpre[i >> 10] + incl[i] - deg[i];
        offs[i] = e;
        cursor[i] = e;
    }
    if (i == 0) offs[Nn] = Etot;
}
__global__ void scatter_k(const int* __restrict__ src, const int* __restrict__ dst,
                          int E, int Nn, int* cursor,
                          int* __restrict__ srcs, int* __restrict__ dsts)
{
    int i = blockIdx.x * 256 + threadIdx.x;
    if (i < E) {
        int d = dst[i];
        int p = atomicAdd(&cursor[d], 1);
        srcs[p] = src[i];
        dsts[p] = d;
    } else if (i < E + Nn) {
        int n = i - E;
        int p = atomicAdd(&cursor[n], 1);
        srcs[p] = n;                    // self loop
        dsts[p] = n;
    }
}

// ---------------- GAT layer 1 aggregate: wave per dst node ----------------
// deg<=64: per-lane weight cache (8 unrolled regs), pass-2 has zero gathers/exps.
__global__ __launch_bounds__(256) void gat1_agg_k(const ushort_t* __restrict__ H1b,
    const float* __restrict__ as1, const float* __restrict__ ad1,
    const int* __restrict__ offs, const int* __restrict__ srcs,
    const float* __restrict__ b1, ushort_t* __restrict__ X1b, int Nn)
{
    int w = (blockIdx.x << 2) + (threadIdx.x >> 6);
    if (w >= Nn) return;
    int lane = threadIdx.x & 63;
    int he = lane & 7, el = lane >> 3;
    int myh = lane >> 3;
    int beg = offs[w], end = offs[w + 1];
    int deg = end - beg;
    float adv = ad1[(w << 3) + he];
    float4 acc = {0.f, 0.f, 0.f, 0.f};

    if (deg <= 64) {
        // pass 1: 8 independent gathers+exps, cached in unrolled regs
        int sv0=0,sv1=0,sv2=0,sv3=0,sv4=0,sv5=0,sv6=0,sv7=0;
        float wv0=0,wv1=0,wv2=0,wv3=0,wv4=0,wv5=0,wv6=0,wv7=0;
        {
            int j;
            j = beg + el;      if (j < end){ sv0 = srcs[j]; wv0 = __expf(lrelu(as1[(sv0<<3)+he]+adv)); }
            j = beg + 8 + el;  if (j < end){ sv1 = srcs[j]; wv1 = __expf(lrelu(as1[(sv1<<3)+he]+adv)); }
            j = beg + 16 + el; if (j < end){ sv2 = srcs[j]; wv2 = __expf(lrelu(as1[(sv2<<3)+he]+adv)); }
            j = beg + 24 + el; if (j < end){ sv3 = srcs[j]; wv3 = __expf(lrelu(as1[(sv3<<3)+he]+adv)); }
            j = beg + 32 + el; if (j < end){ sv4 = srcs[j]; wv4 = __expf(lrelu(as1[(sv4<<3)+he]+adv)); }
            j = beg + 40 + el; if (j < end){ sv5 = srcs[j]; wv5 = __expf(lrelu(as1[(sv5<<3)+he]+adv)); }
            j = beg + 48 + el; if (j < end){ sv6 = srcs[j]; wv6 = __expf(lrelu(as1[(sv6<<3)+he]+adv)); }
            j = beg + 56 + el; if (j < end){ sv7 = srcs[j]; wv7 = __expf(lrelu(as1[(sv7<<3)+he]+adv)); }
        }
        float d = ((wv0 + wv1) + (wv2 + wv3)) + ((wv4 + wv5) + (wv6 + wv7));
        #pragma unroll
        for (int off = 8; off < 64; off <<= 1) d += __shfl_xor(d, off);
        float inv = 1.f / d;
        // normalize on the OWNING lane (he matches the exp's head) BEFORE broadcast,
        // so numerator and denominator are for the same head (R7 bug fix)
        wv0 *= inv; wv1 *= inv; wv2 *= inv; wv3 *= inv;
        wv4 *= inv; wv5 *= inv; wv6 *= inv; wv7 *= inv;

        // pass 2: per 8-edge batch, broadcast cached s/w and gather rows
        #define GAT1_BATCH(SV, WV, Q)                                            \
        {                                                                        \
            int ne = deg - (Q << 3);                                             \
            if (ne > 0) {                                                        \
                ne = min(ne, 8);                                                 \
                int sb[8]; float wb[8];                                          \
                _Pragma("unroll")                                                \
                for (int e8 = 0; e8 < 8; e8++) {                                 \
                    sb[e8] = __shfl(SV, e8 << 3);                                \
                    wb[e8] = __shfl(WV, (e8 << 3) + myh);                        \
                }                                                                \
                if (ne == 8) {                                                   \
                    _Pragma("unroll")                                            \
                    for (int e8 = 0; e8 < 8; e8++) {                             \
                        uint2 v = ((const uint2*)(H1b + ((long)sb[e8] << 8)))[lane]; \
                        acc.x += wb[e8] * bf_lo(v.x);                            \
                        acc.y += wb[e8] * bf_hi(v.x);                            \
                        acc.z += wb[e8] * bf_lo(v.y);                            \
                        acc.w += wb[e8] * bf_hi(v.y);                            \
                    }                                                            \
                } else {                                                         \
                    _Pragma("unroll")                                            \
                    for (int e8 = 0; e8 < 8; e8++) {                             \
                        if (e8 < ne) {                                           \
                            uint2 v = ((const uint2*)(H1b + ((long)sb[e8] << 8)))[lane]; \
                            acc.x += wb[e8] * bf_lo(v.x);                        \
                            acc.y += wb[e8] * bf_hi(v.x);                        \
                            acc.z += wb[e8] * bf_lo(v.y);                        \
                            acc.w += wb[e8] * bf_hi(v.y);                        \
                        }                                                        \
                    }                                                            \
                }                                                                \
            }                                                                    \
        }
        GAT1_BATCH(sv0, wv0, 0)
        GAT1_BATCH(sv1, wv1, 1)
        GAT1_BATCH(sv2, wv2, 2)
        GAT1_BATCH(sv3, wv3, 3)
        GAT1_BATCH(sv4, wv4, 4)
        GAT1_BATCH(sv5, wv5, 5)
        GAT1_BATCH(sv6, wv6, 6)
        GAT1_BATCH(sv7, wv7, 7)
        #undef GAT1_BATCH
    } else {
        // generic fallback (deg > 64): recompute weights, 8 rows in flight
        float dA = 0.f, dB = 0.f;
        for (int j0 = beg; j0 < end; j0 += 16) {
            int j = j0 + el, jb = j0 + 8 + el;
            if (j < end)  dA += __expf(lrelu(as1[(srcs[j] << 3) + he] + adv));
            if (jb < end) dB += __expf(lrelu(as1[(srcs[jb] << 3) + he] + adv));
        }
        float d = dA + dB;
        #pragma unroll
        for (int off = 8; off < 64; off <<= 1) d += __shfl_xor(d, off);
        float inv = 1.f / d;
        for (int j0 = beg; j0 < end; j0 += 8) {
            int j = j0 + el;
            int s = 0; float wv = 0.f;
            if (j < end) {
                s = srcs[j];
                wv = __expf(lrelu(as1[(s << 3) + he] + adv)) * inv;
            }
            int ne = min(end - j0, 8);
            int sb[8]; float wb[8];
            #pragma unroll
            for (int e8 = 0; e8 < 8; e8++) {
                sb[e8] = __shfl(s, e8 << 3);
                wb[e8] = __shfl(wv, (e8 << 3) + myh);
            }
            #pragma unroll
            for (int e8 = 0; e8 < 8; e8++) {
                if (e8 < ne) {
                    uint2 v = ((const uint2*)(H1b + ((long)sb[e8] << 8)))[lane];
                    acc.x += wb[e8] * bf_lo(v.x);
                    acc.y += wb[e8] * bf_hi(v.x);
                    acc.z += wb[e8] * bf_lo(v.y);
                    acc.w += wb[e8] * bf_hi(v.y);
                }
            }
        }
    }

    float4 bb = ((const float4*)b1)[lane];
    float o0 = fmaxf(acc.x + bb.x, 0.f);
    float o1 = fmaxf(acc.y + bb.y, 0.f);
    float o2 = fmaxf(acc.z + bb.z, 0.f);
    float o3 = fmaxf(acc.w + bb.w, 0.f);
    uint2 ov;
    ov.x = (uint_t)f2bf(o0) | ((uint_t)f2bf(o1) << 16);
    ov.y = (uint_t)f2bf(o2) | ((uint_t)f2bf(o3) << 16);
    ((uint2*)(X1b + ((long)w << 8)))[lane] = ov;
}

// ---------------- GEMM2 + alpha2: h2 = x1 @ W2, wave per node ----------------
__global__ __launch_bounds__(256) void gemm2_k(const ushort_t* __restrict__ X1b,
    const float* __restrict__ W2, const float* __restrict__ a2s_w,
    const float* __restrict__ a2d_w, float* __restrict__ H2,
    float* __restrict__ as2, float* __restrict__ ad2, int Nn)
{
    int w = (blockIdx.x << 2) + (threadIdx.x >> 6);
    if (w >= Nn) return;
    int lane = threadIdx.x & 63;
    int c = lane & 15, kg = lane >> 4;
    const uint2* xr = (const uint2*)(X1b + ((long)w << 8));
    float sum = 0.f;
    #pragma unroll
    for (int t = 0; t < 16; t++) {
        uint2 v = xr[(t << 2) + kg];        // channels k..k+3, k = t*16 + kg*4
        int k = (t << 4) + (kg << 2);
        sum += bf_lo(v.x) * W2[(k << 4) + c]     + bf_hi(v.x) * W2[((k+1) << 4) + c]
             + bf_lo(v.y) * W2[((k+2) << 4) + c] + bf_hi(v.y) * W2[((k+3) << 4) + c];
    }
    sum += __shfl_xor(sum, 16);
    sum += __shfl_xor(sum, 32);
    float vs = sum * a2s_w[c];
    float vd = sum * a2d_w[c];
    #pragma unroll
    for (int off = 1; off < 16; off <<= 1) {
        vs += __shfl_xor(vs, off);
        vd += __shfl_xor(vd, off);
    }
    if (kg == 0) {
        H2[(w << 4) + c] = sum;
        if (c == 0) { as2[w] = vs; ad2[w] = vd; }
    }
}

// ---------------- e2 prep: per-edge exp(lrelu(...)) , edge-parallel ----------------
__global__ __launch_bounds__(256) void e2prep_k(const float* __restrict__ as2,
    const float* __restrict__ ad2, const int* __restrict__ srcs,
    const int* __restrict__ dsts, float* __restrict__ e2x, int Etot)
{
    int i = blockIdx.x * 256 + threadIdx.x;
    if (i < Etot)
        e2x[i] = __expf(lrelu(as2[srcs[i]] + ad2[dsts[i]]));
}

// ---------------- GAT layer 2 aggregate + final softmax (streams e2x) ----------------
__global__ __launch_bounds__(256) void gat2_agg_k(const float* __restrict__ H2,
    const float* __restrict__ e2x,
    const int* __restrict__ offs, const int* __restrict__ srcs,
    const float* __restrict__ b2, float* __restrict__ out, int Nn)
{
    int w = (blockIdx.x << 2) + (threadIdx.x >> 6);
    if (w >= Nn) return;
    int lane = threadIdx.x & 63;
    int beg = offs[w], end = offs[w + 1];
    // denom: coalesced stream of e2x
    float d = 0.f;
    for (int j = beg + lane; j < end; j += 64) d += e2x[j];
    #pragma unroll
    for (int off = 1; off < 64; off <<= 1) d += __shfl_xor(d, off);
    float inv = 1.f / d;
    int c = lane & 15, eg = lane >> 4;
    float acc = 0.f;
    for (int j0 = beg; j0 < end; j0 += 4) {
        int j = j0 + eg;
        if (j < end)
            acc += e2x[j] * inv * H2[(srcs[j] << 4) + c];
    }
    acc += __shfl_xor(acc, 16);
    acc += __shfl_xor(acc, 32);
    float v = acc + b2[c];
    float mx = v;
    #pragma unroll
    for (int off = 1; off < 16; off <<= 1) mx = fmaxf(mx, __shfl_xor(mx, off));
    float ex = __expf(v - mx);
    float se = ex;
    #pragma unroll
    for (int off = 1; off < 16; off <<= 1) se += __shfl_xor(se, off);
    if (eg == 0) out[(w << 4) + c] = ex / se;
}

// ---------------- host launcher ----------------
extern "C" void kernel_launch(void* const* d_in, const int* in_sizes, int n_in,
                              void* d_out, int out_size, void* d_ws, size_t ws_size,
                              hipStream_t stream)
{
    const float* x    = (const float*)d_in[0];
    const int*   ei   = (const int*)d_in[1];
    const float* W1   = (const float*)d_in[2];
    const float* a1s  = (const float*)d_in[3];
    const float* a1d  = (const float*)d_in[4];
    const float* b1   = (const float*)d_in[5];
    const float* W2   = (const float*)d_in[6];
    const float* a2s  = (const float*)d_in[7];
    const float* a2d  = (const float*)d_in[8];
    const float* b2   = (const float*)d_in[9];
    float* out = (float*)d_out;

    int N = in_sizes[0] / HID;
    int E = in_sizes[1] / 2;
    int Etot = E + N;
    const int* src = ei;
    const int* dst = ei + E;

    char* p = (char*)d_ws;
    auto alloc = [&](size_t bytes) {
        void* r = (void*)p;
        p += (bytes + 255) & ~(size_t)255;
        return r;
    };
    ushort_t* h1b  = (ushort_t*)alloc((size_t)N * 256 * 2);
    ushort_t* x1b  = (ushort_t*)alloc((size_t)N * 256 * 2);
    ushort_t* w1t  = (ushort_t*)alloc((size_t)256 * 256 * 2);
    float* h2      = (float*)alloc((size_t)N * 16 * 4);
    float* as1     = (float*)alloc((size_t)N * 8 * 4);
    float* ad1     = (float*)alloc((size_t)N * 8 * 4);
    float* as2v    = (float*)alloc((size_t)N * 4);
    float* ad2v    = (float*)alloc((size_t)N * 4);
    int*   deg     = (int*)alloc((size_t)N * 4);
    int*   incl    = (int*)alloc((size_t)N * 4);
    int*   offs    = (int*)alloc((size_t)(N + 1) * 4);
    int*   cursor  = (int*)alloc((size_t)N * 4);
    int*   bsum    = (int*)alloc(256 * 4);
    int*   bpre    = (int*)alloc(256 * 4);
    int*   srcs    = (int*)alloc((size_t)Etot * 4);
    int*   dsts    = (int*)alloc((size_t)Etot * 4);
    float* e2x     = (float*)alloc((size_t)Etot * 4);

    int nb = (N + 1023) / 1024;

    // prep + GEMM1 (MFMA, fused alpha1)
    hipLaunchKernelGGL(w1prep_k, dim3(64), dim3(256), 0, stream, W1, w1t);
    dim3 g1(2, (N + 127) / 128);
    hipLaunchKernelGGL(gemm1_k, g1, dim3(256), 0, stream,
                       x, w1t, a1s, a1d, h1b, as1, ad1, N);
    // CSR build
    hipLaunchKernelGGL(deg_init_k, dim3((N + 255) / 256), dim3(256), 0, stream, deg, N);
    hipLaunchKernelGGL(deg_count_k, dim3((E + 255) / 256), dim3(256), 0, stream, dst, E, deg);
    hipLaunchKernelGGL(scan1_k, dim3(nb), dim3(256), 0, stream, deg, incl, bsum, N);
    hipLaunchKernelGGL(scan2_k, dim3(1), dim3(64), 0, stream, bsum, bpre, nb);
    hipLaunchKernelGGL(scan3_k, dim3((N + 255) / 256), dim3(256), 0, stream,
                       incl, deg, bpre, offs, cursor, N, Etot);
    hipLaunchKernelGGL(scatter_k, dim3((Etot + 255) / 256), dim3(256), 0, stream,
                       src, dst, E, N, cursor, srcs, dsts);
    // layer 1 aggregate
    hipLaunchKernelGGL(gat1_agg_k, dim3((N + 3) / 4), dim3(256), 0, stream,
                       h1b, as1, ad1, offs, srcs, b1, x1b, N);
    // layer 2
    hipLaunchKernelGGL(gemm2_k, dim3((N + 3) / 4), dim3(256), 0, stream,
                       x1b, W2, a2s, a2d, h2, as2v, ad2v, N);
    hipLaunchKernelGGL(e2prep_k, dim3((Etot + 255) / 256), dim3(256), 0, stream,
                       as2v, ad2v, srcs, dsts, e2x, Etot);
    hipLaunchKernelGGL(gat2_agg_k, dim3((N + 3) / 4), dim3(256), 0, stream,
                       h2, e2x, offs, srcs, b2, out, N);
}

// Round 9
// 312.749 us; speedup vs baseline: 1.2227x; 1.0107x over previous
//
#include <hip/hip_runtime.h>
#include <hip/hip_bf16.h>

#define HID 256
#define H1H 8
#define C1 32
#define C2 16
#define NEG 0.2f

typedef unsigned short ushort_t;
typedef unsigned int uint_t;
typedef __attribute__((ext_vector_type(8))) short short8;
typedef __attribute__((ext_vector_type(4))) float f32x4;

__device__ __forceinline__ float lrelu(float t){ return (t >= 0.f) ? t : NEG * t; }
__device__ __forceinline__ ushort_t f2bf(float f){
    uint_t u = __float_as_uint(f);
    u = (u + 0x7fffu + ((u >> 16) & 1u)) >> 16;   // RNE
    return (ushort_t)u;
}
__device__ __forceinline__ float bf_lo(uint_t p){ return __uint_as_float(p << 16); }
__device__ __forceinline__ float bf_hi(uint_t p){ return __uint_as_float(p & 0xffff0000u); }

#define GLOAD_LDS16(g, l) \
    __builtin_amdgcn_global_load_lds( \
        (const __attribute__((address_space(1))) void*)(g), \
        (__attribute__((address_space(3))) void*)(l), 16, 0, 0)

// ---------------- xprep: Xbf = bf16(relu(X)), streaming ----------------
__global__ __launch_bounds__(256) void xprep_k(const float* __restrict__ X,
                                               ushort_t* __restrict__ Xbf, long n4)
{
    long stride = (long)gridDim.x * 256;
    for (long i = (long)blockIdx.x * 256 + threadIdx.x; i < n4; i += stride) {
        float4 v = ((const float4*)X)[i];
        ushort4 o;
        o.x = f2bf(fmaxf(v.x, 0.f)); o.y = f2bf(fmaxf(v.y, 0.f));
        o.z = f2bf(fmaxf(v.z, 0.f)); o.w = f2bf(fmaxf(v.w, 0.f));
        ((ushort4*)Xbf)[i] = o;
    }
}

// ---------------- prep: W1t[n][k] = bf16(W1[k][n]) ----------------
__global__ __launch_bounds__(256) void w1prep_k(const float* __restrict__ W1,
                                                ushort_t* __restrict__ W1t)
{
    __shared__ ushort_t sh[32][33];
    int bx = blockIdx.x & 7, by = blockIdx.x >> 3;   // k-tile, n-tile
    int tx = threadIdx.x & 31, ty = threadIdx.x >> 5; // 32 x 8
    #pragma unroll
    for (int i = 0; i < 32; i += 8)
        sh[ty + i][tx] = f2bf(W1[(long)(bx * 32 + ty + i) * 256 + by * 32 + tx]);
    __syncthreads();
    #pragma unroll
    for (int i = 0; i < 32; i += 8)
        W1t[(long)(by * 32 + ty + i) * 256 + bx * 32 + tx] = sh[tx][ty + i];
}

// ---------------- GEMM1 (MFMA, async-staged): h1b = Xbf @ W1t^T + fused alpha1 ----------------
// 128x128 tile, BK=64, global_load_lds with XOR chunk swizzle (c ^ (row&7)).
__global__ __launch_bounds__(256) void gemm1_k(const ushort_t* __restrict__ Xbf,
                                               const ushort_t* __restrict__ W1t,
                                               const float* __restrict__ a1s_g,
                                               const float* __restrict__ a1d_g,
                                               ushort_t* __restrict__ H1b,
                                               float* __restrict__ as1,
                                               float* __restrict__ ad1, int M)
{
    __shared__ ushort_t Abuf[128 * 64];   // 16 KiB, [row][8 chunks of 8 bf16], chunk-swizzled
    __shared__ ushort_t Bbuf[128 * 64];   // 16 KiB
    int tid = threadIdx.x;
    int bm = blockIdx.y * 128, bn = blockIdx.x * 128;
    int wid = tid >> 6, lane = tid & 63;
    int wr = wid >> 1, wc = wid & 1;
    int lg = lane >> 4, lm = lane & 15;

    f32x4 acc[4][4];
    #pragma unroll
    for (int m = 0; m < 4; m++)
        #pragma unroll
        for (int n = 0; n < 4; n++) acc[m][n] = (f32x4){0.f, 0.f, 0.f, 0.f};

    // staging geometry: chunk idx = q*256 + tid; row = idx>>3, cpos = idx&7,
    // logical chunk lc = cpos ^ (row&7)  (inverse-swizzled source, linear dest)
    int r_st[4], lc_st[4];
    #pragma unroll
    for (int q = 0; q < 4; q++) {
        int idx = q * 256 + tid;
        r_st[q] = idx >> 3;
        lc_st[q] = (idx & 7) ^ (r_st[q] & 7);
    }

    for (int k0 = 0; k0 < 256; k0 += 64) {
        __syncthreads();   // previous compute done before overwrite
        #pragma unroll
        for (int q = 0; q < 4; q++) {
            const ushort_t* asrc = Xbf + (long)(bm + r_st[q]) * 256 + k0 + lc_st[q] * 8;
            GLOAD_LDS16(asrc, Abuf + (q * 256 + wid * 64) * 8);
            const ushort_t* bsrc = W1t + (long)(bn + r_st[q]) * 256 + k0 + lc_st[q] * 8;
            GLOAD_LDS16(bsrc, Bbuf + (q * 256 + wid * 64) * 8);
        }
        __syncthreads();   // compiler drains vmcnt before s_barrier
        #pragma unroll
        for (int ks = 0; ks < 2; ks++) {
            int kg = ks * 4 + lg;
            short8 af[4], bfr[4];
            #pragma unroll
            for (int m = 0; m < 4; m++) {
                int R = wr * 64 + m * 16 + lm;
                af[m] = *(const short8*)&Abuf[(R * 8 + (kg ^ (R & 7))) * 8];
            }
            #pragma unroll
            for (int n = 0; n < 4; n++) {
                int Cc = wc * 64 + n * 16 + lm;
                bfr[n] = *(const short8*)&Bbuf[(Cc * 8 + (kg ^ (Cc & 7))) * 8];
            }
            #pragma unroll
            for (int m = 0; m < 4; m++)
                #pragma unroll
                for (int n = 0; n < 4; n++)
                    acc[m][n] = __builtin_amdgcn_mfma_f32_16x16x32_bf16(af[m], bfr[n], acc[m][n], 0, 0, 0);
        }
    }

    // fused alpha1: cols for (m,r) live in heads h0 (n=0,1) and h0+1 (n=2,3)
    int h0 = ((bn >> 5) + (wc << 1));
    float as_l0 = a1s_g[h0 * 32 + lm],       as_h0 = a1s_g[h0 * 32 + 16 + lm];
    float as_l1 = a1s_g[(h0 + 1) * 32 + lm], as_h1 = a1s_g[(h0 + 1) * 32 + 16 + lm];
    float ad_l0 = a1d_g[h0 * 32 + lm],       ad_h0 = a1d_g[h0 * 32 + 16 + lm];
    float ad_l1 = a1d_g[(h0 + 1) * 32 + lm], ad_h1 = a1d_g[(h0 + 1) * 32 + 16 + lm];

    // epilogue: D[row=(lane>>4)*4+r][col=lane&15]
    #pragma unroll
    for (int m = 0; m < 4; m++) {
        #pragma unroll
        for (int r = 0; r < 4; r++) {
            int gm = bm + wr * 64 + m * 16 + lg * 4 + r;
            float s0 = acc[m][0][r] * as_l0 + acc[m][1][r] * as_h0;
            float s1 = acc[m][2][r] * as_l1 + acc[m][3][r] * as_h1;
            float d0 = acc[m][0][r] * ad_l0 + acc[m][1][r] * ad_h0;
            float d1 = acc[m][2][r] * ad_l1 + acc[m][3][r] * ad_h1;
            #pragma unroll
            for (int off = 1; off < 16; off <<= 1) {
                s0 += __shfl_xor(s0, off);
                s1 += __shfl_xor(s1, off);
                d0 += __shfl_xor(d0, off);
                d1 += __shfl_xor(d1, off);
            }
            if (gm < M) {
                long base = (long)gm * 256 + bn + wc * 64 + lm;
                #pragma unroll
                for (int n = 0; n < 4; n++)
                    H1b[base + n * 16] = f2bf(acc[m][n][r]);
                if (lm == 0) {
                    float2 sv = {s0, s1}, dv = {d0, d1};
                    *(float2*)&as1[(gm << 3) + h0] = sv;
                    *(float2*)&ad1[(gm << 3) + h0] = dv;
                }
            }
        }
    }
}

// ---------------- CSR build ----------------
__global__ void deg_init_k(int* deg, int Nn)
{
    int i = blockIdx.x * 256 + threadIdx.x;
    if (i < Nn) deg[i] = 1;  // self loop
}
__global__ void deg_count_k(const int* __restrict__ dst, int E, int* deg)
{
    int i = blockIdx.x * 256 + threadIdx.x;
    if (i < E) atomicAdd(&deg[dst[i]], 1);
}
__global__ __launch_bounds__(256) void scan1_k(const int* __restrict__ deg,
                                               int* __restrict__ incl,
                                               int* __restrict__ bsum, int Nn)
{
    __shared__ int sh[256];
    int t = threadIdx.x;
    int base = blockIdx.x * 1024 + t * 4;
    int v0 = (base     < Nn) ? deg[base]     : 0;
    int v1 = (base + 1 < Nn) ? deg[base + 1] : 0;
    int v2 = (base + 2 < Nn) ? deg[base + 2] : 0;
    int v3 = (base + 3 < Nn) ? deg[base + 3] : 0;
    int s0 = v0, s1 = s0 + v1, s2 = s1 + v2, s3 = s2 + v3;
    sh[t] = s3;
    __syncthreads();
    for (int off = 1; off < 256; off <<= 1) {
        int x = (t >= off) ? sh[t - off] : 0;
        __syncthreads();
        sh[t] += x;
        __syncthreads();
    }
    int prev = (t > 0) ? sh[t - 1] : 0;
    if (base     < Nn) incl[base]     = prev + s0;
    if (base + 1 < Nn) incl[base + 1] = prev + s1;
    if (base + 2 < Nn) incl[base + 2] = prev + s2;
    if (base + 3 < Nn) incl[base + 3] = prev + s3;
    if (t == 255) bsum[blockIdx.x] = sh[255];
}
__global__ void scan2_k(const int* __restrict__ bsum, int* __restrict__ bpre, int nb)
{
    int t = threadIdx.x;                // single wave, nb <= 64
    int own = (t < nb) ? bsum[t] : 0;
    int v = own;
    for (int off = 1; off < 64; off <<= 1) {
        int x = __shfl_up(v, off);
        if (t >= off) v += x;
    }
    if (t < nb) bpre[t] = v - own;      // exclusive
}
__global__ void scan3_k(const int* __restrict__ incl, const int* __restrict__ deg,
                        const int* __restrict__ bpre, int* __restrict__ offs,
                        int* __restrict__ cursor, int Nn, int Etot)
{
    int i = blockIdx.x * 256 + threadIdx.x;
    if (i < Nn) {
        int e = bpre[i >> 10] + incl[i] - deg[i];
        offs[i] = e;
        cursor[i] = e;
    }
    if (i == 0) offs[Nn] = Etot;
}
// writes interleaved (src,dst) pairs: one random 8B store per edge (1 line, not 2)
__global__ void scatter_k(const int* __restrict__ src, const int* __restrict__ dst,
                          int E, int Nn, int* cursor, int2* __restrict__ esd)
{
    int i = blockIdx.x * 256 + threadIdx.x;
    if (i < E) {
        int d = dst[i];
        int p = atomicAdd(&cursor[d], 1);
        int2 v; v.x = src[i]; v.y = d;
        esd[p] = v;
    } else if (i < E + Nn) {
        int n = i - E;
        int p = atomicAdd(&cursor[n], 1);
        int2 v; v.x = n; v.y = n;       // self loop
        esd[p] = v;
    }
}

// ---------------- GAT layer 1 aggregate: wave per dst node ----------------
// deg<=64: per-lane weight cache (8 unrolled regs), pass-2 has zero gathers/exps.
__global__ __launch_bounds__(256) void gat1_agg_k(const ushort_t* __restrict__ H1b,
    const float* __restrict__ as1, const float* __restrict__ ad1,
    const int* __restrict__ offs, const int2* __restrict__ esd,
    const float* __restrict__ b1, ushort_t* __restrict__ X1b, int Nn)
{
    int w = (blockIdx.x << 2) + (threadIdx.x >> 6);
    if (w >= Nn) return;
    int lane = threadIdx.x & 63;
    int he = lane & 7, el = lane >> 3;
    int myh = lane >> 3;
    int beg = offs[w], end = offs[w + 1];
    int deg = end - beg;
    float adv = ad1[(w << 3) + he];
    float4 acc = {0.f, 0.f, 0.f, 0.f};

    if (deg <= 64) {
        // pass 1: 8 independent gathers+exps, cached in unrolled regs
        int sv0=0,sv1=0,sv2=0,sv3=0,sv4=0,sv5=0,sv6=0,sv7=0;
        float wv0=0,wv1=0,wv2=0,wv3=0,wv4=0,wv5=0,wv6=0,wv7=0;
        {
            int j;
            j = beg + el;      if (j < end){ sv0 = esd[j].x; wv0 = __expf(lrelu(as1[(sv0<<3)+he]+adv)); }
            j = beg + 8 + el;  if (j < end){ sv1 = esd[j].x; wv1 = __expf(lrelu(as1[(sv1<<3)+he]+adv)); }
            j = beg + 16 + el; if (j < end){ sv2 = esd[j].x; wv2 = __expf(lrelu(as1[(sv2<<3)+he]+adv)); }
            j = beg + 24 + el; if (j < end){ sv3 = esd[j].x; wv3 = __expf(lrelu(as1[(sv3<<3)+he]+adv)); }
            j = beg + 32 + el; if (j < end){ sv4 = esd[j].x; wv4 = __expf(lrelu(as1[(sv4<<3)+he]+adv)); }
            j = beg + 40 + el; if (j < end){ sv5 = esd[j].x; wv5 = __expf(lrelu(as1[(sv5<<3)+he]+adv)); }
            j = beg + 48 + el; if (j < end){ sv6 = esd[j].x; wv6 = __expf(lrelu(as1[(sv6<<3)+he]+adv)); }
            j = beg + 56 + el; if (j < end){ sv7 = esd[j].x; wv7 = __expf(lrelu(as1[(sv7<<3)+he]+adv)); }
        }
        float d = ((wv0 + wv1) + (wv2 + wv3)) + ((wv4 + wv5) + (wv6 + wv7));
        #pragma unroll
        for (int off = 8; off < 64; off <<= 1) d += __shfl_xor(d, off);
        float inv = 1.f / d;
        // normalize on the OWNING lane BEFORE broadcast (numerator/denominator same head)
        wv0 *= inv; wv1 *= inv; wv2 *= inv; wv3 *= inv;
        wv4 *= inv; wv5 *= inv; wv6 *= inv; wv7 *= inv;

        // pass 2: per 8-edge batch, broadcast cached s/w and gather rows
        #define GAT1_BATCH(SV, WV, Q)                                            \
        {                                                                        \
            int ne = deg - (Q << 3);                                             \
            if (ne > 0) {                                                        \
                ne = min(ne, 8);                                                 \
                int sb[8]; float wb[8];                                          \
                _Pragma("unroll")                                                \
                for (int e8 = 0; e8 < 8; e8++) {                                 \
                    sb[e8] = __shfl(SV, e8 << 3);                                \
                    wb[e8] = __shfl(WV, (e8 << 3) + myh);                        \
                }                                                                \
                if (ne == 8) {                                                   \
                    _Pragma("unroll")                                            \
                    for (int e8 = 0; e8 < 8; e8++) {                             \
                        uint2 v = ((const uint2*)(H1b + ((long)sb[e8] << 8)))[lane]; \
                        acc.x += wb[e8] * bf_lo(v.x);                            \
                        acc.y += wb[e8] * bf_hi(v.x);                            \
                        acc.z += wb[e8] * bf_lo(v.y);                            \
                        acc.w += wb[e8] * bf_hi(v.y);                            \
                    }                                                            \
                } else {                                                         \
                    _Pragma("unroll")                                            \
                    for (int e8 = 0; e8 < 8; e8++) {                             \
                        if (e8 < ne) {                                           \
                            uint2 v = ((const uint2*)(H1b + ((long)sb[e8] << 8)))[lane]; \
                            acc.x += wb[e8] * bf_lo(v.x);                        \
                            acc.y += wb[e8] * bf_hi(v.x);                        \
                            acc.z += wb[e8] * bf_lo(v.y);                        \
                            acc.w += wb[e8] * bf_hi(v.y);                        \
                        }                                                        \
                    }                                                            \
                }                                                                \
            }                                                                    \
        }
        GAT1_BATCH(sv0, wv0, 0)
        GAT1_BATCH(sv1, wv1, 1)
        GAT1_BATCH(sv2, wv2, 2)
        GAT1_BATCH(sv3, wv3, 3)
        GAT1_BATCH(sv4, wv4, 4)
        GAT1_BATCH(sv5, wv5, 5)
        GAT1_BATCH(sv6, wv6, 6)
        GAT1_BATCH(sv7, wv7, 7)
        #undef GAT1_BATCH
    } else {
        // generic fallback (deg > 64): recompute weights, 8 rows in flight
        float dA = 0.f, dB = 0.f;
        for (int j0 = beg; j0 < end; j0 += 16) {
            int j = j0 + el, jb = j0 + 8 + el;
            if (j < end)  dA += __expf(lrelu(as1[(esd[j].x << 3) + he] + adv));
            if (jb < end) dB += __expf(lrelu(as1[(esd[jb].x << 3) + he] + adv));
        }
        float d = dA + dB;
        #pragma unroll
        for (int off = 8; off < 64; off <<= 1) d += __shfl_xor(d, off);
        float inv = 1.f / d;
        for (int j0 = beg; j0 < end; j0 += 8) {
            int j = j0 + el;
            int s = 0; float wv = 0.f;
            if (j < end) {
                s = esd[j].x;
                wv = __expf(lrelu(as1[(s << 3) + he] + adv)) * inv;
            }
            int ne = min(end - j0, 8);
            int sb[8]; float wb[8];
            #pragma unroll
            for (int e8 = 0; e8 < 8; e8++) {
                sb[e8] = __shfl(s, e8 << 3);
                wb[e8] = __shfl(wv, (e8 << 3) + myh);
            }
            #pragma unroll
            for (int e8 = 0; e8 < 8; e8++) {
                if (e8 < ne) {
                    uint2 v = ((const uint2*)(H1b + ((long)sb[e8] << 8)))[lane];
                    acc.x += wb[e8] * bf_lo(v.x);
                    acc.y += wb[e8] * bf_hi(v.x);
                    acc.z += wb[e8] * bf_lo(v.y);
                    acc.w += wb[e8] * bf_hi(v.y);
                }
            }
        }
    }

    float4 bb = ((const float4*)b1)[lane];
    float o0 = fmaxf(acc.x + bb.x, 0.f);
    float o1 = fmaxf(acc.y + bb.y, 0.f);
    float o2 = fmaxf(acc.z + bb.z, 0.f);
    float o3 = fmaxf(acc.w + bb.w, 0.f);
    uint2 ov;
    ov.x = (uint_t)f2bf(o0) | ((uint_t)f2bf(o1) << 16);
    ov.y = (uint_t)f2bf(o2) | ((uint_t)f2bf(o3) << 16);
    ((uint2*)(X1b + ((long)w << 8)))[lane] = ov;
}

// ---------------- GEMM2 + alpha2: h2 = x1 @ W2, wave per node ----------------
__global__ __launch_bounds__(256) void gemm2_k(const ushort_t* __restrict__ X1b,
    const float* __restrict__ W2, const float* __restrict__ a2s_w,
    const float* __restrict__ a2d_w, float* __restrict__ H2,
    float* __restrict__ as2, float* __restrict__ ad2, int Nn)
{
    int w = (blockIdx.x << 2) + (threadIdx.x >> 6);
    if (w >= Nn) return;
    int lane = threadIdx.x & 63;
    int c = lane & 15, kg = lane >> 4;
    const uint2* xr = (const uint2*)(X1b + ((long)w << 8));
    float sum = 0.f;
    #pragma unroll
    for (int t = 0; t < 16; t++) {
        uint2 v = xr[(t << 2) + kg];        // channels k..k+3, k = t*16 + kg*4
        int k = (t << 4) + (kg << 2);
        sum += bf_lo(v.x) * W2[(k << 4) + c]     + bf_hi(v.x) * W2[((k+1) << 4) + c]
             + bf_lo(v.y) * W2[((k+2) << 4) + c] + bf_hi(v.y) * W2[((k+3) << 4) + c];
    }
    sum += __shfl_xor(sum, 16);
    sum += __shfl_xor(sum, 32);
    float vs = sum * a2s_w[c];
    float vd = sum * a2d_w[c];
    #pragma unroll
    for (int off = 1; off < 16; off <<= 1) {
        vs += __shfl_xor(vs, off);
        vd += __shfl_xor(vd, off);
    }
    if (kg == 0) {
        H2[(w << 4) + c] = sum;
        if (c == 0) { as2[w] = vs; ad2[w] = vd; }
    }
}

// ---------------- e2 prep: per-edge exp(lrelu(...)) , edge-parallel ----------------
__global__ __launch_bounds__(256) void e2prep_k(const float* __restrict__ as2,
    const float* __restrict__ ad2, const int2* __restrict__ esd,
    float* __restrict__ e2x, int Etot)
{
    int i = blockIdx.x * 256 + threadIdx.x;
    if (i < Etot) {
        int2 sd = esd[i];
        e2x[i] = __expf(lrelu(as2[sd.x] + ad2[sd.y]));
    }
}

// ---------------- GAT layer 2 aggregate + final softmax (streams e2x) ----------------
__global__ __launch_bounds__(256) void gat2_agg_k(const float* __restrict__ H2,
    const float* __restrict__ e2x,
    const int* __restrict__ offs, const int2* __restrict__ esd,
    const float* __restrict__ b2, float* __restrict__ out, int Nn)
{
    int w = (blockIdx.x << 2) + (threadIdx.x >> 6);
    if (w >= Nn) return;
    int lane = threadIdx.x & 63;
    int beg = offs[w], end = offs[w + 1];
    // denom: coalesced stream of e2x
    float d = 0.f;
    for (int j = beg + lane; j < end; j += 64) d += e2x[j];
    #pragma unroll
    for (int off = 1; off < 64; off <<= 1) d += __shfl_xor(d, off);
    float inv = 1.f / d;
    int c = lane & 15, eg = lane >> 4;
    float acc = 0.f;
    for (int j0 = beg; j0 < end; j0 += 4) {
        int j = j0 + eg;
        if (j < end)
            acc += e2x[j] * inv * H2[(esd[j].x << 4) + c];
    }
    acc += __shfl_xor(acc, 16);
    acc += __shfl_xor(acc, 32);
    float v = acc + b2[c];
    float mx = v;
    #pragma unroll
    for (int off = 1; off < 16; off <<= 1) mx = fmaxf(mx, __shfl_xor(mx, off));
    float ex = __expf(v - mx);
    float se = ex;
    #pragma unroll
    for (int off = 1; off < 16; off <<= 1) se += __shfl_xor(se, off);
    if (eg == 0) out[(w << 4) + c] = ex / se;
}

// ---------------- host launcher ----------------
extern "C" void kernel_launch(void* const* d_in, const int* in_sizes, int n_in,
                              void* d_out, int out_size, void* d_ws, size_t ws_size,
                              hipStream_t stream)
{
    const float* x    = (const float*)d_in[0];
    const int*   ei   = (const int*)d_in[1];
    const float* W1   = (const float*)d_in[2];
    const float* a1s  = (const float*)d_in[3];
    const float* a1d  = (const float*)d_in[4];
    const float* b1   = (const float*)d_in[5];
    const float* W2   = (const float*)d_in[6];
    const float* a2s  = (const float*)d_in[7];
    const float* a2d  = (const float*)d_in[8];
    const float* b2   = (const float*)d_in[9];
    float* out = (float*)d_out;

    int N = in_sizes[0] / HID;
    int E = in_sizes[1] / 2;
    int Etot = E + N;
    const int* src = ei;
    const int* dst = ei + E;

    char* p = (char*)d_ws;
    auto alloc = [&](size_t bytes) {
        void* r = (void*)p;
        p += (bytes + 255) & ~(size_t)255;
        return r;
    };
    ushort_t* xbf  = (ushort_t*)alloc((size_t)N * 256 * 2);
    ushort_t* h1b  = (ushort_t*)alloc((size_t)N * 256 * 2);
    ushort_t* x1b  = (ushort_t*)alloc((size_t)N * 256 * 2);
    ushort_t* w1t  = (ushort_t*)alloc((size_t)256 * 256 * 2);
    float* h2      = (float*)alloc((size_t)N * 16 * 4);
    float* as1     = (float*)alloc((size_t)N * 8 * 4);
    float* ad1     = (float*)alloc((size_t)N * 8 * 4);
    float* as2v    = (float*)alloc((size_t)N * 4);
    float* ad2v    = (float*)alloc((size_t)N * 4);
    int*   deg     = (int*)alloc((size_t)N * 4);
    int*   incl    = (int*)alloc((size_t)N * 4);
    int*   offs    = (int*)alloc((size_t)(N + 1) * 4);
    int*   cursor  = (int*)alloc((size_t)N * 4);
    int*   bsum    = (int*)alloc(256 * 4);
    int*   bpre    = (int*)alloc(256 * 4);
    int2*  esd     = (int2*)alloc((size_t)Etot * 8);
    float* e2x     = (float*)alloc((size_t)Etot * 4);

    int nb = (N + 1023) / 1024;

    // prep passes
    hipLaunchKernelGGL(xprep_k, dim3(2048), dim3(256), 0, stream,
                       x, xbf, (long)N * 64);
    hipLaunchKernelGGL(w1prep_k, dim3(64), dim3(256), 0, stream, W1, w1t);
    // GEMM1 (MFMA, async-staged, fused alpha1)
    dim3 g1(2, (N + 127) / 128);
    hipLaunchKernelGGL(gemm1_k, g1, dim3(256), 0, stream,
                       xbf, w1t, a1s, a1d, h1b, as1, ad1, N);
    // CSR build
    hipLaunchKernelGGL(deg_init_k, dim3((N + 255) / 256), dim3(256), 0, stream, deg, N);
    hipLaunchKernelGGL(deg_count_k, dim3((E + 255) / 256), dim3(256), 0, stream, dst, E, deg);
    hipLaunchKernelGGL(scan1_k, dim3(nb), dim3(256), 0, stream, deg, incl, bsum, N);
    hipLaunchKernelGGL(scan2_k, dim3(1), dim3(64), 0, stream, bsum, bpre, nb);
    hipLaunchKernelGGL(scan3_k, dim3((N + 255) / 256), dim3(256), 0, stream,
                       incl, deg, bpre, offs, cursor, N, Etot);
    hipLaunchKernelGGL(scatter_k, dim3((Etot + 255) / 256), dim3(256), 0, stream,
                       src, dst, E, N, cursor, esd);
    // layer 1 aggregate
    hipLaunchKernelGGL(gat1_agg_k, dim3((N + 3) / 4), dim3(256), 0, stream,
                       h1b, as1, ad1, offs, esd, b1, x1b, N);
    // layer 2
    hipLaunchKernelGGL(gemm2_k, dim3((N + 3) / 4), dim3(256), 0, stream,
                       x1b, W2, a2s, a2d, h2, as2v, ad2v, N);
    hipLaunchKernelGGL(e2prep_k, dim3((Etot + 255) / 256), dim3(256), 0, stream,
                       as2v, ad2v, esd, e2x, Etot);
    hipLaunchKernelGGL(gat2_agg_k, dim3((N + 3) / 4), dim3(256), 0, stream,
                       h2, e2x, offs, esd, b2, out, N);
}

// Round 10
// 295.506 us; speedup vs baseline: 1.2940x; 1.0584x over previous
//
#include <hip/hip_runtime.h>
#include <hip/hip_bf16.h>

#define HID 256
#define H1H 8
#define C1 32
#define C2 16
#define NEG 0.2f

typedef unsigned short ushort_t;
typedef unsigned int uint_t;
typedef __attribute__((ext_vector_type(8))) short short8;
typedef __attribute__((ext_vector_type(4))) float f32x4;

__device__ __forceinline__ float lrelu(float t){ return (t >= 0.f) ? t : NEG * t; }
__device__ __forceinline__ ushort_t f2bf(float f){
    uint_t u = __float_as_uint(f);
    u = (u + 0x7fffu + ((u >> 16) & 1u)) >> 16;   // RNE
    return (ushort_t)u;
}
__device__ __forceinline__ float bf_lo(uint_t p){ return __uint_as_float(p << 16); }
__device__ __forceinline__ float bf_hi(uint_t p){ return __uint_as_float(p & 0xffff0000u); }

#define GLOAD_LDS16(g, l) \
    __builtin_amdgcn_global_load_lds( \
        (const __attribute__((address_space(1))) void*)(g), \
        (__attribute__((address_space(3))) void*)(l), 16, 0, 0)

// ---------------- prep (merged): blocks 0..63 -> W1t transpose; rest -> Xbf stream ----------------
__global__ __launch_bounds__(256) void prep_k(const float* __restrict__ X,
                                              ushort_t* __restrict__ Xbf, long n4,
                                              const float* __restrict__ W1,
                                              ushort_t* __restrict__ W1t)
{
    if (blockIdx.x < 64) {
        __shared__ ushort_t sh[32][33];
        int bx = blockIdx.x & 7, by = blockIdx.x >> 3;    // k-tile, n-tile
        int tx = threadIdx.x & 31, ty = threadIdx.x >> 5; // 32 x 8
        #pragma unroll
        for (int i = 0; i < 32; i += 8)
            sh[ty + i][tx] = f2bf(W1[(long)(bx * 32 + ty + i) * 256 + by * 32 + tx]);
        __syncthreads();
        #pragma unroll
        for (int i = 0; i < 32; i += 8)
            W1t[(long)(by * 32 + ty + i) * 256 + bx * 32 + tx] = sh[tx][ty + i];
    } else {
        long stride = (long)(gridDim.x - 64) * 256;
        for (long i = (long)(blockIdx.x - 64) * 256 + threadIdx.x; i < n4; i += stride) {
            float4 v = ((const float4*)X)[i];
            ushort4 o;
            o.x = f2bf(fmaxf(v.x, 0.f)); o.y = f2bf(fmaxf(v.y, 0.f));
            o.z = f2bf(fmaxf(v.z, 0.f)); o.w = f2bf(fmaxf(v.w, 0.f));
            ((ushort4*)Xbf)[i] = o;
        }
    }
}

// ---------------- GEMM1 (MFMA, async-staged): h1b = Xbf @ W1t^T + fused alpha1 ----------------
__global__ __launch_bounds__(256) void gemm1_k(const ushort_t* __restrict__ Xbf,
                                               const ushort_t* __restrict__ W1t,
                                               const float* __restrict__ a1s_g,
                                               const float* __restrict__ a1d_g,
                                               ushort_t* __restrict__ H1b,
                                               float* __restrict__ as1,
                                               float* __restrict__ ad1, int M)
{
    __shared__ ushort_t Abuf[128 * 64];   // 16 KiB, [row][8 chunks of 8 bf16], chunk-swizzled
    __shared__ ushort_t Bbuf[128 * 64];   // 16 KiB
    int tid = threadIdx.x;
    int bm = blockIdx.y * 128, bn = blockIdx.x * 128;
    int wid = tid >> 6, lane = tid & 63;
    int wr = wid >> 1, wc = wid & 1;
    int lg = lane >> 4, lm = lane & 15;

    f32x4 acc[4][4];
    #pragma unroll
    for (int m = 0; m < 4; m++)
        #pragma unroll
        for (int n = 0; n < 4; n++) acc[m][n] = (f32x4){0.f, 0.f, 0.f, 0.f};

    int r_st[4], lc_st[4];
    #pragma unroll
    for (int q = 0; q < 4; q++) {
        int idx = q * 256 + tid;
        r_st[q] = idx >> 3;
        lc_st[q] = (idx & 7) ^ (r_st[q] & 7);
    }

    for (int k0 = 0; k0 < 256; k0 += 64) {
        __syncthreads();
        #pragma unroll
        for (int q = 0; q < 4; q++) {
            const ushort_t* asrc = Xbf + (long)(bm + r_st[q]) * 256 + k0 + lc_st[q] * 8;
            GLOAD_LDS16(asrc, Abuf + (q * 256 + wid * 64) * 8);
            const ushort_t* bsrc = W1t + (long)(bn + r_st[q]) * 256 + k0 + lc_st[q] * 8;
            GLOAD_LDS16(bsrc, Bbuf + (q * 256 + wid * 64) * 8);
        }
        __syncthreads();
        #pragma unroll
        for (int ks = 0; ks < 2; ks++) {
            int kg = ks * 4 + lg;
            short8 af[4], bfr[4];
            #pragma unroll
            for (int m = 0; m < 4; m++) {
                int R = wr * 64 + m * 16 + lm;
                af[m] = *(const short8*)&Abuf[(R * 8 + (kg ^ (R & 7))) * 8];
            }
            #pragma unroll
            for (int n = 0; n < 4; n++) {
                int Cc = wc * 64 + n * 16 + lm;
                bfr[n] = *(const short8*)&Bbuf[(Cc * 8 + (kg ^ (Cc & 7))) * 8];
            }
            #pragma unroll
            for (int m = 0; m < 4; m++)
                #pragma unroll
                for (int n = 0; n < 4; n++)
                    acc[m][n] = __builtin_amdgcn_mfma_f32_16x16x32_bf16(af[m], bfr[n], acc[m][n], 0, 0, 0);
        }
    }

    // fused alpha1
    int h0 = ((bn >> 5) + (wc << 1));
    float as_l0 = a1s_g[h0 * 32 + lm],       as_h0 = a1s_g[h0 * 32 + 16 + lm];
    float as_l1 = a1s_g[(h0 + 1) * 32 + lm], as_h1 = a1s_g[(h0 + 1) * 32 + 16 + lm];
    float ad_l0 = a1d_g[h0 * 32 + lm],       ad_h0 = a1d_g[h0 * 32 + 16 + lm];
    float ad_l1 = a1d_g[(h0 + 1) * 32 + lm], ad_h1 = a1d_g[(h0 + 1) * 32 + 16 + lm];

    #pragma unroll
    for (int m = 0; m < 4; m++) {
        #pragma unroll
        for (int r = 0; r < 4; r++) {
            int gm = bm + wr * 64 + m * 16 + lg * 4 + r;
            float s0 = acc[m][0][r] * as_l0 + acc[m][1][r] * as_h0;
            float s1 = acc[m][2][r] * as_l1 + acc[m][3][r] * as_h1;
            float d0 = acc[m][0][r] * ad_l0 + acc[m][1][r] * ad_h0;
            float d1 = acc[m][2][r] * ad_l1 + acc[m][3][r] * ad_h1;
            #pragma unroll
            for (int off = 1; off < 16; off <<= 1) {
                s0 += __shfl_xor(s0, off);
                s1 += __shfl_xor(s1, off);
                d0 += __shfl_xor(d0, off);
                d1 += __shfl_xor(d1, off);
            }
            if (gm < M) {
                long base = (long)gm * 256 + bn + wc * 64 + lm;
                #pragma unroll
                for (int n = 0; n < 4; n++)
                    H1b[base + n * 16] = f2bf(acc[m][n][r]);
                if (lm == 0) {
                    float2 sv = {s0, s1}, dv = {d0, d1};
                    *(float2*)&as1[(gm << 3) + h0] = sv;
                    *(float2*)&ad1[(gm << 3) + h0] = dv;
                }
            }
        }
    }
}

// ---------------- CSR build ----------------
// deg pre-zeroed by hipMemsetAsync; self loops counted as the last Nn items
__global__ void deg_count_k(const int* __restrict__ dst, int E, int Etot, int* deg)
{
    int i = blockIdx.x * 256 + threadIdx.x;
    if (i < E) atomicAdd(&deg[dst[i]], 1);
    else if (i < Etot) atomicAdd(&deg[i - E], 1);
}
__global__ __launch_bounds__(256) void scan1_k(const int* __restrict__ deg,
                                               int* __restrict__ incl,
                                               int* __restrict__ bsum, int Nn)
{
    __shared__ int sh[256];
    int t = threadIdx.x;
    int base = blockIdx.x * 1024 + t * 4;
    int v0 = (base     < Nn) ? deg[base]     : 0;
    int v1 = (base + 1 < Nn) ? deg[base + 1] : 0;
    int v2 = (base + 2 < Nn) ? deg[base + 2] : 0;
    int v3 = (base + 3 < Nn) ? deg[base + 3] : 0;
    int s0 = v0, s1 = s0 + v1, s2 = s1 + v2, s3 = s2 + v3;
    sh[t] = s3;
    __syncthreads();
    for (int off = 1; off < 256; off <<= 1) {
        int x = (t >= off) ? sh[t - off] : 0;
        __syncthreads();
        sh[t] += x;
        __syncthreads();
    }
    int prev = (t > 0) ? sh[t - 1] : 0;
    if (base     < Nn) incl[base]     = prev + s0;
    if (base + 1 < Nn) incl[base + 1] = prev + s1;
    if (base + 2 < Nn) incl[base + 2] = prev + s2;
    if (base + 3 < Nn) incl[base + 3] = prev + s3;
    if (t == 255) bsum[blockIdx.x] = sh[255];
}
__global__ void scan2_k(const int* __restrict__ bsum, int* __restrict__ bpre, int nb)
{
    int t = threadIdx.x;                // single wave, nb <= 64
    int own = (t < nb) ? bsum[t] : 0;
    int v = own;
    for (int off = 1; off < 64; off <<= 1) {
        int x = __shfl_up(v, off);
        if (t >= off) v += x;
    }
    if (t < nb) bpre[t] = v - own;      // exclusive
}
__global__ void scan3_k(const int* __restrict__ incl, const int* __restrict__ deg,
                        const int* __restrict__ bpre, int* __restrict__ offs,
                        int* __restrict__ cursor, int Nn, int Etot)
{
    int i = blockIdx.x * 256 + threadIdx.x;
    if (i < Nn) {
        int e = bpre[i >> 10] + incl[i] - deg[i];
        offs[i] = e;
        cursor[i] = e;
    }
    if (i == 0) offs[Nn] = Etot;
}
__global__ void scatter_k(const int* __restrict__ src, const int* __restrict__ dst,
                          int E, int Nn, int* cursor, int2* __restrict__ esd)
{
    int i = blockIdx.x * 256 + threadIdx.x;
    if (i < E) {
        int d = dst[i];
        int p = atomicAdd(&cursor[d], 1);
        int2 v; v.x = src[i]; v.y = d;
        esd[p] = v;
    } else if (i < E + Nn) {
        int n = i - E;
        int p = atomicAdd(&cursor[n], 1);
        int2 v; v.x = n; v.y = n;       // self loop
        esd[p] = v;
    }
}

// ---------------- GAT layer 1 aggregate: wave per dst node ----------------
__global__ __launch_bounds__(256) void gat1_agg_k(const ushort_t* __restrict__ H1b,
    const float* __restrict__ as1, const float* __restrict__ ad1,
    const int* __restrict__ offs, const int2* __restrict__ esd,
    const float* __restrict__ b1, ushort_t* __restrict__ X1b, int Nn)
{
    int w = (blockIdx.x << 2) + (threadIdx.x >> 6);
    if (w >= Nn) return;
    int lane = threadIdx.x & 63;
    int he = lane & 7, el = lane >> 3;
    int myh = lane >> 3;
    int beg = offs[w], end = offs[w + 1];
    int deg = end - beg;
    float adv = ad1[(w << 3) + he];
    float4 acc = {0.f, 0.f, 0.f, 0.f};

    if (deg <= 64) {
        int sv0=0,sv1=0,sv2=0,sv3=0,sv4=0,sv5=0,sv6=0,sv7=0;
        float wv0=0,wv1=0,wv2=0,wv3=0,wv4=0,wv5=0,wv6=0,wv7=0;
        {
            int j;
            j = beg + el;      if (j < end){ sv0 = esd[j].x; wv0 = __expf(lrelu(as1[(sv0<<3)+he]+adv)); }
            j = beg + 8 + el;  if (j < end){ sv1 = esd[j].x; wv1 = __expf(lrelu(as1[(sv1<<3)+he]+adv)); }
            j = beg + 16 + el; if (j < end){ sv2 = esd[j].x; wv2 = __expf(lrelu(as1[(sv2<<3)+he]+adv)); }
            j = beg + 24 + el; if (j < end){ sv3 = esd[j].x; wv3 = __expf(lrelu(as1[(sv3<<3)+he]+adv)); }
            j = beg + 32 + el; if (j < end){ sv4 = esd[j].x; wv4 = __expf(lrelu(as1[(sv4<<3)+he]+adv)); }
            j = beg + 40 + el; if (j < end){ sv5 = esd[j].x; wv5 = __expf(lrelu(as1[(sv5<<3)+he]+adv)); }
            j = beg + 48 + el; if (j < end){ sv6 = esd[j].x; wv6 = __expf(lrelu(as1[(sv6<<3)+he]+adv)); }
            j = beg + 56 + el; if (j < end){ sv7 = esd[j].x; wv7 = __expf(lrelu(as1[(sv7<<3)+he]+adv)); }
        }
        float d = ((wv0 + wv1) + (wv2 + wv3)) + ((wv4 + wv5) + (wv6 + wv7));
        #pragma unroll
        for (int off = 8; off < 64; off <<= 1) d += __shfl_xor(d, off);
        float inv = 1.f / d;
        wv0 *= inv; wv1 *= inv; wv2 *= inv; wv3 *= inv;
        wv4 *= inv; wv5 *= inv; wv6 *= inv; wv7 *= inv;

        #define GAT1_BATCH(SV, WV, Q)                                            \
        {                                                                        \
            int ne = deg - (Q << 3);                                             \
            if (ne > 0) {                                                        \
                ne = min(ne, 8);                                                 \
                int sb[8]; float wb[8];                                          \
                _Pragma("unroll")                                                \
                for (int e8 = 0; e8 < 8; e8++) {                                 \
                    sb[e8] = __shfl(SV, e8 << 3);                                \
                    wb[e8] = __shfl(WV, (e8 << 3) + myh);                        \
                }                                                                \
                if (ne == 8) {                                                   \
                    _Pragma("unroll")                                            \
                    for (int e8 = 0; e8 < 8; e8++) {                             \
                        uint2 v = ((const uint2*)(H1b + ((long)sb[e8] << 8)))[lane]; \
                        acc.x += wb[e8] * bf_lo(v.x);                            \
                        acc.y += wb[e8] * bf_hi(v.x);                            \
                        acc.z += wb[e8] * bf_lo(v.y);                            \
                        acc.w += wb[e8] * bf_hi(v.y);                            \
                    }                                                            \
                } else {                                                         \
                    _Pragma("unroll")                                            \
                    for (int e8 = 0; e8 < 8; e8++) {                             \
                        if (e8 < ne) {                                           \
                            uint2 v = ((const uint2*)(H1b + ((long)sb[e8] << 8)))[lane]; \
                            acc.x += wb[e8] * bf_lo(v.x);                        \
                            acc.y += wb[e8] * bf_hi(v.x);                        \
                            acc.z += wb[e8] * bf_lo(v.y);                        \
                            acc.w += wb[e8] * bf_hi(v.y);                        \
                        }                                                        \
                    }                                                            \
                }                                                                \
            }                                                                    \
        }
        GAT1_BATCH(sv0, wv0, 0)
        GAT1_BATCH(sv1, wv1, 1)
        GAT1_BATCH(sv2, wv2, 2)
        GAT1_BATCH(sv3, wv3, 3)
        GAT1_BATCH(sv4, wv4, 4)
        GAT1_BATCH(sv5, wv5, 5)
        GAT1_BATCH(sv6, wv6, 6)
        GAT1_BATCH(sv7, wv7, 7)
        #undef GAT1_BATCH
    } else {
        float dA = 0.f, dB = 0.f;
        for (int j0 = beg; j0 < end; j0 += 16) {
            int j = j0 + el, jb = j0 + 8 + el;
            if (j < end)  dA += __expf(lrelu(as1[(esd[j].x << 3) + he] + adv));
            if (jb < end) dB += __expf(lrelu(as1[(esd[jb].x << 3) + he] + adv));
        }
        float d = dA + dB;
        #pragma unroll
        for (int off = 8; off < 64; off <<= 1) d += __shfl_xor(d, off);
        float inv = 1.f / d;
        for (int j0 = beg; j0 < end; j0 += 8) {
            int j = j0 + el;
            int s = 0; float wv = 0.f;
            if (j < end) {
                s = esd[j].x;
                wv = __expf(lrelu(as1[(s << 3) + he] + adv)) * inv;
            }
            int ne = min(end - j0, 8);
            int sb[8]; float wb[8];
            #pragma unroll
            for (int e8 = 0; e8 < 8; e8++) {
                sb[e8] = __shfl(s, e8 << 3);
                wb[e8] = __shfl(wv, (e8 << 3) + myh);
            }
            #pragma unroll
            for (int e8 = 0; e8 < 8; e8++) {
                if (e8 < ne) {
                    uint2 v = ((const uint2*)(H1b + ((long)sb[e8] << 8)))[lane];
                    acc.x += wb[e8] * bf_lo(v.x);
                    acc.y += wb[e8] * bf_hi(v.x);
                    acc.z += wb[e8] * bf_lo(v.y);
                    acc.w += wb[e8] * bf_hi(v.y);
                }
            }
        }
    }

    float4 bb = ((const float4*)b1)[lane];
    float o0 = fmaxf(acc.x + bb.x, 0.f);
    float o1 = fmaxf(acc.y + bb.y, 0.f);
    float o2 = fmaxf(acc.z + bb.z, 0.f);
    float o3 = fmaxf(acc.w + bb.w, 0.f);
    uint2 ov;
    ov.x = (uint_t)f2bf(o0) | ((uint_t)f2bf(o1) << 16);
    ov.y = (uint_t)f2bf(o2) | ((uint_t)f2bf(o3) << 16);
    ((uint2*)(X1b + ((long)w << 8)))[lane] = ov;
}

// ---------------- GEMM2 + alpha2: h2 = x1 @ W2, wave per node ----------------
__global__ __launch_bounds__(256) void gemm2_k(const ushort_t* __restrict__ X1b,
    const float* __restrict__ W2, const float* __restrict__ a2s_w,
    const float* __restrict__ a2d_w, float* __restrict__ H2,
    float* __restrict__ as2, float* __restrict__ ad2, int Nn)
{
    int w = (blockIdx.x << 2) + (threadIdx.x >> 6);
    if (w >= Nn) return;
    int lane = threadIdx.x & 63;
    int c = lane & 15, kg = lane >> 4;
    const uint2* xr = (const uint2*)(X1b + ((long)w << 8));
    float sum = 0.f;
    #pragma unroll
    for (int t = 0; t < 16; t++) {
        uint2 v = xr[(t << 2) + kg];
        int k = (t << 4) + (kg << 2);
        sum += bf_lo(v.x) * W2[(k << 4) + c]     + bf_hi(v.x) * W2[((k+1) << 4) + c]
             + bf_lo(v.y) * W2[((k+2) << 4) + c] + bf_hi(v.y) * W2[((k+3) << 4) + c];
    }
    sum += __shfl_xor(sum, 16);
    sum += __shfl_xor(sum, 32);
    float vs = sum * a2s_w[c];
    float vd = sum * a2d_w[c];
    #pragma unroll
    for (int off = 1; off < 16; off <<= 1) {
        vs += __shfl_xor(vs, off);
        vd += __shfl_xor(vd, off);
    }
    if (kg == 0) {
        H2[(w << 4) + c] = sum;
        if (c == 0) { as2[w] = vs; ad2[w] = vd; }
    }
}

// ---------------- GAT layer 2 aggregate + final softmax (fused e2, recompute) ----------------
__global__ __launch_bounds__(256) void gat2_agg_k(const float* __restrict__ H2,
    const float* __restrict__ as2, const float* __restrict__ ad2,
    const int* __restrict__ offs, const int2* __restrict__ esd,
    const float* __restrict__ b2, float* __restrict__ out, int Nn)
{
    int w = (blockIdx.x << 2) + (threadIdx.x >> 6);
    if (w >= Nn) return;
    int lane = threadIdx.x & 63;
    int beg = offs[w], end = offs[w + 1];
    float adv = ad2[w];                     // wave-constant dst term
    // pass 1: denom (as2 table is 200KB, L2-resident; logits bounded, no max shift)
    float d = 0.f;
    for (int j = beg + lane; j < end; j += 64)
        d += __expf(lrelu(as2[esd[j].x] + adv));
    #pragma unroll
    for (int off = 1; off < 64; off <<= 1) d += __shfl_xor(d, off);
    float inv = 1.f / d;
    // pass 2: weighted H2 gather (weights recomputed; 16 lanes share each edge)
    int c = lane & 15, eg = lane >> 4;
    float acc = 0.f;
    for (int j0 = beg; j0 < end; j0 += 4) {
        int j = j0 + eg;
        if (j < end) {
            int s = esd[j].x;
            float wv = __expf(lrelu(as2[s] + adv)) * inv;
            acc += wv * H2[(s << 4) + c];
        }
    }
    acc += __shfl_xor(acc, 16);
    acc += __shfl_xor(acc, 32);
    float v = acc + b2[c];
    float mx = v;
    #pragma unroll
    for (int off = 1; off < 16; off <<= 1) mx = fmaxf(mx, __shfl_xor(mx, off));
    float ex = __expf(v - mx);
    float se = ex;
    #pragma unroll
    for (int off = 1; off < 16; off <<= 1) se += __shfl_xor(se, off);
    if (eg == 0) out[(w << 4) + c] = ex / se;
}

// ---------------- host launcher ----------------
extern "C" void kernel_launch(void* const* d_in, const int* in_sizes, int n_in,
                              void* d_out, int out_size, void* d_ws, size_t ws_size,
                              hipStream_t stream)
{
    const float* x    = (const float*)d_in[0];
    const int*   ei   = (const int*)d_in[1];
    const float* W1   = (const float*)d_in[2];
    const float* a1s  = (const float*)d_in[3];
    const float* a1d  = (const float*)d_in[4];
    const float* b1   = (const float*)d_in[5];
    const float* W2   = (const float*)d_in[6];
    const float* a2s  = (const float*)d_in[7];
    const float* a2d  = (const float*)d_in[8];
    const float* b2   = (const float*)d_in[9];
    float* out = (float*)d_out;

    int N = in_sizes[0] / HID;
    int E = in_sizes[1] / 2;
    int Etot = E + N;
    const int* src = ei;
    const int* dst = ei + E;

    char* p = (char*)d_ws;
    auto alloc = [&](size_t bytes) {
        void* r = (void*)p;
        p += (bytes + 255) & ~(size_t)255;
        return r;
    };
    ushort_t* xbf  = (ushort_t*)alloc((size_t)N * 256 * 2);
    ushort_t* h1b  = (ushort_t*)alloc((size_t)N * 256 * 2);
    ushort_t* x1b  = (ushort_t*)alloc((size_t)N * 256 * 2);
    ushort_t* w1t  = (ushort_t*)alloc((size_t)256 * 256 * 2);
    float* h2      = (float*)alloc((size_t)N * 16 * 4);
    float* as1     = (float*)alloc((size_t)N * 8 * 4);
    float* ad1     = (float*)alloc((size_t)N * 8 * 4);
    float* as2v    = (float*)alloc((size_t)N * 4);
    float* ad2v    = (float*)alloc((size_t)N * 4);
    int*   deg     = (int*)alloc((size_t)N * 4);
    int*   incl    = (int*)alloc((size_t)N * 4);
    int*   offs    = (int*)alloc((size_t)(N + 1) * 4);
    int*   cursor  = (int*)alloc((size_t)N * 4);
    int*   bsum    = (int*)alloc(256 * 4);
    int*   bpre    = (int*)alloc(256 * 4);
    int2*  esd     = (int2*)alloc((size_t)Etot * 8);

    int nb = (N + 1023) / 1024;

    // prep (merged W1t + Xbf)
    hipLaunchKernelGGL(prep_k, dim3(2048 + 64), dim3(256), 0, stream,
                       x, xbf, (long)N * 64, W1, w1t);
    // GEMM1 (MFMA, async-staged, fused alpha1)
    dim3 g1(2, (N + 127) / 128);
    hipLaunchKernelGGL(gemm1_k, g1, dim3(256), 0, stream,
                       xbf, w1t, a1s, a1d, h1b, as1, ad1, N);
    // CSR build (deg via memset + unified count incl. self loops)
    hipMemsetAsync(deg, 0, (size_t)N * 4, stream);
    hipLaunchKernelGGL(deg_count_k, dim3((Etot + 255) / 256), dim3(256), 0, stream,
                       dst, E, Etot, deg);
    hipLaunchKernelGGL(scan1_k, dim3(nb), dim3(256), 0, stream, deg, incl, bsum, N);
    hipLaunchKernelGGL(scan2_k, dim3(1), dim3(64), 0, stream, bsum, bpre, nb);
    hipLaunchKernelGGL(scan3_k, dim3((N + 255) / 256), dim3(256), 0, stream,
                       incl, deg, bpre, offs, cursor, N, Etot);
    hipLaunchKernelGGL(scatter_k, dim3((Etot + 255) / 256), dim3(256), 0, stream,
                       src, dst, E, N, cursor, esd);
    // layer 1 aggregate
    hipLaunchKernelGGL(gat1_agg_k, dim3((N + 3) / 4), dim3(256), 0, stream,
                       h1b, as1, ad1, offs, esd, b1, x1b, N);
    // layer 2
    hipLaunchKernelGGL(gemm2_k, dim3((N + 3) / 4), dim3(256), 0, stream,
                       x1b, W2, a2s, a2d, h2, as2v, ad2v, N);
    hipLaunchKernelGGL(gat2_agg_k, dim3((N + 3) / 4), dim3(256), 0, stream,
                       h2, as2v, ad2v, offs, esd, b2, out, N);
}

// Round 11
// 251.411 us; speedup vs baseline: 1.5210x; 1.1754x over previous
//
#include <hip/hip_runtime.h>
#include <hip/hip_bf16.h>

#define HID 256
#define H1H 8
#define C1 32
#define C2 16
#define NEG 0.2f

typedef unsigned short ushort_t;
typedef unsigned int uint_t;
typedef __attribute__((ext_vector_type(8))) short short8;
typedef __attribute__((ext_vector_type(4))) float f32x4;

__device__ __forceinline__ float lrelu(float t){ return (t >= 0.f) ? t : NEG * t; }
__device__ __forceinline__ ushort_t f2bf(float f){
    uint_t u = __float_as_uint(f);
    u = (u + 0x7fffu + ((u >> 16) & 1u)) >> 16;   // RNE
    return (ushort_t)u;
}
__device__ __forceinline__ float bf_lo(uint_t p){ return __uint_as_float(p << 16); }
__device__ __forceinline__ float bf_hi(uint_t p){ return __uint_as_float(p & 0xffff0000u); }

#define GLOAD_LDS16(g, l) \
    __builtin_amdgcn_global_load_lds( \
        (const __attribute__((address_space(1))) void*)(g), \
        (__attribute__((address_space(3))) void*)(l), 16, 0, 0)

// ---------------- prep (merged): W1t transpose | W2t bf16 transpose | Xbf stream | deg_count ----
// deg must be zeroed (hipMemsetAsync) BEFORE this kernel.
__global__ __launch_bounds__(256) void prep_k(const float* __restrict__ X,
                                              ushort_t* __restrict__ Xbf, long n4,
                                              const float* __restrict__ W1,
                                              ushort_t* __restrict__ W1t,
                                              const float* __restrict__ W2,
                                              ushort_t* __restrict__ W2t,
                                              const int* __restrict__ dst,
                                              int E, int Etot, int* __restrict__ deg)
{
    int bid = blockIdx.x;
    if (bid < 64) {
        __shared__ ushort_t sh[32][33];
        int bx = bid & 7, by = bid >> 3;                  // k-tile, n-tile
        int tx = threadIdx.x & 31, ty = threadIdx.x >> 5; // 32 x 8
        #pragma unroll
        for (int i = 0; i < 32; i += 8)
            sh[ty + i][tx] = f2bf(W1[(long)(bx * 32 + ty + i) * 256 + by * 32 + tx]);
        __syncthreads();
        #pragma unroll
        for (int i = 0; i < 32; i += 8)
            W1t[(long)(by * 32 + ty + i) * 256 + bx * 32 + tx] = sh[tx][ty + i];
    } else if (bid == 64) {
        // W2t[c][k] = bf16(W2[k][c]); 4096 elems
        for (int idx = threadIdx.x; idx < 4096; idx += 256) {
            int k = idx >> 4, c = idx & 15;
            W2t[c * 256 + k] = f2bf(W2[idx]);
        }
    } else if (bid < 65 + 2048) {
        long stride = (long)2048 * 256;
        for (long i = (long)(bid - 65) * 256 + threadIdx.x; i < n4; i += stride) {
            float4 v = ((const float4*)X)[i];
            ushort4 o;
            o.x = f2bf(fmaxf(v.x, 0.f)); o.y = f2bf(fmaxf(v.y, 0.f));
            o.z = f2bf(fmaxf(v.z, 0.f)); o.w = f2bf(fmaxf(v.w, 0.f));
            ((ushort4*)Xbf)[i] = o;
        }
    } else {
        int i = (bid - 65 - 2048) * 256 + threadIdx.x;
        if (i < E) atomicAdd(&deg[dst[i]], 1);
        else if (i < Etot) atomicAdd(&deg[i - E], 1);   // self loops
    }
}

// ---------------- GEMM1 (MFMA, async-staged): h1b = Xbf @ W1t^T + fused alpha1 ----------------
__global__ __launch_bounds__(256) void gemm1_k(const ushort_t* __restrict__ Xbf,
                                               const ushort_t* __restrict__ W1t,
                                               const float* __restrict__ a1s_g,
                                               const float* __restrict__ a1d_g,
                                               ushort_t* __restrict__ H1b,
                                               float* __restrict__ as1,
                                               float* __restrict__ ad1, int M)
{
    __shared__ ushort_t Abuf[128 * 64];   // 16 KiB, chunk-swizzled
    __shared__ ushort_t Bbuf[128 * 64];   // 16 KiB
    int tid = threadIdx.x;
    int bm = blockIdx.y * 128, bn = blockIdx.x * 128;
    int wid = tid >> 6, lane = tid & 63;
    int wr = wid >> 1, wc = wid & 1;
    int lg = lane >> 4, lm = lane & 15;

    f32x4 acc[4][4];
    #pragma unroll
    for (int m = 0; m < 4; m++)
        #pragma unroll
        for (int n = 0; n < 4; n++) acc[m][n] = (f32x4){0.f, 0.f, 0.f, 0.f};

    int r_st[4], lc_st[4];
    #pragma unroll
    for (int q = 0; q < 4; q++) {
        int idx = q * 256 + tid;
        r_st[q] = idx >> 3;
        lc_st[q] = (idx & 7) ^ (r_st[q] & 7);
    }

    for (int k0 = 0; k0 < 256; k0 += 64) {
        __syncthreads();
        #pragma unroll
        for (int q = 0; q < 4; q++) {
            const ushort_t* asrc = Xbf + (long)(bm + r_st[q]) * 256 + k0 + lc_st[q] * 8;
            GLOAD_LDS16(asrc, Abuf + (q * 256 + wid * 64) * 8);
            const ushort_t* bsrc = W1t + (long)(bn + r_st[q]) * 256 + k0 + lc_st[q] * 8;
            GLOAD_LDS16(bsrc, Bbuf + (q * 256 + wid * 64) * 8);
        }
        __syncthreads();
        #pragma unroll
        for (int ks = 0; ks < 2; ks++) {
            int kg = ks * 4 + lg;
            short8 af[4], bfr[4];
            #pragma unroll
            for (int m = 0; m < 4; m++) {
                int R = wr * 64 + m * 16 + lm;
                af[m] = *(const short8*)&Abuf[(R * 8 + (kg ^ (R & 7))) * 8];
            }
            #pragma unroll
            for (int n = 0; n < 4; n++) {
                int Cc = wc * 64 + n * 16 + lm;
                bfr[n] = *(const short8*)&Bbuf[(Cc * 8 + (kg ^ (Cc & 7))) * 8];
            }
            #pragma unroll
            for (int m = 0; m < 4; m++)
                #pragma unroll
                for (int n = 0; n < 4; n++)
                    acc[m][n] = __builtin_amdgcn_mfma_f32_16x16x32_bf16(af[m], bfr[n], acc[m][n], 0, 0, 0);
        }
    }

    // fused alpha1
    int h0 = ((bn >> 5) + (wc << 1));
    float as_l0 = a1s_g[h0 * 32 + lm],       as_h0 = a1s_g[h0 * 32 + 16 + lm];
    float as_l1 = a1s_g[(h0 + 1) * 32 + lm], as_h1 = a1s_g[(h0 + 1) * 32 + 16 + lm];
    float ad_l0 = a1d_g[h0 * 32 + lm],       ad_h0 = a1d_g[h0 * 32 + 16 + lm];
    float ad_l1 = a1d_g[(h0 + 1) * 32 + lm], ad_h1 = a1d_g[(h0 + 1) * 32 + 16 + lm];

    #pragma unroll
    for (int m = 0; m < 4; m++) {
        #pragma unroll
        for (int r = 0; r < 4; r++) {
            int gm = bm + wr * 64 + m * 16 + lg * 4 + r;
            float s0 = acc[m][0][r] * as_l0 + acc[m][1][r] * as_h0;
            float s1 = acc[m][2][r] * as_l1 + acc[m][3][r] * as_h1;
            float d0 = acc[m][0][r] * ad_l0 + acc[m][1][r] * ad_h0;
            float d1 = acc[m][2][r] * ad_l1 + acc[m][3][r] * ad_h1;
            #pragma unroll
            for (int off = 1; off < 16; off <<= 1) {
                s0 += __shfl_xor(s0, off);
                s1 += __shfl_xor(s1, off);
                d0 += __shfl_xor(d0, off);
                d1 += __shfl_xor(d1, off);
            }
            if (gm < M) {
                long base = (long)gm * 256 + bn + wc * 64 + lm;
                #pragma unroll
                for (int n = 0; n < 4; n++)
                    H1b[base + n * 16] = f2bf(acc[m][n][r]);
                if (lm == 0) {
                    float2 sv = {s0, s1}, dv = {d0, d1};
                    *(float2*)&as1[(gm << 3) + h0] = sv;
                    *(float2*)&ad1[(gm << 3) + h0] = dv;
                }
            }
        }
    }
}

// ---------------- CSR scans / scatter ----------------
__global__ __launch_bounds__(256) void scan1_k(const int* __restrict__ deg,
                                               int* __restrict__ incl,
                                               int* __restrict__ bsum, int Nn)
{
    __shared__ int sh[256];
    int t = threadIdx.x;
    int base = blockIdx.x * 1024 + t * 4;
    int v0 = (base     < Nn) ? deg[base]     : 0;
    int v1 = (base + 1 < Nn) ? deg[base + 1] : 0;
    int v2 = (base + 2 < Nn) ? deg[base + 2] : 0;
    int v3 = (base + 3 < Nn) ? deg[base + 3] : 0;
    int s0 = v0, s1 = s0 + v1, s2 = s1 + v2, s3 = s2 + v3;
    sh[t] = s3;
    __syncthreads();
    for (int off = 1; off < 256; off <<= 1) {
        int x = (t >= off) ? sh[t - off] : 0;
        __syncthreads();
        sh[t] += x;
        __syncthreads();
    }
    int prev = (t > 0) ? sh[t - 1] : 0;
    if (base     < Nn) incl[base]     = prev + s0;
    if (base + 1 < Nn) incl[base + 1] = prev + s1;
    if (base + 2 < Nn) incl[base + 2] = prev + s2;
    if (base + 3 < Nn) incl[base + 3] = prev + s3;
    if (t == 255) bsum[blockIdx.x] = sh[255];
}
__global__ void scan2_k(const int* __restrict__ bsum, int* __restrict__ bpre, int nb)
{
    int t = threadIdx.x;                // single wave, nb <= 64
    int own = (t < nb) ? bsum[t] : 0;
    int v = own;
    for (int off = 1; off < 64; off <<= 1) {
        int x = __shfl_up(v, off);
        if (t >= off) v += x;
    }
    if (t < nb) bpre[t] = v - own;      // exclusive
}
__global__ void scan3_k(const int* __restrict__ incl, const int* __restrict__ deg,
                        const int* __restrict__ bpre, int* __restrict__ offs,
                        int* __restrict__ cursor, int Nn, int Etot)
{
    int i = blockIdx.x * 256 + threadIdx.x;
    if (i < Nn) {
        int e = bpre[i >> 10] + incl[i] - deg[i];
        offs[i] = e;
        cursor[i] = e;
    }
    if (i == 0) offs[Nn] = Etot;
}
__global__ void scatter_k(const int* __restrict__ src, const int* __restrict__ dst,
                          int E, int Nn, int* cursor, int2* __restrict__ esd)
{
    int i = blockIdx.x * 256 + threadIdx.x;
    if (i < E) {
        int d = dst[i];
        int p = atomicAdd(&cursor[d], 1);
        int2 v; v.x = src[i]; v.y = d;
        esd[p] = v;
    } else if (i < E + Nn) {
        int n = i - E;
        int p = atomicAdd(&cursor[n], 1);
        int2 v; v.x = n; v.y = n;       // self loop
        esd[p] = v;
    }
}

// ---------------- GAT layer 1 aggregate: wave per dst node ----------------
__global__ __launch_bounds__(256) void gat1_agg_k(const ushort_t* __restrict__ H1b,
    const float* __restrict__ as1, const float* __restrict__ ad1,
    const int* __restrict__ offs, const int2* __restrict__ esd,
    const float* __restrict__ b1, ushort_t* __restrict__ X1b, int Nn)
{
    int w = (blockIdx.x << 2) + (threadIdx.x >> 6);
    if (w >= Nn) return;
    int lane = threadIdx.x & 63;
    int he = lane & 7, el = lane >> 3;
    int myh = lane >> 3;
    int beg = offs[w], end = offs[w + 1];
    int deg = end - beg;
    float adv = ad1[(w << 3) + he];
    float4 acc = {0.f, 0.f, 0.f, 0.f};

    if (deg <= 64) {
        int sv0=0,sv1=0,sv2=0,sv3=0,sv4=0,sv5=0,sv6=0,sv7=0;
        float wv0=0,wv1=0,wv2=0,wv3=0,wv4=0,wv5=0,wv6=0,wv7=0;
        {
            int j;
            j = beg + el;      if (j < end){ sv0 = esd[j].x; wv0 = __expf(lrelu(as1[(sv0<<3)+he]+adv)); }
            j = beg + 8 + el;  if (j < end){ sv1 = esd[j].x; wv1 = __expf(lrelu(as1[(sv1<<3)+he]+adv)); }
            j = beg + 16 + el; if (j < end){ sv2 = esd[j].x; wv2 = __expf(lrelu(as1[(sv2<<3)+he]+adv)); }
            j = beg + 24 + el; if (j < end){ sv3 = esd[j].x; wv3 = __expf(lrelu(as1[(sv3<<3)+he]+adv)); }
            j = beg + 32 + el; if (j < end){ sv4 = esd[j].x; wv4 = __expf(lrelu(as1[(sv4<<3)+he]+adv)); }
            j = beg + 40 + el; if (j < end){ sv5 = esd[j].x; wv5 = __expf(lrelu(as1[(sv5<<3)+he]+adv)); }
            j = beg + 48 + el; if (j < end){ sv6 = esd[j].x; wv6 = __expf(lrelu(as1[(sv6<<3)+he]+adv)); }
            j = beg + 56 + el; if (j < end){ sv7 = esd[j].x; wv7 = __expf(lrelu(as1[(sv7<<3)+he]+adv)); }
        }
        float d = ((wv0 + wv1) + (wv2 + wv3)) + ((wv4 + wv5) + (wv6 + wv7));
        #pragma unroll
        for (int off = 8; off < 64; off <<= 1) d += __shfl_xor(d, off);
        float inv = 1.f / d;
        wv0 *= inv; wv1 *= inv; wv2 *= inv; wv3 *= inv;
        wv4 *= inv; wv5 *= inv; wv6 *= inv; wv7 *= inv;

        #define GAT1_BATCH(SV, WV, Q)                                            \
        {                                                                        \
            int ne = deg - (Q << 3);                                             \
            if (ne > 0) {                                                        \
                ne = min(ne, 8);                                                 \
                int sb[8]; float wb[8];                                          \
                _Pragma("unroll")                                                \
                for (int e8 = 0; e8 < 8; e8++) {                                 \
                    sb[e8] = __shfl(SV, e8 << 3);                                \
                    wb[e8] = __shfl(WV, (e8 << 3) + myh);                        \
                }                                                                \
                if (ne == 8) {                                                   \
                    _Pragma("unroll")                                            \
                    for (int e8 = 0; e8 < 8; e8++) {                             \
                        uint2 v = ((const uint2*)(H1b + ((long)sb[e8] << 8)))[lane]; \
                        acc.x += wb[e8] * bf_lo(v.x);                            \
                        acc.y += wb[e8] * bf_hi(v.x);                            \
                        acc.z += wb[e8] * bf_lo(v.y);                            \
                        acc.w += wb[e8] * bf_hi(v.y);                            \
                    }                                                            \
                } else {                                                         \
                    _Pragma("unroll")                                            \
                    for (int e8 = 0; e8 < 8; e8++) {                             \
                        if (e8 < ne) {                                           \
                            uint2 v = ((const uint2*)(H1b + ((long)sb[e8] << 8)))[lane]; \
                            acc.x += wb[e8] * bf_lo(v.x);                        \
                            acc.y += wb[e8] * bf_hi(v.x);                        \
                            acc.z += wb[e8] * bf_lo(v.y);                        \
                            acc.w += wb[e8] * bf_hi(v.y);                        \
                        }                                                        \
                    }                                                            \
                }                                                                \
            }                                                                    \
        }
        GAT1_BATCH(sv0, wv0, 0)
        GAT1_BATCH(sv1, wv1, 1)
        GAT1_BATCH(sv2, wv2, 2)
        GAT1_BATCH(sv3, wv3, 3)
        GAT1_BATCH(sv4, wv4, 4)
        GAT1_BATCH(sv5, wv5, 5)
        GAT1_BATCH(sv6, wv6, 6)
        GAT1_BATCH(sv7, wv7, 7)
        #undef GAT1_BATCH
    } else {
        float dA = 0.f, dB = 0.f;
        for (int j0 = beg; j0 < end; j0 += 16) {
            int j = j0 + el, jb = j0 + 8 + el;
            if (j < end)  dA += __expf(lrelu(as1[(esd[j].x << 3) + he] + adv));
            if (jb < end) dB += __expf(lrelu(as1[(esd[jb].x << 3) + he] + adv));
        }
        float d = dA + dB;
        #pragma unroll
        for (int off = 8; off < 64; off <<= 1) d += __shfl_xor(d, off);
        float inv = 1.f / d;
        for (int j0 = beg; j0 < end; j0 += 8) {
            int j = j0 + el;
            int s = 0; float wv = 0.f;
            if (j < end) {
                s = esd[j].x;
                wv = __expf(lrelu(as1[(s << 3) + he] + adv)) * inv;
            }
            int ne = min(end - j0, 8);
            int sb[8]; float wb[8];
            #pragma unroll
            for (int e8 = 0; e8 < 8; e8++) {
                sb[e8] = __shfl(s, e8 << 3);
                wb[e8] = __shfl(wv, (e8 << 3) + myh);
            }
            #pragma unroll
            for (int e8 = 0; e8 < 8; e8++) {
                if (e8 < ne) {
                    uint2 v = ((const uint2*)(H1b + ((long)sb[e8] << 8)))[lane];
                    acc.x += wb[e8] * bf_lo(v.x);
                    acc.y += wb[e8] * bf_hi(v.x);
                    acc.z += wb[e8] * bf_lo(v.y);
                    acc.w += wb[e8] * bf_hi(v.y);
                }
            }
        }
    }

    float4 bb = ((const float4*)b1)[lane];
    float o0 = fmaxf(acc.x + bb.x, 0.f);
    float o1 = fmaxf(acc.y + bb.y, 0.f);
    float o2 = fmaxf(acc.z + bb.z, 0.f);
    float o3 = fmaxf(acc.w + bb.w, 0.f);
    uint2 ov;
    ov.x = (uint_t)f2bf(o0) | ((uint_t)f2bf(o1) << 16);
    ov.y = (uint_t)f2bf(o2) | ((uint_t)f2bf(o3) << 16);
    ((uint2*)(X1b + ((long)w << 8)))[lane] = ov;
}

// ---------------- GEMM2 (MFMA) + fused alpha2: h2 = x1b @ W2t^T ----------------
// wave handles 16 rows x 16 cols; A/B frags direct from global (16B/lane).
__global__ __launch_bounds__(256) void gemm2_k(const ushort_t* __restrict__ X1b,
    const ushort_t* __restrict__ W2t, const float* __restrict__ a2s_w,
    const float* __restrict__ a2d_w, float* __restrict__ H2,
    float* __restrict__ as2, float* __restrict__ ad2, int Nn)
{
    int wid = threadIdx.x >> 6, lane = threadIdx.x & 63;
    int row0 = blockIdx.x * 64 + wid * 16;
    if (row0 >= Nn) return;
    int lm = lane & 15, lg = lane >> 4;
    f32x4 acc = (f32x4){0.f, 0.f, 0.f, 0.f};
    const ushort_t* arow = X1b + (long)(row0 + lm) * 256 + lg * 8;  // A: row=lm, k=lg*8+j
    const ushort_t* brow = W2t + lm * 256 + lg * 8;                  // B: col=lm, same k
    #pragma unroll
    for (int k0 = 0; k0 < 256; k0 += 32) {
        short8 af = *(const short8*)(arow + k0);
        short8 bf = *(const short8*)(brow + k0);
        acc = __builtin_amdgcn_mfma_f32_16x16x32_bf16(af, bf, acc, 0, 0, 0);
    }
    // D: col=lm, row(within tile)=lg*4+r
    float a2sv = a2s_w[lm], a2dv = a2d_w[lm];
    #pragma unroll
    for (int r = 0; r < 4; r++) {
        int grow = row0 + lg * 4 + r;
        if (grow < Nn) H2[(grow << 4) + lm] = acc[r];
        float s = acc[r] * a2sv, d2 = acc[r] * a2dv;
        #pragma unroll
        for (int off = 1; off < 16; off <<= 1) {
            s += __shfl_xor(s, off);
            d2 += __shfl_xor(d2, off);
        }
        if (lm == 0 && grow < Nn) { as2[grow] = s; ad2[grow] = d2; }
    }
}

// ---------------- GAT layer 2 aggregate + final softmax (weight-cached) ----------------
__global__ __launch_bounds__(256) void gat2_agg_k(const float* __restrict__ H2,
    const float* __restrict__ as2, const float* __restrict__ ad2,
    const int* __restrict__ offs, const int2* __restrict__ esd,
    const float* __restrict__ b2, float* __restrict__ out, int Nn)
{
    int w = (blockIdx.x << 2) + (threadIdx.x >> 6);
    if (w >= Nn) return;
    int lane = threadIdx.x & 63;
    int beg = offs[w], end = offs[w + 1];
    int deg = end - beg;
    float adv = ad2[w];
    int c = lane & 15, eg = lane >> 4;
    float acc = 0.f;

    if (deg <= 64) {
        // pass 1: one edge per lane, cache src + normalized weight
        int j = beg + lane;
        int s_l = 0; float w_l = 0.f;
        if (j < end) { s_l = esd[j].x; w_l = __expf(lrelu(as2[s_l] + adv)); }
        float d = w_l;
        #pragma unroll
        for (int off = 1; off < 64; off <<= 1) d += __shfl_xor(d, off);
        float w_n = w_l / d;
        // pass 2: broadcast cached (s,w), gather H2
        for (int j0 = 0; j0 < deg; j0 += 4) {
            int jj = j0 + eg;
            int s = __shfl(s_l, jj);
            float wv = __shfl(w_n, jj);
            if (jj < deg)
                acc += wv * H2[(s << 4) + c];
        }
    } else {
        float d = 0.f;
        for (int j = beg + lane; j < end; j += 64)
            d += __expf(lrelu(as2[esd[j].x] + adv));
        #pragma unroll
        for (int off = 1; off < 64; off <<= 1) d += __shfl_xor(d, off);
        float inv = 1.f / d;
        for (int j0 = beg; j0 < end; j0 += 4) {
            int j = j0 + eg;
            if (j < end) {
                int s = esd[j].x;
                float wv = __expf(lrelu(as2[s] + adv)) * inv;
                acc += wv * H2[(s << 4) + c];
            }
        }
    }
    acc += __shfl_xor(acc, 16);
    acc += __shfl_xor(acc, 32);
    float v = acc + b2[c];
    float mx = v;
    #pragma unroll
    for (int off = 1; off < 16; off <<= 1) mx = fmaxf(mx, __shfl_xor(mx, off));
    float ex = __expf(v - mx);
    float se = ex;
    #pragma unroll
    for (int off = 1; off < 16; off <<= 1) se += __shfl_xor(se, off);
    if (eg == 0) out[(w << 4) + c] = ex / se;
}

// ---------------- host launcher ----------------
extern "C" void kernel_launch(void* const* d_in, const int* in_sizes, int n_in,
                              void* d_out, int out_size, void* d_ws, size_t ws_size,
                              hipStream_t stream)
{
    const float* x    = (const float*)d_in[0];
    const int*   ei   = (const int*)d_in[1];
    const float* W1   = (const float*)d_in[2];
    const float* a1s  = (const float*)d_in[3];
    const float* a1d  = (const float*)d_in[4];
    const float* b1   = (const float*)d_in[5];
    const float* W2   = (const float*)d_in[6];
    const float* a2s  = (const float*)d_in[7];
    const float* a2d  = (const float*)d_in[8];
    const float* b2   = (const float*)d_in[9];
    float* out = (float*)d_out;

    int N = in_sizes[0] / HID;
    int E = in_sizes[1] / 2;
    int Etot = E + N;
    const int* src = ei;
    const int* dst = ei + E;

    char* p = (char*)d_ws;
    auto alloc = [&](size_t bytes) {
        void* r = (void*)p;
        p += (bytes + 255) & ~(size_t)255;
        return r;
    };
    ushort_t* xbf  = (ushort_t*)alloc((size_t)N * 256 * 2);
    ushort_t* h1b  = (ushort_t*)alloc((size_t)N * 256 * 2);
    ushort_t* x1b  = (ushort_t*)alloc((size_t)N * 256 * 2);
    ushort_t* w1t  = (ushort_t*)alloc((size_t)256 * 256 * 2);
    ushort_t* w2t  = (ushort_t*)alloc((size_t)16 * 256 * 2);
    float* h2      = (float*)alloc((size_t)N * 16 * 4);
    float* as1     = (float*)alloc((size_t)N * 8 * 4);
    float* ad1     = (float*)alloc((size_t)N * 8 * 4);
    float* as2v    = (float*)alloc((size_t)N * 4);
    float* ad2v    = (float*)alloc((size_t)N * 4);
    int*   deg     = (int*)alloc((size_t)N * 4);
    int*   incl    = (int*)alloc((size_t)N * 4);
    int*   offs    = (int*)alloc((size_t)(N + 1) * 4);
    int*   cursor  = (int*)alloc((size_t)N * 4);
    int*   bsum    = (int*)alloc(256 * 4);
    int*   bpre    = (int*)alloc(256 * 4);
    int2*  esd     = (int2*)alloc((size_t)Etot * 8);

    int nb = (N + 1023) / 1024;
    int cnt_blocks = (Etot + 255) / 256;

    // zero deg, then merged prep (W1t | W2t | Xbf | deg_count)
    hipMemsetAsync(deg, 0, (size_t)N * 4, stream);
    hipLaunchKernelGGL(prep_k, dim3(65 + 2048 + cnt_blocks), dim3(256), 0, stream,
                       x, xbf, (long)N * 64, W1, w1t, W2, w2t, dst, E, Etot, deg);
    // GEMM1 (MFMA, async-staged, fused alpha1)
    dim3 g1(2, (N + 127) / 128);
    hipLaunchKernelGGL(gemm1_k, g1, dim3(256), 0, stream,
                       xbf, w1t, a1s, a1d, h1b, as1, ad1, N);
    // CSR scans + scatter
    hipLaunchKernelGGL(scan1_k, dim3(nb), dim3(256), 0, stream, deg, incl, bsum, N);
    hipLaunchKernelGGL(scan2_k, dim3(1), dim3(64), 0, stream, bsum, bpre, nb);
    hipLaunchKernelGGL(scan3_k, dim3((N + 255) / 256), dim3(256), 0, stream,
                       incl, deg, bpre, offs, cursor, N, Etot);
    hipLaunchKernelGGL(scatter_k, dim3(cnt_blocks), dim3(256), 0, stream,
                       src, dst, E, N, cursor, esd);
    // layer 1 aggregate
    hipLaunchKernelGGL(gat1_agg_k, dim3((N + 3) / 4), dim3(256), 0, stream,
                       h1b, as1, ad1, offs, esd, b1, x1b, N);
    // layer 2: MFMA gemm2 + aggregate
    hipLaunchKernelGGL(gemm2_k, dim3((N + 63) / 64), dim3(256), 0, stream,
                       x1b, w2t, a2s, a2d, h2, as2v, ad2v, N);
    hipLaunchKernelGGL(gat2_agg_k, dim3((N + 3) / 4), dim3(256), 0, stream,
                       h2, as2v, ad2v, offs, esd, b2, out, N);
}

// Round 12
// 246.249 us; speedup vs baseline: 1.5529x; 1.0210x over previous
//
#include <hip/hip_runtime.h>
#include <hip/hip_bf16.h>

#define HID 256
#define H1H 8
#define C1 32
#define C2 16
#define NEG 0.2f

typedef unsigned short ushort_t;
typedef unsigned int uint_t;
typedef __attribute__((ext_vector_type(8))) short short8;
typedef __attribute__((ext_vector_type(4))) float f32x4;

__device__ __forceinline__ float lrelu(float t){ return (t >= 0.f) ? t : NEG * t; }
__device__ __forceinline__ ushort_t f2bf(float f){
    uint_t u = __float_as_uint(f);
    u = (u + 0x7fffu + ((u >> 16) & 1u)) >> 16;   // RNE
    return (ushort_t)u;
}
__device__ __forceinline__ float bf_lo(uint_t p){ return __uint_as_float(p << 16); }
__device__ __forceinline__ float bf_hi(uint_t p){ return __uint_as_float(p & 0xffff0000u); }

#define GLOAD_LDS16(g, l) \
    __builtin_amdgcn_global_load_lds( \
        (const __attribute__((address_space(1))) void*)(g), \
        (__attribute__((address_space(3))) void*)(l), 16, 0, 0)

// ---------------- prep (merged): W1t transpose | W2t bf16 transpose | Xbf stream | deg_count ----
// deg must be zeroed (hipMemsetAsync) BEFORE this kernel.
__global__ __launch_bounds__(256) void prep_k(const float* __restrict__ X,
                                              ushort_t* __restrict__ Xbf, long n4,
                                              const float* __restrict__ W1,
                                              ushort_t* __restrict__ W1t,
                                              const float* __restrict__ W2,
                                              ushort_t* __restrict__ W2t,
                                              const int* __restrict__ dst,
                                              int E, int Etot, int* __restrict__ deg)
{
    int bid = blockIdx.x;
    if (bid < 64) {
        __shared__ ushort_t sh[32][33];
        int bx = bid & 7, by = bid >> 3;                  // k-tile, n-tile
        int tx = threadIdx.x & 31, ty = threadIdx.x >> 5; // 32 x 8
        #pragma unroll
        for (int i = 0; i < 32; i += 8)
            sh[ty + i][tx] = f2bf(W1[(long)(bx * 32 + ty + i) * 256 + by * 32 + tx]);
        __syncthreads();
        #pragma unroll
        for (int i = 0; i < 32; i += 8)
            W1t[(long)(by * 32 + ty + i) * 256 + bx * 32 + tx] = sh[tx][ty + i];
    } else if (bid == 64) {
        // W2t[c][k] = bf16(W2[k][c]); 4096 elems
        for (int idx = threadIdx.x; idx < 4096; idx += 256) {
            int k = idx >> 4, c = idx & 15;
            W2t[c * 256 + k] = f2bf(W2[idx]);
        }
    } else if (bid < 65 + 2048) {
        long stride = (long)2048 * 256;
        for (long i = (long)(bid - 65) * 256 + threadIdx.x; i < n4; i += stride) {
            float4 v = ((const float4*)X)[i];
            ushort4 o;
            o.x = f2bf(fmaxf(v.x, 0.f)); o.y = f2bf(fmaxf(v.y, 0.f));
            o.z = f2bf(fmaxf(v.z, 0.f)); o.w = f2bf(fmaxf(v.w, 0.f));
            ((ushort4*)Xbf)[i] = o;
        }
    } else {
        int i = (bid - 65 - 2048) * 256 + threadIdx.x;
        if (i < E) atomicAdd(&deg[dst[i]], 1);
        else if (i < Etot) atomicAdd(&deg[i - E], 1);   // self loops
    }
}

// ---------------- GEMM1 (MFMA, async-staged) + co-scheduled edge scatter ----------------
// blocks [0, nGemm): 128x128 GEMM tile; blocks [nGemm, ...): 1024-edge scatter (4/thread MLP).
__global__ __launch_bounds__(256) void gemm1_k(const ushort_t* __restrict__ Xbf,
                                               const ushort_t* __restrict__ W1t,
                                               const float* __restrict__ a1s_g,
                                               const float* __restrict__ a1d_g,
                                               ushort_t* __restrict__ H1b,
                                               float* __restrict__ as1,
                                               float* __restrict__ ad1, int M, int nGemm,
                                               const int* __restrict__ src,
                                               const int* __restrict__ dst,
                                               int E, int Etot, int* __restrict__ cursor,
                                               int* __restrict__ srcs)
{
    __shared__ ushort_t Abuf[128 * 64];   // 16 KiB, chunk-swizzled
    __shared__ ushort_t Bbuf[128 * 64];   // 16 KiB
    int bid = blockIdx.x;
    int tid = threadIdx.x;

    if (bid >= nGemm) {
        // ---- scatter path: 4 independent edges per thread ----
        long base = (long)(bid - nGemm) * 1024;
        #pragma unroll
        for (int q = 0; q < 4; q++) {
            long i = base + q * 256 + tid;
            if (i < E) {
                int d = dst[i];
                int p = atomicAdd(&cursor[d], 1);
                srcs[p] = src[i];
            } else if (i < Etot) {
                int n = (int)(i - E);
                int p = atomicAdd(&cursor[n], 1);
                srcs[p] = n;                    // self loop
            }
        }
        return;
    }

    int bm = (bid >> 1) * 128, bn = (bid & 1) * 128;
    int wid = tid >> 6, lane = tid & 63;
    int wr = wid >> 1, wc = wid & 1;
    int lg = lane >> 4, lm = lane & 15;

    f32x4 acc[4][4];
    #pragma unroll
    for (int m = 0; m < 4; m++)
        #pragma unroll
        for (int n = 0; n < 4; n++) acc[m][n] = (f32x4){0.f, 0.f, 0.f, 0.f};

    int r_st[4], lc_st[4];
    #pragma unroll
    for (int q = 0; q < 4; q++) {
        int idx = q * 256 + tid;
        r_st[q] = idx >> 3;
        lc_st[q] = (idx & 7) ^ (r_st[q] & 7);
    }

    for (int k0 = 0; k0 < 256; k0 += 64) {
        __syncthreads();
        #pragma unroll
        for (int q = 0; q < 4; q++) {
            const ushort_t* asrc = Xbf + (long)(bm + r_st[q]) * 256 + k0 + lc_st[q] * 8;
            GLOAD_LDS16(asrc, Abuf + (q * 256 + wid * 64) * 8);
            const ushort_t* bsrc = W1t + (long)(bn + r_st[q]) * 256 + k0 + lc_st[q] * 8;
            GLOAD_LDS16(bsrc, Bbuf + (q * 256 + wid * 64) * 8);
        }
        __syncthreads();
        #pragma unroll
        for (int ks = 0; ks < 2; ks++) {
            int kg = ks * 4 + lg;
            short8 af[4], bfr[4];
            #pragma unroll
            for (int m = 0; m < 4; m++) {
                int R = wr * 64 + m * 16 + lm;
                af[m] = *(const short8*)&Abuf[(R * 8 + (kg ^ (R & 7))) * 8];
            }
            #pragma unroll
            for (int n = 0; n < 4; n++) {
                int Cc = wc * 64 + n * 16 + lm;
                bfr[n] = *(const short8*)&Bbuf[(Cc * 8 + (kg ^ (Cc & 7))) * 8];
            }
            #pragma unroll
            for (int m = 0; m < 4; m++)
                #pragma unroll
                for (int n = 0; n < 4; n++)
                    acc[m][n] = __builtin_amdgcn_mfma_f32_16x16x32_bf16(af[m], bfr[n], acc[m][n], 0, 0, 0);
        }
    }

    // fused alpha1
    int h0 = ((bn >> 5) + (wc << 1));
    float as_l0 = a1s_g[h0 * 32 + lm],       as_h0 = a1s_g[h0 * 32 + 16 + lm];
    float as_l1 = a1s_g[(h0 + 1) * 32 + lm], as_h1 = a1s_g[(h0 + 1) * 32 + 16 + lm];
    float ad_l0 = a1d_g[h0 * 32 + lm],       ad_h0 = a1d_g[h0 * 32 + 16 + lm];
    float ad_l1 = a1d_g[(h0 + 1) * 32 + lm], ad_h1 = a1d_g[(h0 + 1) * 32 + 16 + lm];

    #pragma unroll
    for (int m = 0; m < 4; m++) {
        #pragma unroll
        for (int r = 0; r < 4; r++) {
            int gm = bm + wr * 64 + m * 16 + lg * 4 + r;
            float s0 = acc[m][0][r] * as_l0 + acc[m][1][r] * as_h0;
            float s1 = acc[m][2][r] * as_l1 + acc[m][3][r] * as_h1;
            float d0 = acc[m][0][r] * ad_l0 + acc[m][1][r] * ad_h0;
            float d1 = acc[m][2][r] * ad_l1 + acc[m][3][r] * ad_h1;
            #pragma unroll
            for (int off = 1; off < 16; off <<= 1) {
                s0 += __shfl_xor(s0, off);
                s1 += __shfl_xor(s1, off);
                d0 += __shfl_xor(d0, off);
                d1 += __shfl_xor(d1, off);
            }
            if (gm < M) {
                long base = (long)gm * 256 + bn + wc * 64 + lm;
                #pragma unroll
                for (int n = 0; n < 4; n++)
                    H1b[base + n * 16] = f2bf(acc[m][n][r]);
                if (lm == 0) {
                    float2 sv = {s0, s1}, dv = {d0, d1};
                    *(float2*)&as1[(gm << 3) + h0] = sv;
                    *(float2*)&ad1[(gm << 3) + h0] = dv;
                }
            }
        }
    }
}

// ---------------- CSR scans ----------------
__global__ __launch_bounds__(256) void scan1_k(const int* __restrict__ deg,
                                               int* __restrict__ incl,
                                               int* __restrict__ bsum, int Nn)
{
    __shared__ int sh[256];
    int t = threadIdx.x;
    int base = blockIdx.x * 1024 + t * 4;
    int v0 = (base     < Nn) ? deg[base]     : 0;
    int v1 = (base + 1 < Nn) ? deg[base + 1] : 0;
    int v2 = (base + 2 < Nn) ? deg[base + 2] : 0;
    int v3 = (base + 3 < Nn) ? deg[base + 3] : 0;
    int s0 = v0, s1 = s0 + v1, s2 = s1 + v2, s3 = s2 + v3;
    sh[t] = s3;
    __syncthreads();
    for (int off = 1; off < 256; off <<= 1) {
        int x = (t >= off) ? sh[t - off] : 0;
        __syncthreads();
        sh[t] += x;
        __syncthreads();
    }
    int prev = (t > 0) ? sh[t - 1] : 0;
    if (base     < Nn) incl[base]     = prev + s0;
    if (base + 1 < Nn) incl[base + 1] = prev + s1;
    if (base + 2 < Nn) incl[base + 2] = prev + s2;
    if (base + 3 < Nn) incl[base + 3] = prev + s3;
    if (t == 255) bsum[blockIdx.x] = sh[255];
}
__global__ void scan2_k(const int* __restrict__ bsum, int* __restrict__ bpre, int nb)
{
    int t = threadIdx.x;                // single wave, nb <= 64
    int own = (t < nb) ? bsum[t] : 0;
    int v = own;
    for (int off = 1; off < 64; off <<= 1) {
        int x = __shfl_up(v, off);
        if (t >= off) v += x;
    }
    if (t < nb) bpre[t] = v - own;      // exclusive
}
__global__ void scan3_k(const int* __restrict__ incl, const int* __restrict__ deg,
                        const int* __restrict__ bpre, int* __restrict__ offs,
                        int* __restrict__ cursor, int Nn, int Etot)
{
    int i = blockIdx.x * 256 + threadIdx.x;
    if (i < Nn) {
        int e = bpre[i >> 10] + incl[i] - deg[i];
        offs[i] = e;
        cursor[i] = e;
    }
    if (i == 0) offs[Nn] = Etot;
}

// ---------------- GAT layer 1 aggregate: wave per dst node ----------------
__global__ __launch_bounds__(256) void gat1_agg_k(const ushort_t* __restrict__ H1b,
    const float* __restrict__ as1, const float* __restrict__ ad1,
    const int* __restrict__ offs, const int* __restrict__ srcs,
    const float* __restrict__ b1, ushort_t* __restrict__ X1b, int Nn)
{
    int w = (blockIdx.x << 2) + (threadIdx.x >> 6);
    if (w >= Nn) return;
    int lane = threadIdx.x & 63;
    int he = lane & 7, el = lane >> 3;
    int myh = lane >> 3;
    int beg = offs[w], end = offs[w + 1];
    int deg = end - beg;
    float adv = ad1[(w << 3) + he];
    float4 acc = {0.f, 0.f, 0.f, 0.f};

    if (deg <= 64) {
        int sv0=0,sv1=0,sv2=0,sv3=0,sv4=0,sv5=0,sv6=0,sv7=0;
        float wv0=0,wv1=0,wv2=0,wv3=0,wv4=0,wv5=0,wv6=0,wv7=0;
        {
            int j;
            j = beg + el;      if (j < end){ sv0 = srcs[j]; wv0 = __expf(lrelu(as1[(sv0<<3)+he]+adv)); }
            j = beg + 8 + el;  if (j < end){ sv1 = srcs[j]; wv1 = __expf(lrelu(as1[(sv1<<3)+he]+adv)); }
            j = beg + 16 + el; if (j < end){ sv2 = srcs[j]; wv2 = __expf(lrelu(as1[(sv2<<3)+he]+adv)); }
            j = beg + 24 + el; if (j < end){ sv3 = srcs[j]; wv3 = __expf(lrelu(as1[(sv3<<3)+he]+adv)); }
            j = beg + 32 + el; if (j < end){ sv4 = srcs[j]; wv4 = __expf(lrelu(as1[(sv4<<3)+he]+adv)); }
            j = beg + 40 + el; if (j < end){ sv5 = srcs[j]; wv5 = __expf(lrelu(as1[(sv5<<3)+he]+adv)); }
            j = beg + 48 + el; if (j < end){ sv6 = srcs[j]; wv6 = __expf(lrelu(as1[(sv6<<3)+he]+adv)); }
            j = beg + 56 + el; if (j < end){ sv7 = srcs[j]; wv7 = __expf(lrelu(as1[(sv7<<3)+he]+adv)); }
        }
        float d = ((wv0 + wv1) + (wv2 + wv3)) + ((wv4 + wv5) + (wv6 + wv7));
        #pragma unroll
        for (int off = 8; off < 64; off <<= 1) d += __shfl_xor(d, off);
        float inv = 1.f / d;
        wv0 *= inv; wv1 *= inv; wv2 *= inv; wv3 *= inv;
        wv4 *= inv; wv5 *= inv; wv6 *= inv; wv7 *= inv;

        #define GAT1_BATCH(SV, WV, Q)                                            \
        {                                                                        \
            int ne = deg - (Q << 3);                                             \
            if (ne > 0) {                                                        \
                ne = min(ne, 8);                                                 \
                int sb[8]; float wb[8];                                          \
                _Pragma("unroll")                                                \
                for (int e8 = 0; e8 < 8; e8++) {                                 \
                    sb[e8] = __shfl(SV, e8 << 3);                                \
                    wb[e8] = __shfl(WV, (e8 << 3) + myh);                        \
                }                                                                \
                if (ne == 8) {                                                   \
                    _Pragma("unroll")                                            \
                    for (int e8 = 0; e8 < 8; e8++) {                             \
                        uint2 v = ((const uint2*)(H1b + ((long)sb[e8] << 8)))[lane]; \
                        acc.x += wb[e8] * bf_lo(v.x);                            \
                        acc.y += wb[e8] * bf_hi(v.x);                            \
                        acc.z += wb[e8] * bf_lo(v.y);                            \
                        acc.w += wb[e8] * bf_hi(v.y);                            \
                    }                                                            \
                } else {                                                         \
                    _Pragma("unroll")                                            \
                    for (int e8 = 0; e8 < 8; e8++) {                             \
                        if (e8 < ne) {                                           \
                            uint2 v = ((const uint2*)(H1b + ((long)sb[e8] << 8)))[lane]; \
                            acc.x += wb[e8] * bf_lo(v.x);                        \
                            acc.y += wb[e8] * bf_hi(v.x);                        \
                            acc.z += wb[e8] * bf_lo(v.y);                        \
                            acc.w += wb[e8] * bf_hi(v.y);                        \
                        }                                                        \
                    }                                                            \
                }                                                                \
            }                                                                    \
        }
        GAT1_BATCH(sv0, wv0, 0)
        GAT1_BATCH(sv1, wv1, 1)
        GAT1_BATCH(sv2, wv2, 2)
        GAT1_BATCH(sv3, wv3, 3)
        GAT1_BATCH(sv4, wv4, 4)
        GAT1_BATCH(sv5, wv5, 5)
        GAT1_BATCH(sv6, wv6, 6)
        GAT1_BATCH(sv7, wv7, 7)
        #undef GAT1_BATCH
    } else {
        float dA = 0.f, dB = 0.f;
        for (int j0 = beg; j0 < end; j0 += 16) {
            int j = j0 + el, jb = j0 + 8 + el;
            if (j < end)  dA += __expf(lrelu(as1[(srcs[j] << 3) + he] + adv));
            if (jb < end) dB += __expf(lrelu(as1[(srcs[jb] << 3) + he] + adv));
        }
        float d = dA + dB;
        #pragma unroll
        for (int off = 8; off < 64; off <<= 1) d += __shfl_xor(d, off);
        float inv = 1.f / d;
        for (int j0 = beg; j0 < end; j0 += 8) {
            int j = j0 + el;
            int s = 0; float wv = 0.f;
            if (j < end) {
                s = srcs[j];
                wv = __expf(lrelu(as1[(s << 3) + he] + adv)) * inv;
            }
            int ne = min(end - j0, 8);
            int sb[8]; float wb[8];
            #pragma unroll
            for (int e8 = 0; e8 < 8; e8++) {
                sb[e8] = __shfl(s, e8 << 3);
                wb[e8] = __shfl(wv, (e8 << 3) + myh);
            }
            #pragma unroll
            for (int e8 = 0; e8 < 8; e8++) {
                if (e8 < ne) {
                    uint2 v = ((const uint2*)(H1b + ((long)sb[e8] << 8)))[lane];
                    acc.x += wb[e8] * bf_lo(v.x);
                    acc.y += wb[e8] * bf_hi(v.x);
                    acc.z += wb[e8] * bf_lo(v.y);
                    acc.w += wb[e8] * bf_hi(v.y);
                }
            }
        }
    }

    float4 bb = ((const float4*)b1)[lane];
    float o0 = fmaxf(acc.x + bb.x, 0.f);
    float o1 = fmaxf(acc.y + bb.y, 0.f);
    float o2 = fmaxf(acc.z + bb.z, 0.f);
    float o3 = fmaxf(acc.w + bb.w, 0.f);
    uint2 ov;
    ov.x = (uint_t)f2bf(o0) | ((uint_t)f2bf(o1) << 16);
    ov.y = (uint_t)f2bf(o2) | ((uint_t)f2bf(o3) << 16);
    ((uint2*)(X1b + ((long)w << 8)))[lane] = ov;
}

// ---------------- GEMM2 (MFMA) + fused alpha2: h2 = x1b @ W2t^T ----------------
__global__ __launch_bounds__(256) void gemm2_k(const ushort_t* __restrict__ X1b,
    const ushort_t* __restrict__ W2t, const float* __restrict__ a2s_w,
    const float* __restrict__ a2d_w, float* __restrict__ H2,
    float* __restrict__ as2, float* __restrict__ ad2, int Nn)
{
    int wid = threadIdx.x >> 6, lane = threadIdx.x & 63;
    int row0 = blockIdx.x * 64 + wid * 16;
    if (row0 >= Nn) return;
    int lm = lane & 15, lg = lane >> 4;
    f32x4 acc = (f32x4){0.f, 0.f, 0.f, 0.f};
    const ushort_t* arow = X1b + (long)(row0 + lm) * 256 + lg * 8;
    const ushort_t* brow = W2t + lm * 256 + lg * 8;
    #pragma unroll
    for (int k0 = 0; k0 < 256; k0 += 32) {
        short8 af = *(const short8*)(arow + k0);
        short8 bf = *(const short8*)(brow + k0);
        acc = __builtin_amdgcn_mfma_f32_16x16x32_bf16(af, bf, acc, 0, 0, 0);
    }
    float a2sv = a2s_w[lm], a2dv = a2d_w[lm];
    #pragma unroll
    for (int r = 0; r < 4; r++) {
        int grow = row0 + lg * 4 + r;
        if (grow < Nn) H2[(grow << 4) + lm] = acc[r];
        float s = acc[r] * a2sv, d2 = acc[r] * a2dv;
        #pragma unroll
        for (int off = 1; off < 16; off <<= 1) {
            s += __shfl_xor(s, off);
            d2 += __shfl_xor(d2, off);
        }
        if (lm == 0 && grow < Nn) { as2[grow] = s; ad2[grow] = d2; }
    }
}

// ---------------- GAT layer 2 aggregate + final softmax (weight-cached) ----------------
__global__ __launch_bounds__(256) void gat2_agg_k(const float* __restrict__ H2,
    const float* __restrict__ as2, const float* __restrict__ ad2,
    const int* __restrict__ offs, const int* __restrict__ srcs,
    const float* __restrict__ b2, float* __restrict__ out, int Nn)
{
    int w = (blockIdx.x << 2) + (threadIdx.x >> 6);
    if (w >= Nn) return;
    int lane = threadIdx.x & 63;
    int beg = offs[w], end = offs[w + 1];
    int deg = end - beg;
    float adv = ad2[w];
    int c = lane & 15, eg = lane >> 4;
    float acc = 0.f;

    if (deg <= 64) {
        int j = beg + lane;
        int s_l = 0; float w_l = 0.f;
        if (j < end) { s_l = srcs[j]; w_l = __expf(lrelu(as2[s_l] + adv)); }
        float d = w_l;
        #pragma unroll
        for (int off = 1; off < 64; off <<= 1) d += __shfl_xor(d, off);
        float w_n = w_l / d;
        for (int j0 = 0; j0 < deg; j0 += 4) {
            int jj = j0 + eg;
            int s = __shfl(s_l, jj);
            float wv = __shfl(w_n, jj);
            if (jj < deg)
                acc += wv * H2[(s << 4) + c];
        }
    } else {
        float d = 0.f;
        for (int j = beg + lane; j < end; j += 64)
            d += __expf(lrelu(as2[srcs[j]] + adv));
        #pragma unroll
        for (int off = 1; off < 64; off <<= 1) d += __shfl_xor(d, off);
        float inv = 1.f / d;
        for (int j0 = beg; j0 < end; j0 += 4) {
            int j = j0 + eg;
            if (j < end) {
                int s = srcs[j];
                float wv = __expf(lrelu(as2[s] + adv)) * inv;
                acc += wv * H2[(s << 4) + c];
            }
        }
    }
    acc += __shfl_xor(acc, 16);
    acc += __shfl_xor(acc, 32);
    float v = acc + b2[c];
    float mx = v;
    #pragma unroll
    for (int off = 1; off < 16; off <<= 1) mx = fmaxf(mx, __shfl_xor(mx, off));
    float ex = __expf(v - mx);
    float se = ex;
    #pragma unroll
    for (int off = 1; off < 16; off <<= 1) se += __shfl_xor(se, off);
    if (eg == 0) out[(w << 4) + c] = ex / se;
}

// ---------------- host launcher ----------------
extern "C" void kernel_launch(void* const* d_in, const int* in_sizes, int n_in,
                              void* d_out, int out_size, void* d_ws, size_t ws_size,
                              hipStream_t stream)
{
    const float* x    = (const float*)d_in[0];
    const int*   ei   = (const int*)d_in[1];
    const float* W1   = (const float*)d_in[2];
    const float* a1s  = (const float*)d_in[3];
    const float* a1d  = (const float*)d_in[4];
    const float* b1   = (const float*)d_in[5];
    const float* W2   = (const float*)d_in[6];
    const float* a2s  = (const float*)d_in[7];
    const float* a2d  = (const float*)d_in[8];
    const float* b2   = (const float*)d_in[9];
    float* out = (float*)d_out;

    int N = in_sizes[0] / HID;
    int E = in_sizes[1] / 2;
    int Etot = E + N;
    const int* src = ei;
    const int* dst = ei + E;

    char* p = (char*)d_ws;
    auto alloc = [&](size_t bytes) {
        void* r = (void*)p;
        p += (bytes + 255) & ~(size_t)255;
        return r;
    };
    ushort_t* xbf  = (ushort_t*)alloc((size_t)N * 256 * 2);
    ushort_t* h1b  = (ushort_t*)alloc((size_t)N * 256 * 2);
    ushort_t* x1b  = (ushort_t*)alloc((size_t)N * 256 * 2);
    ushort_t* w1t  = (ushort_t*)alloc((size_t)256 * 256 * 2);
    ushort_t* w2t  = (ushort_t*)alloc((size_t)16 * 256 * 2);
    float* h2      = (float*)alloc((size_t)N * 16 * 4);
    float* as1     = (float*)alloc((size_t)N * 8 * 4);
    float* ad1     = (float*)alloc((size_t)N * 8 * 4);
    float* as2v    = (float*)alloc((size_t)N * 4);
    float* ad2v    = (float*)alloc((size_t)N * 4);
    int*   deg     = (int*)alloc((size_t)N * 4);
    int*   incl    = (int*)alloc((size_t)N * 4);
    int*   offs    = (int*)alloc((size_t)(N + 1) * 4);
    int*   cursor  = (int*)alloc((size_t)N * 4);
    int*   bsum    = (int*)alloc(256 * 4);
    int*   bpre    = (int*)alloc(256 * 4);
    int*   srcs    = (int*)alloc((size_t)Etot * 4);

    int nb = (N + 1023) / 1024;
    int cnt_blocks = (Etot + 255) / 256;
    int nGemm = 2 * ((N + 127) / 128);
    int scat_blocks = (Etot + 1023) / 1024;

    // zero deg, then merged prep (W1t | W2t | Xbf | deg_count)
    hipMemsetAsync(deg, 0, (size_t)N * 4, stream);
    hipLaunchKernelGGL(prep_k, dim3(65 + 2048 + cnt_blocks), dim3(256), 0, stream,
                       x, xbf, (long)N * 64, W1, w1t, W2, w2t, dst, E, Etot, deg);
    // CSR scans (tiny) before fused gemm1+scatter
    hipLaunchKernelGGL(scan1_k, dim3(nb), dim3(256), 0, stream, deg, incl, bsum, N);
    hipLaunchKernelGGL(scan2_k, dim3(1), dim3(64), 0, stream, bsum, bpre, nb);
    hipLaunchKernelGGL(scan3_k, dim3((N + 255) / 256), dim3(256), 0, stream,
                       incl, deg, bpre, offs, cursor, N, Etot);
    // GEMM1 (MFMA) with co-scheduled scatter blocks
    hipLaunchKernelGGL(gemm1_k, dim3(nGemm + scat_blocks), dim3(256), 0, stream,
                       xbf, w1t, a1s, a1d, h1b, as1, ad1, N, nGemm,
                       src, dst, E, Etot, cursor, srcs);
    // layer 1 aggregate
    hipLaunchKernelGGL(gat1_agg_k, dim3((N + 3) / 4), dim3(256), 0, stream,
                       h1b, as1, ad1, offs, srcs, b1, x1b, N);
    // layer 2: MFMA gemm2 + aggregate
    hipLaunchKernelGGL(gemm2_k, dim3((N + 63) / 64), dim3(256), 0, stream,
                       x1b, w2t, a2s, a2d, h2, as2v, ad2v, N);
    hipLaunchKernelGGL(gat2_agg_k, dim3((N + 3) / 4), dim3(256), 0, stream,
                       h2, as2v, ad2v, offs, srcs, b2, out, N);
}

// Round 13
// 207.541 us; speedup vs baseline: 1.8425x; 1.1865x over previous
//
#include <hip/hip_runtime.h>
#include <hip/hip_bf16.h>

#define HID 256
#define H1H 8
#define C1 32
#define C2 16
#define NEG 0.2f

typedef unsigned short ushort_t;
typedef unsigned int uint_t;
typedef __attribute__((ext_vector_type(8))) short short8;
typedef __attribute__((ext_vector_type(4))) float f32x4;

__device__ __forceinline__ float lrelu(float t){ return (t >= 0.f) ? t : NEG * t; }
__device__ __forceinline__ ushort_t f2bf(float f){
    uint_t u = __float_as_uint(f);
    u = (u + 0x7fffu + ((u >> 16) & 1u)) >> 16;   // RNE
    return (ushort_t)u;
}
__device__ __forceinline__ float bf_lo(uint_t p){ return __uint_as_float(p << 16); }
__device__ __forceinline__ float bf_hi(uint_t p){ return __uint_as_float(p & 0xffff0000u); }

#define GLOAD_LDS16(g, l) \
    __builtin_amdgcn_global_load_lds( \
        (const __attribute__((address_space(1))) void*)(g), \
        (__attribute__((address_space(3))) void*)(l), 16, 0, 0)

// ---------------- prep (merged): W1t | W2t | Xbf stream | deg_count + slot ----------------
// deg must be zeroed (hipMemsetAsync) BEFORE this kernel.
__global__ __launch_bounds__(256) void prep_k(const float* __restrict__ X,
                                              ushort_t* __restrict__ Xbf, long n4,
                                              const float* __restrict__ W1,
                                              ushort_t* __restrict__ W1t,
                                              const float* __restrict__ W2,
                                              ushort_t* __restrict__ W2t,
                                              const int* __restrict__ dst,
                                              int E, int Etot, int* __restrict__ deg,
                                              int* __restrict__ slot)
{
    int bid = blockIdx.x;
    if (bid < 64) {
        __shared__ ushort_t sh[32][33];
        int bx = bid & 7, by = bid >> 3;                  // k-tile, n-tile
        int tx = threadIdx.x & 31, ty = threadIdx.x >> 5; // 32 x 8
        #pragma unroll
        for (int i = 0; i < 32; i += 8)
            sh[ty + i][tx] = f2bf(W1[(long)(bx * 32 + ty + i) * 256 + by * 32 + tx]);
        __syncthreads();
        #pragma unroll
        for (int i = 0; i < 32; i += 8)
            W1t[(long)(by * 32 + ty + i) * 256 + bx * 32 + tx] = sh[tx][ty + i];
    } else if (bid == 64) {
        // W2t[c][k] = bf16(W2[k][c]); 4096 elems
        for (int idx = threadIdx.x; idx < 4096; idx += 256) {
            int k = idx >> 4, c = idx & 15;
            W2t[c * 256 + k] = f2bf(W2[idx]);
        }
    } else if (bid < 65 + 2048) {
        long stride = (long)2048 * 256;
        for (long i = (long)(bid - 65) * 256 + threadIdx.x; i < n4; i += stride) {
            float4 v = ((const float4*)X)[i];
            ushort4 o;
            o.x = f2bf(fmaxf(v.x, 0.f)); o.y = f2bf(fmaxf(v.y, 0.f));
            o.z = f2bf(fmaxf(v.z, 0.f)); o.w = f2bf(fmaxf(v.w, 0.f));
            ((ushort4*)Xbf)[i] = o;
        }
    } else {
        int i = (bid - 65 - 2048) * 256 + threadIdx.x;
        if (i < E) {
            int p = atomicAdd(&deg[dst[i]], 1);
            slot[i] = p;                                  // within-node slot index
        } else if (i < Etot) {
            int p = atomicAdd(&deg[i - E], 1);            // self loop
            slot[i] = p;
        }
    }
}

// ---------------- GEMM1 (MFMA, async-staged): h1b = Xbf @ W1t^T + fused alpha1 ----------------
__global__ __launch_bounds__(256) void gemm1_k(const ushort_t* __restrict__ Xbf,
                                               const ushort_t* __restrict__ W1t,
                                               const float* __restrict__ a1s_g,
                                               const float* __restrict__ a1d_g,
                                               ushort_t* __restrict__ H1b,
                                               float* __restrict__ as1,
                                               float* __restrict__ ad1, int M)
{
    __shared__ ushort_t Abuf[128 * 64];   // 16 KiB, chunk-swizzled
    __shared__ ushort_t Bbuf[128 * 64];   // 16 KiB
    int tid = threadIdx.x;
    int bm = blockIdx.y * 128, bn = blockIdx.x * 128;
    int wid = tid >> 6, lane = tid & 63;
    int wr = wid >> 1, wc = wid & 1;
    int lg = lane >> 4, lm = lane & 15;

    f32x4 acc[4][4];
    #pragma unroll
    for (int m = 0; m < 4; m++)
        #pragma unroll
        for (int n = 0; n < 4; n++) acc[m][n] = (f32x4){0.f, 0.f, 0.f, 0.f};

    int r_st[4], lc_st[4];
    #pragma unroll
    for (int q = 0; q < 4; q++) {
        int idx = q * 256 + tid;
        r_st[q] = idx >> 3;
        lc_st[q] = (idx & 7) ^ (r_st[q] & 7);
    }

    for (int k0 = 0; k0 < 256; k0 += 64) {
        __syncthreads();
        #pragma unroll
        for (int q = 0; q < 4; q++) {
            const ushort_t* asrc = Xbf + (long)(bm + r_st[q]) * 256 + k0 + lc_st[q] * 8;
            GLOAD_LDS16(asrc, Abuf + (q * 256 + wid * 64) * 8);
            const ushort_t* bsrc = W1t + (long)(bn + r_st[q]) * 256 + k0 + lc_st[q] * 8;
            GLOAD_LDS16(bsrc, Bbuf + (q * 256 + wid * 64) * 8);
        }
        __syncthreads();
        #pragma unroll
        for (int ks = 0; ks < 2; ks++) {
            int kg = ks * 4 + lg;
            short8 af[4], bfr[4];
            #pragma unroll
            for (int m = 0; m < 4; m++) {
                int R = wr * 64 + m * 16 + lm;
                af[m] = *(const short8*)&Abuf[(R * 8 + (kg ^ (R & 7))) * 8];
            }
            #pragma unroll
            for (int n = 0; n < 4; n++) {
                int Cc = wc * 64 + n * 16 + lm;
                bfr[n] = *(const short8*)&Bbuf[(Cc * 8 + (kg ^ (Cc & 7))) * 8];
            }
            #pragma unroll
            for (int m = 0; m < 4; m++)
                #pragma unroll
                for (int n = 0; n < 4; n++)
                    acc[m][n] = __builtin_amdgcn_mfma_f32_16x16x32_bf16(af[m], bfr[n], acc[m][n], 0, 0, 0);
        }
    }

    // fused alpha1
    int h0 = ((bn >> 5) + (wc << 1));
    float as_l0 = a1s_g[h0 * 32 + lm],       as_h0 = a1s_g[h0 * 32 + 16 + lm];
    float as_l1 = a1s_g[(h0 + 1) * 32 + lm], as_h1 = a1s_g[(h0 + 1) * 32 + 16 + lm];
    float ad_l0 = a1d_g[h0 * 32 + lm],       ad_h0 = a1d_g[h0 * 32 + 16 + lm];
    float ad_l1 = a1d_g[(h0 + 1) * 32 + lm], ad_h1 = a1d_g[(h0 + 1) * 32 + 16 + lm];

    #pragma unroll
    for (int m = 0; m < 4; m++) {
        #pragma unroll
        for (int r = 0; r < 4; r++) {
            int gm = bm + wr * 64 + m * 16 + lg * 4 + r;
            float s0 = acc[m][0][r] * as_l0 + acc[m][1][r] * as_h0;
            float s1 = acc[m][2][r] * as_l1 + acc[m][3][r] * as_h1;
            float d0 = acc[m][0][r] * ad_l0 + acc[m][1][r] * ad_h0;
            float d1 = acc[m][2][r] * ad_l1 + acc[m][3][r] * ad_h1;
            #pragma unroll
            for (int off = 1; off < 16; off <<= 1) {
                s0 += __shfl_xor(s0, off);
                s1 += __shfl_xor(s1, off);
                d0 += __shfl_xor(d0, off);
                d1 += __shfl_xor(d1, off);
            }
            if (gm < M) {
                long base = (long)gm * 256 + bn + wc * 64 + lm;
                #pragma unroll
                for (int n = 0; n < 4; n++)
                    H1b[base + n * 16] = f2bf(acc[m][n][r]);
                if (lm == 0) {
                    float2 sv = {s0, s1}, dv = {d0, d1};
                    *(float2*)&as1[(gm << 3) + h0] = sv;
                    *(float2*)&ad1[(gm << 3) + h0] = dv;
                }
            }
        }
    }
}

// ---------------- CSR scans ----------------
__global__ __launch_bounds__(256) void scan1_k(const int* __restrict__ deg,
                                               int* __restrict__ incl,
                                               int* __restrict__ bsum, int Nn)
{
    __shared__ int sh[256];
    int t = threadIdx.x;
    int base = blockIdx.x * 1024 + t * 4;
    int v0 = (base     < Nn) ? deg[base]     : 0;
    int v1 = (base + 1 < Nn) ? deg[base + 1] : 0;
    int v2 = (base + 2 < Nn) ? deg[base + 2] : 0;
    int v3 = (base + 3 < Nn) ? deg[base + 3] : 0;
    int s0 = v0, s1 = s0 + v1, s2 = s1 + v2, s3 = s2 + v3;
    sh[t] = s3;
    __syncthreads();
    for (int off = 1; off < 256; off <<= 1) {
        int x = (t >= off) ? sh[t - off] : 0;
        __syncthreads();
        sh[t] += x;
        __syncthreads();
    }
    int prev = (t > 0) ? sh[t - 1] : 0;
    if (base     < Nn) incl[base]     = prev + s0;
    if (base + 1 < Nn) incl[base + 1] = prev + s1;
    if (base + 2 < Nn) incl[base + 2] = prev + s2;
    if (base + 3 < Nn) incl[base + 3] = prev + s3;
    if (t == 255) bsum[blockIdx.x] = sh[255];
}
__global__ void scan2_k(const int* __restrict__ bsum, int* __restrict__ bpre, int nb)
{
    int t = threadIdx.x;                // single wave, nb <= 64
    int own = (t < nb) ? bsum[t] : 0;
    int v = own;
    for (int off = 1; off < 64; off <<= 1) {
        int x = __shfl_up(v, off);
        if (t >= off) v += x;
    }
    if (t < nb) bpre[t] = v - own;      // exclusive
}
__global__ void scan3_k(const int* __restrict__ incl, const int* __restrict__ deg,
                        const int* __restrict__ bpre, int* __restrict__ offs,
                        int Nn, int Etot)
{
    int i = blockIdx.x * 256 + threadIdx.x;
    if (i < Nn) {
        int e = bpre[i >> 10] + incl[i] - deg[i];
        offs[i] = e;
    }
    if (i == 0) offs[Nn] = Etot;
}

// ---------------- scatter: atomic-free (slot precomputed in prep) ----------------
__global__ __launch_bounds__(256) void scatter_k(const int* __restrict__ src,
    const int* __restrict__ dst, const int* __restrict__ slot,
    const int* __restrict__ offs, int E, int Etot, int* __restrict__ srcs)
{
    long base = (long)blockIdx.x * 1024;
    #pragma unroll
    for (int q = 0; q < 4; q++) {
        long i = base + q * 256 + threadIdx.x;
        if (i < E) {
            int d = dst[i];
            srcs[offs[d] + slot[i]] = src[i];       // offs is L2-resident (200 KB)
        } else if (i < Etot) {
            int n = (int)(i - E);
            srcs[offs[n] + slot[i]] = n;            // self loop
        }
    }
}

// ---------------- GAT layer 1 aggregate: wave per dst node ----------------
__global__ __launch_bounds__(256) void gat1_agg_k(const ushort_t* __restrict__ H1b,
    const float* __restrict__ as1, const float* __restrict__ ad1,
    const int* __restrict__ offs, const int* __restrict__ srcs,
    const float* __restrict__ b1, ushort_t* __restrict__ X1b, int Nn)
{
    int w = (blockIdx.x << 2) + (threadIdx.x >> 6);
    if (w >= Nn) return;
    int lane = threadIdx.x & 63;
    int he = lane & 7, el = lane >> 3;
    int myh = lane >> 3;
    int beg = offs[w], end = offs[w + 1];
    int deg = end - beg;
    float adv = ad1[(w << 3) + he];
    float4 acc = {0.f, 0.f, 0.f, 0.f};

    if (deg <= 64) {
        int sv0=0,sv1=0,sv2=0,sv3=0,sv4=0,sv5=0,sv6=0,sv7=0;
        float wv0=0,wv1=0,wv2=0,wv3=0,wv4=0,wv5=0,wv6=0,wv7=0;
        {
            int j;
            j = beg + el;      if (j < end){ sv0 = srcs[j]; wv0 = __expf(lrelu(as1[(sv0<<3)+he]+adv)); }
            j = beg + 8 + el;  if (j < end){ sv1 = srcs[j]; wv1 = __expf(lrelu(as1[(sv1<<3)+he]+adv)); }
            j = beg + 16 + el; if (j < end){ sv2 = srcs[j]; wv2 = __expf(lrelu(as1[(sv2<<3)+he]+adv)); }
            j = beg + 24 + el; if (j < end){ sv3 = srcs[j]; wv3 = __expf(lrelu(as1[(sv3<<3)+he]+adv)); }
            j = beg + 32 + el; if (j < end){ sv4 = srcs[j]; wv4 = __expf(lrelu(as1[(sv4<<3)+he]+adv)); }
            j = beg + 40 + el; if (j < end){ sv5 = srcs[j]; wv5 = __expf(lrelu(as1[(sv5<<3)+he]+adv)); }
            j = beg + 48 + el; if (j < end){ sv6 = srcs[j]; wv6 = __expf(lrelu(as1[(sv6<<3)+he]+adv)); }
            j = beg + 56 + el; if (j < end){ sv7 = srcs[j]; wv7 = __expf(lrelu(as1[(sv7<<3)+he]+adv)); }
        }
        float d = ((wv0 + wv1) + (wv2 + wv3)) + ((wv4 + wv5) + (wv6 + wv7));
        #pragma unroll
        for (int off = 8; off < 64; off <<= 1) d += __shfl_xor(d, off);
        float inv = 1.f / d;
        wv0 *= inv; wv1 *= inv; wv2 *= inv; wv3 *= inv;
        wv4 *= inv; wv5 *= inv; wv6 *= inv; wv7 *= inv;

        #define GAT1_BATCH(SV, WV, Q)                                            \
        {                                                                        \
            int ne = deg - (Q << 3);                                             \
            if (ne > 0) {                                                        \
                ne = min(ne, 8);                                                 \
                int sb[8]; float wb[8];                                          \
                _Pragma("unroll")                                                \
                for (int e8 = 0; e8 < 8; e8++) {                                 \
                    sb[e8] = __shfl(SV, e8 << 3);                                \
                    wb[e8] = __shfl(WV, (e8 << 3) + myh);                        \
                }                                                                \
                if (ne == 8) {                                                   \
                    _Pragma("unroll")                                            \
                    for (int e8 = 0; e8 < 8; e8++) {                             \
                        uint2 v = ((const uint2*)(H1b + ((long)sb[e8] << 8)))[lane]; \
                        acc.x += wb[e8] * bf_lo(v.x);                            \
                        acc.y += wb[e8] * bf_hi(v.x);                            \
                        acc.z += wb[e8] * bf_lo(v.y);                            \
                        acc.w += wb[e8] * bf_hi(v.y);                            \
                    }                                                            \
                } else {                                                         \
                    _Pragma("unroll")                                            \
                    for (int e8 = 0; e8 < 8; e8++) {                             \
                        if (e8 < ne) {                                           \
                            uint2 v = ((const uint2*)(H1b + ((long)sb[e8] << 8)))[lane]; \
                            acc.x += wb[e8] * bf_lo(v.x);                        \
                            acc.y += wb[e8] * bf_hi(v.x);                        \
                            acc.z += wb[e8] * bf_lo(v.y);                        \
                            acc.w += wb[e8] * bf_hi(v.y);                        \
                        }                                                        \
                    }                                                            \
                }                                                                \
            }                                                                    \
        }
        GAT1_BATCH(sv0, wv0, 0)
        GAT1_BATCH(sv1, wv1, 1)
        GAT1_BATCH(sv2, wv2, 2)
        GAT1_BATCH(sv3, wv3, 3)
        GAT1_BATCH(sv4, wv4, 4)
        GAT1_BATCH(sv5, wv5, 5)
        GAT1_BATCH(sv6, wv6, 6)
        GAT1_BATCH(sv7, wv7, 7)
        #undef GAT1_BATCH
    } else {
        float dA = 0.f, dB = 0.f;
        for (int j0 = beg; j0 < end; j0 += 16) {
            int j = j0 + el, jb = j0 + 8 + el;
            if (j < end)  dA += __expf(lrelu(as1[(srcs[j] << 3) + he] + adv));
            if (jb < end) dB += __expf(lrelu(as1[(srcs[jb] << 3) + he] + adv));
        }
        float d = dA + dB;
        #pragma unroll
        for (int off = 8; off < 64; off <<= 1) d += __shfl_xor(d, off);
        float inv = 1.f / d;
        for (int j0 = beg; j0 < end; j0 += 8) {
            int j = j0 + el;
            int s = 0; float wv = 0.f;
            if (j < end) {
                s = srcs[j];
                wv = __expf(lrelu(as1[(s << 3) + he] + adv)) * inv;
            }
            int ne = min(end - j0, 8);
            int sb[8]; float wb[8];
            #pragma unroll
            for (int e8 = 0; e8 < 8; e8++) {
                sb[e8] = __shfl(s, e8 << 3);
                wb[e8] = __shfl(wv, (e8 << 3) + myh);
            }
            #pragma unroll
            for (int e8 = 0; e8 < 8; e8++) {
                if (e8 < ne) {
                    uint2 v = ((const uint2*)(H1b + ((long)sb[e8] << 8)))[lane];
                    acc.x += wb[e8] * bf_lo(v.x);
                    acc.y += wb[e8] * bf_hi(v.x);
                    acc.z += wb[e8] * bf_lo(v.y);
                    acc.w += wb[e8] * bf_hi(v.y);
                }
            }
        }
    }

    float4 bb = ((const float4*)b1)[lane];
    float o0 = fmaxf(acc.x + bb.x, 0.f);
    float o1 = fmaxf(acc.y + bb.y, 0.f);
    float o2 = fmaxf(acc.z + bb.z, 0.f);
    float o3 = fmaxf(acc.w + bb.w, 0.f);
    uint2 ov;
    ov.x = (uint_t)f2bf(o0) | ((uint_t)f2bf(o1) << 16);
    ov.y = (uint_t)f2bf(o2) | ((uint_t)f2bf(o3) << 16);
    ((uint2*)(X1b + ((long)w << 8)))[lane] = ov;
}

// ---------------- GEMM2 (MFMA) + fused alpha2: h2 = x1b @ W2t^T ----------------
__global__ __launch_bounds__(256) void gemm2_k(const ushort_t* __restrict__ X1b,
    const ushort_t* __restrict__ W2t, const float* __restrict__ a2s_w,
    const float* __restrict__ a2d_w, float* __restrict__ H2,
    float* __restrict__ as2, float* __restrict__ ad2, int Nn)
{
    int wid = threadIdx.x >> 6, lane = threadIdx.x & 63;
    int row0 = blockIdx.x * 64 + wid * 16;
    if (row0 >= Nn) return;
    int lm = lane & 15, lg = lane >> 4;
    f32x4 acc = (f32x4){0.f, 0.f, 0.f, 0.f};
    const ushort_t* arow = X1b + (long)(row0 + lm) * 256 + lg * 8;
    const ushort_t* brow = W2t + lm * 256 + lg * 8;
    #pragma unroll
    for (int k0 = 0; k0 < 256; k0 += 32) {
        short8 af = *(const short8*)(arow + k0);
        short8 bf = *(const short8*)(brow + k0);
        acc = __builtin_amdgcn_mfma_f32_16x16x32_bf16(af, bf, acc, 0, 0, 0);
    }
    float a2sv = a2s_w[lm], a2dv = a2d_w[lm];
    #pragma unroll
    for (int r = 0; r < 4; r++) {
        int grow = row0 + lg * 4 + r;
        if (grow < Nn) H2[(grow << 4) + lm] = acc[r];
        float s = acc[r] * a2sv, d2 = acc[r] * a2dv;
        #pragma unroll
        for (int off = 1; off < 16; off <<= 1) {
            s += __shfl_xor(s, off);
            d2 += __shfl_xor(d2, off);
        }
        if (lm == 0 && grow < Nn) { as2[grow] = s; ad2[grow] = d2; }
    }
}

// ---------------- GAT layer 2 aggregate + final softmax (weight-cached) ----------------
__global__ __launch_bounds__(256) void gat2_agg_k(const float* __restrict__ H2,
    const float* __restrict__ as2, const float* __restrict__ ad2,
    const int* __restrict__ offs, const int* __restrict__ srcs,
    const float* __restrict__ b2, float* __restrict__ out, int Nn)
{
    int w = (blockIdx.x << 2) + (threadIdx.x >> 6);
    if (w >= Nn) return;
    int lane = threadIdx.x & 63;
    int beg = offs[w], end = offs[w + 1];
    int deg = end - beg;
    float adv = ad2[w];
    int c = lane & 15, eg = lane >> 4;
    float acc = 0.f;

    if (deg <= 64) {
        int j = beg + lane;
        int s_l = 0; float w_l = 0.f;
        if (j < end) { s_l = srcs[j]; w_l = __expf(lrelu(as2[s_l] + adv)); }
        float d = w_l;
        #pragma unroll
        for (int off = 1; off < 64; off <<= 1) d += __shfl_xor(d, off);
        float w_n = w_l / d;
        for (int j0 = 0; j0 < deg; j0 += 4) {
            int jj = j0 + eg;
            int s = __shfl(s_l, jj);
            float wv = __shfl(w_n, jj);
            if (jj < deg)
                acc += wv * H2[(s << 4) + c];
        }
    } else {
        float d = 0.f;
        for (int j = beg + lane; j < end; j += 64)
            d += __expf(lrelu(as2[srcs[j]] + adv));
        #pragma unroll
        for (int off = 1; off < 64; off <<= 1) d += __shfl_xor(d, off);
        float inv = 1.f / d;
        for (int j0 = beg; j0 < end; j0 += 4) {
            int j = j0 + eg;
            if (j < end) {
                int s = srcs[j];
                float wv = __expf(lrelu(as2[s] + adv)) * inv;
                acc += wv * H2[(s << 4) + c];
            }
        }
    }
    acc += __shfl_xor(acc, 16);
    acc += __shfl_xor(acc, 32);
    float v = acc + b2[c];
    float mx = v;
    #pragma unroll
    for (int off = 1; off < 16; off <<= 1) mx = fmaxf(mx, __shfl_xor(mx, off));
    float ex = __expf(v - mx);
    float se = ex;
    #pragma unroll
    for (int off = 1; off < 16; off <<= 1) se += __shfl_xor(se, off);
    if (eg == 0) out[(w << 4) + c] = ex / se;
}

// ---------------- host launcher ----------------
extern "C" void kernel_launch(void* const* d_in, const int* in_sizes, int n_in,
                              void* d_out, int out_size, void* d_ws, size_t ws_size,
                              hipStream_t stream)
{
    const float* x    = (const float*)d_in[0];
    const int*   ei   = (const int*)d_in[1];
    const float* W1   = (const float*)d_in[2];
    const float* a1s  = (const float*)d_in[3];
    const float* a1d  = (const float*)d_in[4];
    const float* b1   = (const float*)d_in[5];
    const float* W2   = (const float*)d_in[6];
    const float* a2s  = (const float*)d_in[7];
    const float* a2d  = (const float*)d_in[8];
    const float* b2   = (const float*)d_in[9];
    float* out = (float*)d_out;

    int N = in_sizes[0] / HID;
    int E = in_sizes[1] / 2;
    int Etot = E + N;
    const int* src = ei;
    const int* dst = ei + E;

    char* p = (char*)d_ws;
    auto alloc = [&](size_t bytes) {
        void* r = (void*)p;
        p += (bytes + 255) & ~(size_t)255;
        return r;
    };
    ushort_t* xbf  = (ushort_t*)alloc((size_t)N * 256 * 2);
    ushort_t* h1b  = (ushort_t*)alloc((size_t)N * 256 * 2);
    ushort_t* x1b  = (ushort_t*)alloc((size_t)N * 256 * 2);
    ushort_t* w1t  = (ushort_t*)alloc((size_t)256 * 256 * 2);
    ushort_t* w2t  = (ushort_t*)alloc((size_t)16 * 256 * 2);
    float* h2      = (float*)alloc((size_t)N * 16 * 4);
    float* as1     = (float*)alloc((size_t)N * 8 * 4);
    float* ad1     = (float*)alloc((size_t)N * 8 * 4);
    float* as2v    = (float*)alloc((size_t)N * 4);
    float* ad2v    = (float*)alloc((size_t)N * 4);
    int*   deg     = (int*)alloc((size_t)N * 4);
    int*   incl    = (int*)alloc((size_t)N * 4);
    int*   offs    = (int*)alloc((size_t)(N + 1) * 4);
    int*   bsum    = (int*)alloc(256 * 4);
    int*   bpre    = (int*)alloc(256 * 4);
    int*   srcs    = (int*)alloc((size_t)Etot * 4);
    int*   slot    = (int*)alloc((size_t)Etot * 4);

    int nb = (N + 1023) / 1024;
    int cnt_blocks = (Etot + 255) / 256;
    int scat_blocks = (Etot + 1023) / 1024;

    // zero deg, then merged prep (W1t | W2t | Xbf | deg_count+slot)
    hipMemsetAsync(deg, 0, (size_t)N * 4, stream);
    hipLaunchKernelGGL(prep_k, dim3(65 + 2048 + cnt_blocks), dim3(256), 0, stream,
                       x, xbf, (long)N * 64, W1, w1t, W2, w2t, dst, E, Etot, deg, slot);
    // CSR scans
    hipLaunchKernelGGL(scan1_k, dim3(nb), dim3(256), 0, stream, deg, incl, bsum, N);
    hipLaunchKernelGGL(scan2_k, dim3(1), dim3(64), 0, stream, bsum, bpre, nb);
    hipLaunchKernelGGL(scan3_k, dim3((N + 255) / 256), dim3(256), 0, stream,
                       incl, deg, bpre, offs, N, Etot);
    // atomic-free scatter
    hipLaunchKernelGGL(scatter_k, dim3(scat_blocks), dim3(256), 0, stream,
                       src, dst, slot, offs, E, Etot, srcs);
    // GEMM1 (MFMA, async-staged, fused alpha1)
    dim3 g1(2, (N + 127) / 128);
    hipLaunchKernelGGL(gemm1_k, g1, dim3(256), 0, stream,
                       xbf, w1t, a1s, a1d, h1b, as1, ad1, N);
    // layer 1 aggregate
    hipLaunchKernelGGL(gat1_agg_k, dim3((N + 3) / 4), dim3(256), 0, stream,
                       h1b, as1, ad1, offs, srcs, b1, x1b, N);
    // layer 2: MFMA gemm2 + aggregate
    hipLaunchKernelGGL(gemm2_k, dim3((N + 63) / 64), dim3(256), 0, stream,
                       x1b, w2t, a2s, a2d, h2, as2v, ad2v, N);
    hipLaunchKernelGGL(gat2_agg_k, dim3((N + 3) / 4), dim3(256), 0, stream,
                       h2, as2v, ad2v, offs, srcs, b2, out, N);
}